// Round 2
// baseline (252.511 us; speedup 1.0000x reference)
//
#include <hip/hip_runtime.h>
#include <cstddef>

typedef __attribute__((ext_vector_type(8))) __bf16 bf16x8;
typedef __attribute__((ext_vector_type(4))) float f32x4;
typedef unsigned short u16;
typedef unsigned int   u32;

// ---------- helpers ----------
__device__ __forceinline__ u16 f2bf(float f){
  union { float f; u32 u; } v; v.f = f;
  u32 r = v.u + 0x7FFFu + ((v.u >> 16) & 1u);   // RNE
  return (u16)(r >> 16);
}

__device__ __forceinline__ void gll16(const void* g, void* l){
  // async global->LDS, 16B per lane; LDS dest = wave-uniform base + lane*16
  __builtin_amdgcn_global_load_lds((__attribute__((address_space(1))) void*)g,
                                   (__attribute__((address_space(3))) void*)l, 16, 0, 0);
}

// ---------- prep: Wk = wk_c @ wk_e (64x64), Wv likewise ----------
__global__ void prep_wkv(const float* __restrict__ kc, const float* __restrict__ ke,
                         const float* __restrict__ vc, const float* __restrict__ ve,
                         float* __restrict__ Wk, float* __restrict__ Wv){
  int p = blockIdx.x & 1, chunk = blockIdx.x >> 1;
  const float* cm = p ? vc : kc;
  const float* em = p ? ve : ke;
  float* om = p ? Wv : Wk;
  int idx = chunk*256 + threadIdx.x;     // 0..4095
  int d = idx >> 6, j = idx & 63;
  float acc = 0.f;
  #pragma unroll
  for (int r=0;r<32;++r) acc += cm[d*32+r]*em[r*64+j];
  om[idx] = acc;
}

// ---------- prep: folded bias b2[3072] ----------
__global__ void prep_bias(const float* __restrict__ b, const float* __restrict__ Wk,
                          const float* __restrict__ Wv, float* __restrict__ b2){
  int n = blockIdx.x*256 + threadIdx.x;
  if (n >= 3072) return;
  if (n < 1024) { b2[n] = b[n]; return; }
  int rem = n - 1024;
  int p = rem >> 10; rem &= 1023;
  int h = rem >> 6, j = rem & 63;
  const float* Wm = p ? Wv : Wk;
  const float* bs = b + 1024 + p*1024 + h*64;
  float acc = 0.f;
  #pragma unroll
  for (int d=0;d<64;++d) acc += bs[d]*Wm[d*64+j];
  b2[n] = acc;
}

// ---------- prep: fold K/V expansion into attn weights (transposed, bf16) ----------
// Wt[n][c] (n in [1024,3072)) = sum_d W[c][1024+p*1024+h*64+d] * Wm[d][j]
__global__ __launch_bounds__(256) void prep_fold(const float* __restrict__ W,
            const float* __restrict__ Wk, const float* __restrict__ Wv,
            u16* __restrict__ Wt){
  __shared__ float WkL[64*64];     // permuted: [d][ (j&1)*32 + (j>>1) ]
  int p = blockIdx.x >> 7, h = (blockIdx.x >> 3) & 15, ct = blockIdx.x & 7;
  const float* Wm = p ? Wv : Wk;
  int tid = threadIdx.x;
  #pragma unroll
  for (int t=0;t<16;++t){
    int idx = tid + t*256;
    int d = idx >> 6, j = idx & 63;
    WkL[d*64 + (j&1)*32 + (j>>1)] = Wm[idx];
  }
  __syncthreads();
  int cw = tid & 127, jh = tid >> 7;        // jh in {0,1}
  int c0 = ct*128;
  int coloff = 1024 + p*1024 + h*64;
  const float* wrow = W + (size_t)(c0+cw)*3072 + coloff;
  float acc[32];
  #pragma unroll
  for (int i=0;i<32;++i) acc[i]=0.f;
  for (int d=0; d<64; ++d){
    float wvv = wrow[d];
    const float4* col = (const float4*)&WkL[d*64 + jh*32];
    #pragma unroll
    for (int q=0;q<8;++q){
      float4 cv = col[q];
      acc[q*4+0] += wvv*cv.x;
      acc[q*4+1] += wvv*cv.y;
      acc[q*4+2] += wvv*cv.z;
      acc[q*4+3] += wvv*cv.w;
    }
  }
  int nbase = 1024 + p*1024 + h*64;
  #pragma unroll
  for (int i=0;i<32;++i){
    int j = jh + 2*i;
    Wt[(size_t)(nbase + j)*1024 + c0 + cw] = f2bf(acc[i]);
  }
}

// ---------- prep: transpose+convert fp32 [1024 x ld] -> bf16 [1024 x ld_dst] ----------
// dst[n][c] = src[c][n]
__global__ __launch_bounds__(256) void transpose_cvt(const float* __restrict__ src, int ld_src,
            u16* __restrict__ dst, int ld_dst){
  __shared__ float tile[64][65];
  int c0 = blockIdx.x*64, n0 = blockIdx.y*64;
  int tx = threadIdx.x & 63, ty = threadIdx.x >> 6;  // ty 0..3
  #pragma unroll 4
  for (int k=0;k<16;++k){
    int r = 4*k + ty;
    tile[r][tx] = src[(size_t)(c0+r)*ld_src + n0 + tx];
  }
  __syncthreads();
  #pragma unroll 4
  for (int k=0;k<16;++k){
    int r = 4*k + ty;
    dst[(size_t)(n0+r)*ld_dst + c0 + tx] = f2bf(tile[tx][r]);
  }
}

// ---------- prep: x fp32 -> bf16 ----------
__global__ void convert_x(const float* __restrict__ x, u16* __restrict__ o, int n4){
  int i = blockIdx.x*blockDim.x + threadIdx.x;
  if (i >= n4) return;
  float4 v = ((const float4*)x)[i];
  ushort4 r; r.x = f2bf(v.x); r.y = f2bf(v.y); r.z = f2bf(v.z); r.w = f2bf(v.w);
  ((ushort4*)o)[i] = r;
}

// ---------- bf16 GEMM: C[M,N] = A[M,K] * Bt[N,K]^T + bias ----------
// 128x128 tile, BK=64, 4 waves (each 64x64), mfma_f32_16x16x32_bf16
template<typename OT>
__global__ __launch_bounds__(256) void gemm_bt(const u16* __restrict__ A, const u16* __restrict__ Bt,
        const float* __restrict__ bias, OT* __restrict__ C, int M, int N, int K, int ldc){
  __shared__ u16 As[128*64];
  __shared__ u16 Bs[128*64];
  const int tid = threadIdx.x, wv = tid>>6, ln = tid&63;
  const int lr = ln&15, g8 = (ln>>4)*8;
  const int m0 = blockIdx.x*128, n0 = blockIdx.y*128;
  const int wr = (wv>>1)*64, wc = (wv&1)*64;
  f32x4 acc[4][4] = {};
  const int nk = K >> 6;
  for (int kt=0; kt<nk; ++kt){
    #pragma unroll
    for (int it=0; it<4; ++it){
      int chunk = wv*4+it;                      // 16 chunks of 8 rows
      int row = chunk*8 + (ln>>3), colc = (ln&7)*8;
      gll16(A  + (size_t)(m0+row)*K + kt*64 + colc, &As[chunk*512]);
      gll16(Bt + (size_t)(n0+row)*K + kt*64 + colc, &Bs[chunk*512]);
    }
    __syncthreads();
    #pragma unroll
    for (int ks=0; ks<2; ++ks){
      bf16x8 af[4], bfr[4];
      #pragma unroll
      for (int mt=0;mt<4;++mt) af[mt]  = *(const bf16x8*)&As[(wr+mt*16+lr)*64 + ks*32 + g8];
      #pragma unroll
      for (int nt=0;nt<4;++nt) bfr[nt] = *(const bf16x8*)&Bs[(wc+nt*16+lr)*64 + ks*32 + g8];
      #pragma unroll
      for (int mt=0;mt<4;++mt)
        #pragma unroll
        for (int nt=0;nt<4;++nt)
          acc[mt][nt] = __builtin_amdgcn_mfma_f32_16x16x32_bf16(af[mt], bfr[nt], acc[mt][nt], 0,0,0);
    }
    __syncthreads();
  }
  #pragma unroll
  for (int mt=0;mt<4;++mt){
    int row = m0 + wr + mt*16 + 4*(ln>>4);
    #pragma unroll
    for (int nt=0;nt<4;++nt){
      int col = n0 + wc + nt*16 + lr;
      float bv = bias[col];
      #pragma unroll
      for (int r=0;r<4;++r){
        float v = acc[mt][nt][r] + bv;
        if constexpr (sizeof(OT) == 2) C[(size_t)(row+r)*ldc + col] = f2bf(v);
        else                           C[(size_t)(row+r)*ldc + col] = v;
      }
    }
  }
}

// ---------- causal flash attention ----------
// QKV [4096][3072] bf16 rows = b*2048+t; Q at col 0, Kexp at 1024, Vexp at 2048 (+h*64)
// grid (32 q-tiles of 64, 32 bh). 4 waves; wave owns 16 q rows.
__global__ __launch_bounds__(256) void attn_fwd(const u16* __restrict__ QKV, u16* __restrict__ Out){
  const int qt = blockIdx.x, bh = blockIdx.y;
  const int b = bh >> 4, h = bh & 15;
  const int tid = threadIdx.x, wv = tid>>6, ln = tid&63;
  const int lr = ln&15, gq = ln>>4, g8 = gq*8;
  __shared__ u16 Ks[64*72];        // [kv][d] pad 72
  __shared__ u16 Vs[64*72];        // transposed [d][kv] pad 72
  __shared__ u16 Ps[4][16*72];     // per-wave P [q][kv] pad 72
  const int q0 = qt*64;
  const size_t base = (size_t)(b*2048) * 3072;
  const u16* qrow = QKV + base + (size_t)(q0 + wv*16 + lr)*3072 + h*64;
  bf16x8 qf0 = *(const bf16x8*)(qrow + g8);
  bf16x8 qf1 = *(const bf16x8*)(qrow + 32 + g8);
  f32x4 o[4] = {};
  float m_r[4], l_r[4];
  #pragma unroll
  for (int r=0;r<4;++r){ m_r[r] = -1e30f; l_r[r] = 0.f; }
  const int sr = tid>>2, sc = (tid&3)*16;       // staging: row, col-chunk
  const u16* ksrc = QKV + base + 1024 + h*64;
  const u16* vsrc = QKV + base + 2048 + h*64;
  const int qrow0 = q0 + wv*16 + 4*gq;

  for (int kt=0; kt<=qt; ++kt){
    __syncthreads();                            // protect LDS from previous PV reads
    const int kv0 = kt*64;
    { // stage K [kv][d] and V^T [d][kv]
      const uint4* s1 = (const uint4*)(ksrc + (size_t)(kv0+sr)*3072 + sc);
      *(uint4*)&Ks[sr*72 + sc]     = s1[0];
      *(uint4*)&Ks[sr*72 + sc + 8] = s1[1];
      const uint4* s2 = (const uint4*)(vsrc + (size_t)(kv0+sr)*3072 + sc);
      uint4 v0 = s2[0], v1 = s2[1];
      const u16* t0 = (const u16*)&v0;
      #pragma unroll
      for (int i=0;i<8;++i) Vs[(sc+i)*72 + sr] = t0[i];
      const u16* t1 = (const u16*)&v1;
      #pragma unroll
      for (int i=0;i<8;++i) Vs[(sc+8+i)*72 + sr] = t1[i];
    }
    __syncthreads();
    // S = Q K^T
    f32x4 s4[4] = {};
    #pragma unroll
    for (int nt=0;nt<4;++nt){
      bf16x8 b0 = *(const bf16x8*)&Ks[(nt*16+lr)*72 + g8];
      s4[nt] = __builtin_amdgcn_mfma_f32_16x16x32_bf16(qf0, b0, s4[nt], 0,0,0);
      bf16x8 b1 = *(const bf16x8*)&Ks[(nt*16+lr)*72 + 32 + g8];
      s4[nt] = __builtin_amdgcn_mfma_f32_16x16x32_bf16(qf1, b1, s4[nt], 0,0,0);
    }
    // scale + causal mask + row max
    float mnew[4];
    #pragma unroll
    for (int r=0;r<4;++r) mnew[r] = -1e30f;
    #pragma unroll
    for (int nt=0;nt<4;++nt){
      int kg = kv0 + nt*16 + lr;
      #pragma unroll
      for (int r=0;r<4;++r){
        float v = s4[nt][r]*0.125f;
        if (kt==qt && kg > qrow0 + r) v = -1e30f;
        s4[nt][r] = v;
        mnew[r] = fmaxf(mnew[r], v);
      }
    }
    #pragma unroll
    for (int r=0;r<4;++r){
      float m = mnew[r];
      m = fmaxf(m, __shfl_xor(m,1)); m = fmaxf(m, __shfl_xor(m,2));
      m = fmaxf(m, __shfl_xor(m,4)); m = fmaxf(m, __shfl_xor(m,8));
      float mo = m_r[r];
      float mn = fmaxf(mo, m);
      m_r[r] = mn;
      float alpha = __expf(mo - mn);
      l_r[r] *= alpha;
      #pragma unroll
      for (int dt=0;dt<4;++dt) o[dt][r] *= alpha;
    }
    // P = exp(S - m), store bf16 to LDS, row sums
    float rs[4] = {0.f,0.f,0.f,0.f};
    #pragma unroll
    for (int nt=0;nt<4;++nt){
      #pragma unroll
      for (int r=0;r<4;++r){
        float p = __expf(s4[nt][r] - m_r[r]);
        rs[r] += p;
        Ps[wv][(4*gq+r)*72 + nt*16 + lr] = f2bf(p);
      }
    }
    #pragma unroll
    for (int r=0;r<4;++r){
      float t = rs[r];
      t += __shfl_xor(t,1); t += __shfl_xor(t,2);
      t += __shfl_xor(t,4); t += __shfl_xor(t,8);
      l_r[r] += t;
    }
    __syncthreads();   // cross-lane P visibility
    // O += P V
    #pragma unroll
    for (int ks=0; ks<2; ++ks){
      bf16x8 pa = *(const bf16x8*)&Ps[wv][lr*72 + ks*32 + g8];
      #pragma unroll
      for (int dt=0;dt<4;++dt){
        bf16x8 vb = *(const bf16x8*)&Vs[(dt*16+lr)*72 + ks*32 + g8];
        o[dt] = __builtin_amdgcn_mfma_f32_16x16x32_bf16(pa, vb, o[dt], 0,0,0);
      }
    }
  }
  // epilogue: merged-head layout [4096][1024]
  #pragma unroll
  for (int dt=0;dt<4;++dt){
    #pragma unroll
    for (int r=0;r<4;++r){
      float v = o[dt][r] / l_r[r];
      Out[(size_t)(b*2048 + q0 + wv*16 + 4*gq + r)*1024 + h*64 + dt*16 + lr] = f2bf(v);
    }
  }
}

// ---------- workspace layout (bytes) ----------
#define WS_WK   0u
#define WS_WV   16384u
#define WS_B2   32768u
#define WS_WT   49152u                               // 3072*1024*2 = 6291456
#define WS_W2T  (WS_WT + 6291456u)                   // 1024*1024*2 = 2097152
#define WS_XB   (WS_W2T + 2097152u)                  // 4096*1024*2 = 8388608
#define WS_QKV  (WS_XB + 8388608u)                   // 4096*3072*2 = 25165824
#define WS_ATT  (WS_QKV + 25165824u)                 // 4096*1024*2 = 8388608

extern "C" void kernel_launch(void* const* d_in, const int* in_sizes, int n_in,
                              void* d_out, int out_size, void* d_ws, size_t ws_size,
                              hipStream_t stream) {
  const float* x  = (const float*)d_in[0];
  const float* Wa = (const float*)d_in[1];
  const float* ba = (const float*)d_in[2];
  const float* Wp = (const float*)d_in[3];
  const float* bp = (const float*)d_in[4];
  const float* kc = (const float*)d_in[5];
  const float* ke = (const float*)d_in[6];
  const float* vc = (const float*)d_in[7];
  const float* ve = (const float*)d_in[8];
  float* out = (float*)d_out;
  char* ws = (char*)d_ws;
  float* Wk  = (float*)(ws + WS_WK);
  float* Wv  = (float*)(ws + WS_WV);
  float* b2  = (float*)(ws + WS_B2);
  u16* Wt    = (u16*)(ws + WS_WT);
  u16* W2t   = (u16*)(ws + WS_W2T);
  u16* Xb    = (u16*)(ws + WS_XB);
  u16* QKVb  = (u16*)(ws + WS_QKV);
  u16* Att   = (u16*)(ws + WS_ATT);

  prep_wkv<<<32, 256, 0, stream>>>(kc, ke, vc, ve, Wk, Wv);
  prep_bias<<<12, 256, 0, stream>>>(ba, Wk, Wv, b2);
  prep_fold<<<256, 256, 0, stream>>>(Wa, Wk, Wv, Wt);
  transpose_cvt<<<dim3(16,16), 256, 0, stream>>>(Wa, 3072, Wt, 1024);   // Q part (n<1024)
  transpose_cvt<<<dim3(16,16), 256, 0, stream>>>(Wp, 1024, W2t, 1024);  // proj weight
  convert_x<<<4096, 256, 0, stream>>>(x, Xb, 1048576);
  gemm_bt<u16><<<dim3(32,24), 256, 0, stream>>>(Xb, Wt, b2, QKVb, 4096, 3072, 1024, 3072);
  attn_fwd<<<dim3(32,32), 256, 0, stream>>>(QKVb, Att);   // FIX: 32 q-tiles (T=2048), was 16
  gemm_bt<float><<<dim3(32,8), 256, 0, stream>>>(Att, W2t, bp, out, 4096, 1024, 1024, 1024);
}

// Round 3
// 182.868 us; speedup vs baseline: 1.3808x; 1.3808x over previous
//
#include <hip/hip_runtime.h>
#include <cstddef>

typedef __attribute__((ext_vector_type(8))) __bf16 bf16x8;
typedef __attribute__((ext_vector_type(4))) float f32x4;
typedef unsigned short u16;
typedef unsigned int   u32;

// ---------- helpers ----------
__device__ __forceinline__ u16 f2bf(float f){
  union { float f; u32 u; } v; v.f = f;
  u32 r = v.u + 0x7FFFu + ((v.u >> 16) & 1u);   // RNE
  return (u16)(r >> 16);
}
__device__ __forceinline__ u32 pack2(float a, float b){
  return (u32)f2bf(a) | ((u32)f2bf(b) << 16);
}

__device__ __forceinline__ void gll16(const void* g, void* l){
  // async global->LDS, 16B per lane; LDS dest = wave-uniform base + lane*16
  __builtin_amdgcn_global_load_lds((__attribute__((address_space(1))) void*)g,
                                   (__attribute__((address_space(3))) void*)l, 16, 0, 0);
}

// ---------- prep: Wk = wk_c @ wk_e (64x64), Wv likewise ----------
__global__ void prep_wkv(const float* __restrict__ kc, const float* __restrict__ ke,
                         const float* __restrict__ vc, const float* __restrict__ ve,
                         float* __restrict__ Wk, float* __restrict__ Wv){
  int p = blockIdx.x & 1, chunk = blockIdx.x >> 1;
  const float* cm = p ? vc : kc;
  const float* em = p ? ve : ke;
  float* om = p ? Wv : Wk;
  int idx = chunk*256 + threadIdx.x;     // 0..4095
  int d = idx >> 6, j = idx & 63;
  float acc = 0.f;
  #pragma unroll
  for (int r=0;r<32;++r) acc += cm[d*32+r]*em[r*64+j];
  om[idx] = acc;
}

// ---------- prep: folded bias b2[3072] ----------
__global__ void prep_bias(const float* __restrict__ b, const float* __restrict__ Wk,
                          const float* __restrict__ Wv, float* __restrict__ b2){
  int n = blockIdx.x*256 + threadIdx.x;
  if (n >= 3072) return;
  if (n < 1024) { b2[n] = b[n]; return; }
  int rem = n - 1024;
  int p = rem >> 10; rem &= 1023;
  int h = rem >> 6, j = rem & 63;
  const float* Wm = p ? Wv : Wk;
  const float* bs = b + 1024 + p*1024 + h*64;
  float acc = 0.f;
  #pragma unroll
  for (int d=0;d<64;++d) acc += bs[d]*Wm[d*64+j];
  b2[n] = acc;
}

// ---------- prep: fold K/V expansion into attn weights (transposed, bf16) ----------
__global__ __launch_bounds__(256) void prep_fold(const float* __restrict__ W,
            const float* __restrict__ Wk, const float* __restrict__ Wv,
            u16* __restrict__ Wt){
  __shared__ float WkL[64*64];     // permuted: [d][ (j&1)*32 + (j>>1) ]
  int p = blockIdx.x >> 7, h = (blockIdx.x >> 3) & 15, ct = blockIdx.x & 7;
  const float* Wm = p ? Wv : Wk;
  int tid = threadIdx.x;
  #pragma unroll
  for (int t=0;t<16;++t){
    int idx = tid + t*256;
    int d = idx >> 6, j = idx & 63;
    WkL[d*64 + (j&1)*32 + (j>>1)] = Wm[idx];
  }
  __syncthreads();
  int cw = tid & 127, jh = tid >> 7;        // jh in {0,1}
  int c0 = ct*128;
  int coloff = 1024 + p*1024 + h*64;
  const float* wrow = W + (size_t)(c0+cw)*3072 + coloff;
  float acc[32];
  #pragma unroll
  for (int i=0;i<32;++i) acc[i]=0.f;
  for (int d=0; d<64; ++d){
    float wvv = wrow[d];
    const float4* col = (const float4*)&WkL[d*64 + jh*32];
    #pragma unroll
    for (int q=0;q<8;++q){
      float4 cv = col[q];
      acc[q*4+0] += wvv*cv.x;
      acc[q*4+1] += wvv*cv.y;
      acc[q*4+2] += wvv*cv.z;
      acc[q*4+3] += wvv*cv.w;
    }
  }
  int nbase = 1024 + p*1024 + h*64;
  #pragma unroll
  for (int i=0;i<32;++i){
    int j = jh + 2*i;
    Wt[(size_t)(nbase + j)*1024 + c0 + cw] = f2bf(acc[i]);
  }
}

// ---------- prep: transpose+convert fp32 [1024 x ld] -> bf16 ----------
__global__ __launch_bounds__(256) void transpose_cvt(const float* __restrict__ src, int ld_src,
            u16* __restrict__ dst, int ld_dst){
  __shared__ float tile[64][65];
  int c0 = blockIdx.x*64, n0 = blockIdx.y*64;
  int tx = threadIdx.x & 63, ty = threadIdx.x >> 6;  // ty 0..3
  #pragma unroll 4
  for (int k=0;k<16;++k){
    int r = 4*k + ty;
    tile[r][tx] = src[(size_t)(c0+r)*ld_src + n0 + tx];
  }
  __syncthreads();
  #pragma unroll 4
  for (int k=0;k<16;++k){
    int r = 4*k + ty;
    dst[(size_t)(n0+r)*ld_dst + c0 + tx] = f2bf(tile[tx][r]);
  }
}

// ---------- prep: x fp32 -> bf16 ----------
__global__ void convert_x(const float* __restrict__ x, u16* __restrict__ o, int n4){
  int i = blockIdx.x*blockDim.x + threadIdx.x;
  if (i >= n4) return;
  float4 v = ((const float4*)x)[i];
  ushort4 r; r.x = f2bf(v.x); r.y = f2bf(v.y); r.z = f2bf(v.z); r.w = f2bf(v.w);
  ((ushort4*)o)[i] = r;
}

// ---------- V transpose: QKV V-part -> Vt[bh*64+d][t], k-slot-permuted per 32-block ----------
// Vt column position p within a 32-block holds t-offset o(p) = 16*((p&7)>>2) + 4*((p&31)>>3) + (p&3)
__global__ __launch_bounds__(256) void v_transpose(const u16* __restrict__ QKV, u16* __restrict__ Vt){
  __shared__ u16 tile[64][72];   // [t][d]
  int tt = blockIdx.x, bh = blockIdx.y;
  int b = bh >> 4, h = bh & 15;
  int tid = threadIdx.x;
  int r = tid >> 2, cc = (tid & 3)*16;
  const u16* src = QKV + (size_t)(b*2048 + tt*64 + r)*3072 + 2048 + h*64 + cc;
  *(uint4*)&tile[r][cc]     = *(const uint4*)src;
  *(uint4*)&tile[r][cc + 8] = *(const uint4*)(src + 8);
  __syncthreads();
  int d = tid >> 2, pc = (tid & 3)*16;
  u16 vals[16];
  #pragma unroll
  for (int i=0;i<16;++i){
    int p = pc + i;
    int c = p >> 5, q = p & 31, g = q >> 3, j = q & 7;
    int o = 16*(j>>2) + 4*g + (j&3);
    vals[i] = tile[c*32 + o][d];
  }
  u16* drow = Vt + (size_t)(bh*64 + d)*2048 + tt*64 + pc;
  *(uint4*)drow       = *(const uint4*)&vals[0];
  *(uint4*)(drow + 8) = *(const uint4*)&vals[8];
}

// ---------- bf16 GEMM: C[M,N] = A[M,K] * Bt[N,K]^T + bias ----------
template<typename OT>
__global__ __launch_bounds__(256) void gemm_bt(const u16* __restrict__ A, const u16* __restrict__ Bt,
        const float* __restrict__ bias, OT* __restrict__ C, int M, int N, int K, int ldc){
  __shared__ u16 As[128*64];
  __shared__ u16 Bs[128*64];
  const int tid = threadIdx.x, wv = tid>>6, ln = tid&63;
  const int lr = ln&15, g8 = (ln>>4)*8;
  const int m0 = blockIdx.x*128, n0 = blockIdx.y*128;
  const int wr = (wv>>1)*64, wc = (wv&1)*64;
  f32x4 acc[4][4] = {};
  const int nk = K >> 6;
  for (int kt=0; kt<nk; ++kt){
    #pragma unroll
    for (int it=0; it<4; ++it){
      int chunk = wv*4+it;
      int row = chunk*8 + (ln>>3), colc = (ln&7)*8;
      gll16(A  + (size_t)(m0+row)*K + kt*64 + colc, &As[chunk*512]);
      gll16(Bt + (size_t)(n0+row)*K + kt*64 + colc, &Bs[chunk*512]);
    }
    __syncthreads();
    #pragma unroll
    for (int ks=0; ks<2; ++ks){
      bf16x8 af[4], bfr[4];
      #pragma unroll
      for (int mt=0;mt<4;++mt) af[mt]  = *(const bf16x8*)&As[(wr+mt*16+lr)*64 + ks*32 + g8];
      #pragma unroll
      for (int nt=0;nt<4;++nt) bfr[nt] = *(const bf16x8*)&Bs[(wc+nt*16+lr)*64 + ks*32 + g8];
      #pragma unroll
      for (int mt=0;mt<4;++mt)
        #pragma unroll
        for (int nt=0;nt<4;++nt)
          acc[mt][nt] = __builtin_amdgcn_mfma_f32_16x16x32_bf16(af[mt], bfr[nt], acc[mt][nt], 0,0,0);
    }
    __syncthreads();
  }
  #pragma unroll
  for (int mt=0;mt<4;++mt){
    int row = m0 + wr + mt*16 + 4*(ln>>4);
    #pragma unroll
    for (int nt=0;nt<4;++nt){
      int col = n0 + wc + nt*16 + lr;
      float bv = bias[col];
      #pragma unroll
      for (int r=0;r<4;++r){
        float v = acc[mt][nt][r] + bv;
        if constexpr (sizeof(OT) == 2) C[(size_t)(row+r)*ldc + col] = f2bf(v);
        else                           C[(size_t)(row+r)*ldc + col] = v;
      }
    }
  }
}

// ---------- causal flash attention, swapped-QK^T, in-register P ----------
// QKV [4096][3072]; Vt [32*64][2048] (k-slot-permuted). Out [4096][1024] merged heads.
// grid (32 qt, 32 bh), 4 waves; wave wv owns q rows [qt*64+wv*16, +16).
__global__ __launch_bounds__(256, 4) void attn_fwd(const u16* __restrict__ QKV,
            const u16* __restrict__ Vt, u16* __restrict__ Out){
  const int qt = blockIdx.x, bh = blockIdx.y;
  const int b = bh >> 4, h = bh & 15;
  const int tid = threadIdx.x, wv = tid>>6, ln = tid&63;
  const int lr = ln&15, gq = ln>>4;
  __shared__ u16 KB[2][64*64];
  __shared__ u16 VB[2][64*64];
  const int q0 = qt*64;
  const size_t base = (size_t)(b*2048) * 3072;
  // Q fragments (B-operand: col=lane&15=q), natural g8 layout
  const u16* qrow = QKV + base + (size_t)(q0 + wv*16 + lr)*3072 + h*64;
  bf16x8 qf0 = *(const bf16x8*)(qrow + gq*8);
  bf16x8 qf1 = *(const bf16x8*)(qrow + 32 + gq*8);
  const int qglob = q0 + wv*16 + lr;      // this lane's q (softmax layout)
  f32x4 o[4] = {};
  float m_r = -1e30f, l_r = 0.f;
  const u16* ksrc = QKV + base + 1024 + h*64;
  const u16* vsrc = Vt + (size_t)(bh*64)*2048;

  // staging: 2 gll16 per array per thread; chunk c=(i*4+wv)*64+ln; row=c>>3, swizzled source
  const int c0a = (0*4+wv)*64 + ln, c1a = (1*4+wv)*64 + ln;
  const int r0 = c0a>>3, sc0 = ((c0a&7) ^ (r0&7))*8;
  const int r1 = c1a>>3, sc1 = ((c1a&7) ^ (r1&7))*8;

  #define STAGE(bb, kt2) do { \
    int kv0s = (kt2)*64; \
    gll16(ksrc + (size_t)(kv0s+r0)*3072 + sc0, &KB[bb][(0*4+wv)*512]); \
    gll16(vsrc + (size_t)r0*2048 + kv0s + sc0, &VB[bb][(0*4+wv)*512]); \
    gll16(ksrc + (size_t)(kv0s+r1)*3072 + sc1, &KB[bb][(1*4+wv)*512]); \
    gll16(vsrc + (size_t)r1*2048 + kv0s + sc1, &VB[bb][(1*4+wv)*512]); \
  } while(0)

  STAGE(0, 0);
  __syncthreads();
  int buf = 0;

  for (int kt=0; kt<=qt; ++kt){
    if (kt < qt) STAGE(buf^1, kt+1);
    const int kv0 = kt*64;
    // S^T = K Q^T : col=lane&15=q, row k = kv0 + nt*16 + 4*gq + r
    f32x4 s4[4] = {};
    #pragma unroll
    for (int nt=0;nt<4;++nt){
      int row = nt*16 + lr;
      int sw = (row&7)<<4;
      const char* kb = (const char*)&KB[buf][row*64];
      bf16x8 k0 = *(const bf16x8*)(kb + ((gq*16) ^ sw));
      bf16x8 k1 = *(const bf16x8*)(kb + ((64 + gq*16) ^ sw));
      s4[nt] = __builtin_amdgcn_mfma_f32_16x16x32_bf16(k0, qf0, s4[nt], 0,0,0);
      s4[nt] = __builtin_amdgcn_mfma_f32_16x16x32_bf16(k1, qf1, s4[nt], 0,0,0);
    }
    // scale + causal mask + per-q (lane) max
    float mloc = -1e30f;
    #pragma unroll
    for (int nt=0;nt<4;++nt){
      #pragma unroll
      for (int r=0;r<4;++r){
        float v = s4[nt][r]*0.125f;
        if (kt==qt){ int k = kv0 + nt*16 + 4*gq + r; if (k > qglob) v = -1e30f; }
        s4[nt][r] = v;
        mloc = fmaxf(mloc, v);
      }
    }
    mloc = fmaxf(mloc, __shfl_xor(mloc, 16));
    mloc = fmaxf(mloc, __shfl_xor(mloc, 32));
    float mn = fmaxf(m_r, mloc);
    float alpha = __expf(m_r - mn);
    m_r = mn; l_r *= alpha;
    // rescale O (alpha per O-row q=4*gq+r, fetched from lane 4*gq+r)
    float a_o[4];
    #pragma unroll
    for (int r=0;r<4;++r) a_o[r] = __shfl(alpha, 4*gq + r);
    #pragma unroll
    for (int dt=0;dt<4;++dt)
      #pragma unroll
      for (int r=0;r<4;++r) o[dt][r] *= a_o[r];
    // P = exp(S-m), pack into A-fragments (lane-local, zero cross-lane)
    float rs = 0.f;
    u32 w[2][4];
    #pragma unroll
    for (int c=0;c<2;++c){
      float pv[8];
      #pragma unroll
      for (int u=0;u<4;++u){
        pv[u]   = __expf(s4[2*c  ][u] - m_r);
        pv[4+u] = __expf(s4[2*c+1][u] - m_r);
      }
      #pragma unroll
      for (int u=0;u<8;++u) rs += pv[u];
      w[c][0] = pack2(pv[0], pv[1]);
      w[c][1] = pack2(pv[2], pv[3]);
      w[c][2] = pack2(pv[4], pv[5]);
      w[c][3] = pack2(pv[6], pv[7]);
    }
    rs += __shfl_xor(rs, 16);
    rs += __shfl_xor(rs, 32);
    l_r += rs;
    // O += P V  (V fragments contiguous thanks to permuted Vt layout)
    #pragma unroll
    for (int c=0;c<2;++c){
      union { u32 u[4]; bf16x8 v; } pa;
      pa.u[0]=w[c][0]; pa.u[1]=w[c][1]; pa.u[2]=w[c][2]; pa.u[3]=w[c][3];
      #pragma unroll
      for (int dt=0;dt<4;++dt){
        int row = dt*16 + lr;
        int sw = (row&7)<<4;
        const char* vb0 = (const char*)&VB[buf][row*64];
        bf16x8 vb = *(const bf16x8*)(vb0 + ((c*64 + gq*16) ^ sw));
        o[dt] = __builtin_amdgcn_mfma_f32_16x16x32_bf16(pa.v, vb, o[dt], 0,0,0);
      }
    }
    __syncthreads();
    buf ^= 1;
  }
  // epilogue: O rows q=4*gq+r, cols d=dt*16+lr; divide by l (per q, from lane 4*gq+r)
  float l_o[4];
  #pragma unroll
  for (int r=0;r<4;++r) l_o[r] = __shfl(l_r, 4*gq + r);
  #pragma unroll
  for (int dt=0;dt<4;++dt){
    #pragma unroll
    for (int r=0;r<4;++r){
      float v = o[dt][r] / l_o[r];
      Out[(size_t)(b*2048 + q0 + wv*16 + 4*gq + r)*1024 + h*64 + dt*16 + lr] = f2bf(v);
    }
  }
}

// ---------- workspace layout (bytes) ----------
#define WS_WK   0u
#define WS_WV   16384u
#define WS_B2   32768u
#define WS_WT   49152u                               // 3072*1024*2 = 6291456
#define WS_W2T  (WS_WT + 6291456u)                   // 1024*1024*2 = 2097152
#define WS_XB   (WS_W2T + 2097152u)                  // 4096*1024*2 = 8388608 (reused as Vt)
#define WS_QKV  (WS_XB + 8388608u)                   // 4096*3072*2 = 25165824
#define WS_ATT  (WS_QKV + 25165824u)                 // 4096*1024*2 = 8388608

extern "C" void kernel_launch(void* const* d_in, const int* in_sizes, int n_in,
                              void* d_out, int out_size, void* d_ws, size_t ws_size,
                              hipStream_t stream) {
  const float* x  = (const float*)d_in[0];
  const float* Wa = (const float*)d_in[1];
  const float* ba = (const float*)d_in[2];
  const float* Wp = (const float*)d_in[3];
  const float* bp = (const float*)d_in[4];
  const float* kc = (const float*)d_in[5];
  const float* ke = (const float*)d_in[6];
  const float* vc = (const float*)d_in[7];
  const float* ve = (const float*)d_in[8];
  float* out = (float*)d_out;
  char* ws = (char*)d_ws;
  float* Wk  = (float*)(ws + WS_WK);
  float* Wv  = (float*)(ws + WS_WV);
  float* b2  = (float*)(ws + WS_B2);
  u16* Wt    = (u16*)(ws + WS_WT);
  u16* W2t   = (u16*)(ws + WS_W2T);
  u16* Xb    = (u16*)(ws + WS_XB);
  u16* QKVb  = (u16*)(ws + WS_QKV);
  u16* Att   = (u16*)(ws + WS_ATT);
  u16* Vt    = Xb;   // Xb dead after gemm1; reuse as Vt

  prep_wkv<<<32, 256, 0, stream>>>(kc, ke, vc, ve, Wk, Wv);
  prep_bias<<<12, 256, 0, stream>>>(ba, Wk, Wv, b2);
  prep_fold<<<256, 256, 0, stream>>>(Wa, Wk, Wv, Wt);
  transpose_cvt<<<dim3(16,16), 256, 0, stream>>>(Wa, 3072, Wt, 1024);   // Q part (n<1024)
  transpose_cvt<<<dim3(16,16), 256, 0, stream>>>(Wp, 1024, W2t, 1024);  // proj weight
  convert_x<<<4096, 256, 0, stream>>>(x, Xb, 1048576);
  gemm_bt<u16><<<dim3(32,24), 256, 0, stream>>>(Xb, Wt, b2, QKVb, 4096, 3072, 1024, 3072);
  v_transpose<<<dim3(32,32), 256, 0, stream>>>(QKVb, Vt);
  attn_fwd<<<dim3(32,32), 256, 0, stream>>>(QKVb, Vt, Att);
  gemm_bt<float><<<dim3(32,8), 256, 0, stream>>>(Att, W2t, bp, out, 4096, 1024, 1024, 1024);
}

// Round 4
// 165.868 us; speedup vs baseline: 1.5224x; 1.1025x over previous
//
#include <hip/hip_runtime.h>
#include <cstddef>

typedef __attribute__((ext_vector_type(8))) __bf16 bf16x8;
typedef __attribute__((ext_vector_type(4))) float f32x4;
typedef unsigned short u16;
typedef unsigned int   u32;

// ---------- helpers ----------
__device__ __forceinline__ u16 f2bf(float f){
  union { float f; u32 u; } v; v.f = f;
  u32 r = v.u + 0x7FFFu + ((v.u >> 16) & 1u);   // RNE
  return (u16)(r >> 16);
}
__device__ __forceinline__ u32 pack2(float a, float b){
  return (u32)f2bf(a) | ((u32)f2bf(b) << 16);
}

__device__ __forceinline__ void gll16(const void* g, void* l){
  __builtin_amdgcn_global_load_lds((__attribute__((address_space(1))) void*)g,
                                   (__attribute__((address_space(3))) void*)l, 16, 0, 0);
}

// ---------- prep: Wk = wk_c @ wk_e (64x64), Wv likewise ----------
__global__ void prep_wkv(const float* __restrict__ kc, const float* __restrict__ ke,
                         const float* __restrict__ vc, const float* __restrict__ ve,
                         float* __restrict__ Wk, float* __restrict__ Wv){
  int p = blockIdx.x & 1, chunk = blockIdx.x >> 1;
  const float* cm = p ? vc : kc;
  const float* em = p ? ve : ke;
  float* om = p ? Wv : Wk;
  int idx = chunk*256 + threadIdx.x;     // 0..4095
  int d = idx >> 6, j = idx & 63;
  float acc = 0.f;
  #pragma unroll
  for (int r=0;r<32;++r) acc += cm[d*32+r]*em[r*64+j];
  om[idx] = acc;
}

// ---------- prep: folded bias b2[3072] ----------
__global__ void prep_bias(const float* __restrict__ b, const float* __restrict__ Wk,
                          const float* __restrict__ Wv, float* __restrict__ b2){
  int n = blockIdx.x*256 + threadIdx.x;
  if (n >= 3072) return;
  if (n < 1024) { b2[n] = b[n]; return; }
  int rem = n - 1024;
  int p = rem >> 10; rem &= 1023;
  int h = rem >> 6, j = rem & 63;
  const float* Wm = p ? Wv : Wk;
  const float* bs = b + 1024 + p*1024 + h*64;
  float acc = 0.f;
  #pragma unroll
  for (int d=0;d<64;++d) acc += bs[d]*Wm[d*64+j];
  b2[n] = acc;
}

// ---------- prep: fold K/V expansion into attn weights (transposed, bf16) ----------
__global__ __launch_bounds__(256) void prep_fold(const float* __restrict__ W,
            const float* __restrict__ Wk, const float* __restrict__ Wv,
            u16* __restrict__ Wt){
  __shared__ float WkL[64*64];     // permuted: [d][ (j&1)*32 + (j>>1) ]
  int p = blockIdx.x >> 7, h = (blockIdx.x >> 3) & 15, ct = blockIdx.x & 7;
  const float* Wm = p ? Wv : Wk;
  int tid = threadIdx.x;
  #pragma unroll
  for (int t=0;t<16;++t){
    int idx = tid + t*256;
    int d = idx >> 6, j = idx & 63;
    WkL[d*64 + (j&1)*32 + (j>>1)] = Wm[idx];
  }
  __syncthreads();
  int cw = tid & 127, jh = tid >> 7;        // jh in {0,1}
  int c0 = ct*128;
  int coloff = 1024 + p*1024 + h*64;
  const float* wrow = W + (size_t)(c0+cw)*3072 + coloff;
  float acc[32];
  #pragma unroll
  for (int i=0;i<32;++i) acc[i]=0.f;
  for (int d=0; d<64; ++d){
    float wvv = wrow[d];
    const float4* col = (const float4*)&WkL[d*64 + jh*32];
    #pragma unroll
    for (int q=0;q<8;++q){
      float4 cv = col[q];
      acc[q*4+0] += wvv*cv.x;
      acc[q*4+1] += wvv*cv.y;
      acc[q*4+2] += wvv*cv.z;
      acc[q*4+3] += wvv*cv.w;
    }
  }
  int nbase = 1024 + p*1024 + h*64;
  #pragma unroll
  for (int i=0;i<32;++i){
    int j = jh + 2*i;
    Wt[(size_t)(nbase + j)*1024 + c0 + cw] = f2bf(acc[i]);
  }
}

// ---------- prep: transpose+convert fp32 [1024 x ld] -> bf16 ----------
__global__ __launch_bounds__(256) void transpose_cvt(const float* __restrict__ src, int ld_src,
            u16* __restrict__ dst, int ld_dst){
  __shared__ float tile[64][65];
  int c0 = blockIdx.x*64, n0 = blockIdx.y*64;
  int tx = threadIdx.x & 63, ty = threadIdx.x >> 6;  // ty 0..3
  #pragma unroll 4
  for (int k=0;k<16;++k){
    int r = 4*k + ty;
    tile[r][tx] = src[(size_t)(c0+r)*ld_src + n0 + tx];
  }
  __syncthreads();
  #pragma unroll 4
  for (int k=0;k<16;++k){
    int r = 4*k + ty;
    dst[(size_t)(n0+r)*ld_dst + c0 + tx] = f2bf(tile[tx][r]);
  }
}

// ---------- prep: x fp32 -> bf16 ----------
__global__ void convert_x(const float* __restrict__ x, u16* __restrict__ o, int n4){
  int i = blockIdx.x*blockDim.x + threadIdx.x;
  if (i >= n4) return;
  float4 v = ((const float4*)x)[i];
  ushort4 r; r.x = f2bf(v.x); r.y = f2bf(v.y); r.z = f2bf(v.z); r.w = f2bf(v.w);
  ((ushort4*)o)[i] = r;
}

// ---------- V transpose: QKV V-part -> Vt[bh*64+d][t], k-slot-permuted per 32-block ----------
__global__ __launch_bounds__(256) void v_transpose(const u16* __restrict__ QKV, u16* __restrict__ Vt){
  __shared__ u16 tile[64][72];   // [t][d]
  int tt = blockIdx.x, bh = blockIdx.y;
  int b = bh >> 4, h = bh & 15;
  int tid = threadIdx.x;
  int r = tid >> 2, cc = (tid & 3)*16;
  const u16* src = QKV + (size_t)(b*2048 + tt*64 + r)*3072 + 2048 + h*64 + cc;
  *(uint4*)&tile[r][cc]     = *(const uint4*)src;
  *(uint4*)&tile[r][cc + 8] = *(const uint4*)(src + 8);
  __syncthreads();
  int d = tid >> 2, pc = (tid & 3)*16;
  u16 vals[16];
  #pragma unroll
  for (int i=0;i<16;++i){
    int p = pc + i;
    int c = p >> 5, q = p & 31, g = q >> 3, j = q & 7;
    int o = 16*(j>>2) + 4*g + (j&3);
    vals[i] = tile[c*32 + o][d];
  }
  u16* drow = Vt + (size_t)(bh*64 + d)*2048 + tt*64 + pc;
  *(uint4*)drow       = *(const uint4*)&vals[0];
  *(uint4*)(drow + 8) = *(const uint4*)&vals[8];
}

// ---------- bf16 GEMM: C[M,N] = A[M,K] * Bt[N,K]^T + bias; XCD-swizzled ----------
template<typename OT>
__global__ __launch_bounds__(256) void gemm_bt(const u16* __restrict__ A, const u16* __restrict__ Bt,
        const float* __restrict__ bias, OT* __restrict__ C, int M, int N, int K, int ldc){
  __shared__ u16 As[128*64];
  __shared__ u16 Bs[128*64];
  // T1: XCD-aware swizzle (grid size % 8 == 0 for both launches)
  const int nwg = gridDim.x * gridDim.y;
  const int id  = blockIdx.x + gridDim.x * blockIdx.y;
  const int nid = (id & 7) * (nwg >> 3) + (id >> 3);
  const int bx = nid % gridDim.x, by = nid / gridDim.x;
  const int tid = threadIdx.x, wv = tid>>6, ln = tid&63;
  const int lr = ln&15, g8 = (ln>>4)*8;
  const int m0 = bx*128, n0 = by*128;
  const int wr = (wv>>1)*64, wc = (wv&1)*64;
  f32x4 acc[4][4] = {};
  const int nk = K >> 6;
  for (int kt=0; kt<nk; ++kt){
    #pragma unroll
    for (int it=0; it<4; ++it){
      int chunk = wv*4+it;
      int row = chunk*8 + (ln>>3), colc = (ln&7)*8;
      gll16(A  + (size_t)(m0+row)*K + kt*64 + colc, &As[chunk*512]);
      gll16(Bt + (size_t)(n0+row)*K + kt*64 + colc, &Bs[chunk*512]);
    }
    __syncthreads();
    #pragma unroll
    for (int ks=0; ks<2; ++ks){
      bf16x8 af[4], bfr[4];
      #pragma unroll
      for (int mt=0;mt<4;++mt) af[mt]  = *(const bf16x8*)&As[(wr+mt*16+lr)*64 + ks*32 + g8];
      #pragma unroll
      for (int nt=0;nt<4;++nt) bfr[nt] = *(const bf16x8*)&Bs[(wc+nt*16+lr)*64 + ks*32 + g8];
      #pragma unroll
      for (int mt=0;mt<4;++mt)
        #pragma unroll
        for (int nt=0;nt<4;++nt)
          acc[mt][nt] = __builtin_amdgcn_mfma_f32_16x16x32_bf16(af[mt], bfr[nt], acc[mt][nt], 0,0,0);
    }
    __syncthreads();
  }
  #pragma unroll
  for (int mt=0;mt<4;++mt){
    int row = m0 + wr + mt*16 + 4*(ln>>4);
    #pragma unroll
    for (int nt=0;nt<4;++nt){
      int col = n0 + wc + nt*16 + lr;
      float bv = bias[col];
      #pragma unroll
      for (int r=0;r<4;++r){
        float v = acc[mt][nt][r] + bv;
        if constexpr (sizeof(OT) == 2) C[(size_t)(row+r)*ldc + col] = f2bf(v);
        else                           C[(size_t)(row+r)*ldc + col] = v;
      }
    }
  }
}

// ---------- causal flash attention, swapped-QK^T, in-register P ----------
// grid (bh=32, y=32); qt = balance-remap(y) so co-resident blocks' work sums constant.
__global__ __launch_bounds__(256, 4) void attn_fwd(const u16* __restrict__ QKV,
            const u16* __restrict__ Vt, u16* __restrict__ Out){
  const int bh = blockIdx.x;
  const int y = blockIdx.y;
  // quadruples {y, 23-y, y, 55-y} over y0,y0+8,y0+16,y0+24: qt-sum = 62 (uniform CU load)
  const int qt = (y < 8) ? y : (y < 16) ? 23 - y : (y < 24) ? y : 55 - y;
  const int b = bh >> 4, h = bh & 15;
  const int tid = threadIdx.x, wv = tid>>6, ln = tid&63;
  const int lr = ln&15, gq = ln>>4;
  __shared__ u16 KB[2][64*64];
  __shared__ u16 VB[2][64*64];
  const int q0 = qt*64;
  const size_t base = (size_t)(b*2048) * 3072;
  const u16* qrow = QKV + base + (size_t)(q0 + wv*16 + lr)*3072 + h*64;
  bf16x8 qf0 = *(const bf16x8*)(qrow + gq*8);
  bf16x8 qf1 = *(const bf16x8*)(qrow + 32 + gq*8);
  const int qglob = q0 + wv*16 + lr;      // this lane's q (softmax layout)
  f32x4 o[4] = {};
  float m_r = -1e30f, l_r = 0.f;
  const u16* ksrc = QKV + base + 1024 + h*64;
  const u16* vsrc = Vt + (size_t)(bh*64)*2048;
  const float SCL = 0.125f * 1.44269504f;   // scale * log2(e): exp2 domain

  const int c0a = (0*4+wv)*64 + ln, c1a = (1*4+wv)*64 + ln;
  const int r0 = c0a>>3, sc0 = ((c0a&7) ^ (r0&7))*8;
  const int r1 = c1a>>3, sc1 = ((c1a&7) ^ (r1&7))*8;

  #define STAGE(bb, kt2) do { \
    int kv0s = (kt2)*64; \
    gll16(ksrc + (size_t)(kv0s+r0)*3072 + sc0, &KB[bb][(0*4+wv)*512]); \
    gll16(vsrc + (size_t)r0*2048 + kv0s + sc0, &VB[bb][(0*4+wv)*512]); \
    gll16(ksrc + (size_t)(kv0s+r1)*3072 + sc1, &KB[bb][(1*4+wv)*512]); \
    gll16(vsrc + (size_t)r1*2048 + kv0s + sc1, &VB[bb][(1*4+wv)*512]); \
  } while(0)

  STAGE(0, 0);
  __syncthreads();
  int buf = 0;

  for (int kt=0; kt<=qt; ++kt){
    if (kt < qt) STAGE(buf^1, kt+1);
    const int kv0 = kt*64;
    // S^T = K Q^T : col=lane&15=q, row k = kv0 + nt*16 + 4*gq + r
    f32x4 s4[4] = {};
    __builtin_amdgcn_s_setprio(1);
    #pragma unroll
    for (int nt=0;nt<4;++nt){
      int row = nt*16 + lr;
      int sw = (row&7)<<4;
      const char* kb = (const char*)&KB[buf][row*64];
      bf16x8 k0 = *(const bf16x8*)(kb + ((gq*16) ^ sw));
      bf16x8 k1 = *(const bf16x8*)(kb + ((64 + gq*16) ^ sw));
      s4[nt] = __builtin_amdgcn_mfma_f32_16x16x32_bf16(k0, qf0, s4[nt], 0,0,0);
      s4[nt] = __builtin_amdgcn_mfma_f32_16x16x32_bf16(k1, qf1, s4[nt], 0,0,0);
    }
    __builtin_amdgcn_s_setprio(0);
    // scale (exp2 domain) + causal mask + per-q (lane) max
    float mloc = -1e30f;
    #pragma unroll
    for (int nt=0;nt<4;++nt){
      #pragma unroll
      for (int r=0;r<4;++r){
        float v = s4[nt][r]*SCL;
        if (kt==qt){ int k = kv0 + nt*16 + 4*gq + r; if (k > qglob) v = -1e30f; }
        s4[nt][r] = v;
        mloc = fmaxf(mloc, v);
      }
    }
    mloc = fmaxf(mloc, __shfl_xor(mloc, 16));
    mloc = fmaxf(mloc, __shfl_xor(mloc, 32));
    // T13 defer-max: only rescale when max grew materially (P stays <= 2^8)
    if (__any(mloc > m_r + 8.0f)){
      float mn = fmaxf(m_r, mloc);
      float alpha = __builtin_amdgcn_exp2f(m_r - mn);
      m_r = mn; l_r *= alpha;
      float a_o[4];
      #pragma unroll
      for (int r=0;r<4;++r) a_o[r] = __shfl(alpha, 4*gq + r);
      #pragma unroll
      for (int dt=0;dt<4;++dt)
        #pragma unroll
        for (int r=0;r<4;++r) o[dt][r] *= a_o[r];
    }
    // P = exp2(S-m), pack into A-fragments (lane-local, zero cross-lane)
    float rs = 0.f;
    u32 w[2][4];
    #pragma unroll
    for (int c=0;c<2;++c){
      float pv[8];
      #pragma unroll
      for (int u=0;u<4;++u){
        pv[u]   = __builtin_amdgcn_exp2f(s4[2*c  ][u] - m_r);
        pv[4+u] = __builtin_amdgcn_exp2f(s4[2*c+1][u] - m_r);
      }
      #pragma unroll
      for (int u=0;u<8;++u) rs += pv[u];
      w[c][0] = pack2(pv[0], pv[1]);
      w[c][1] = pack2(pv[2], pv[3]);
      w[c][2] = pack2(pv[4], pv[5]);
      w[c][3] = pack2(pv[6], pv[7]);
    }
    rs += __shfl_xor(rs, 16);
    rs += __shfl_xor(rs, 32);
    l_r += rs;
    // O += P V  (V fragments contiguous thanks to permuted Vt layout)
    __builtin_amdgcn_s_setprio(1);
    #pragma unroll
    for (int c=0;c<2;++c){
      union { u32 u[4]; bf16x8 v; } pa;
      pa.u[0]=w[c][0]; pa.u[1]=w[c][1]; pa.u[2]=w[c][2]; pa.u[3]=w[c][3];
      #pragma unroll
      for (int dt=0;dt<4;++dt){
        int row = dt*16 + lr;
        int sw = (row&7)<<4;
        const char* vb0 = (const char*)&VB[buf][row*64];
        bf16x8 vb = *(const bf16x8*)(vb0 + ((c*64 + gq*16) ^ sw));
        o[dt] = __builtin_amdgcn_mfma_f32_16x16x32_bf16(pa.v, vb, o[dt], 0,0,0);
      }
    }
    __builtin_amdgcn_s_setprio(0);
    __syncthreads();
    buf ^= 1;
  }
  // epilogue
  float l_o[4];
  #pragma unroll
  for (int r=0;r<4;++r) l_o[r] = __shfl(l_r, 4*gq + r);
  #pragma unroll
  for (int dt=0;dt<4;++dt){
    #pragma unroll
    for (int r=0;r<4;++r){
      float v = o[dt][r] / l_o[r];
      Out[(size_t)(b*2048 + q0 + wv*16 + 4*gq + r)*1024 + h*64 + dt*16 + lr] = f2bf(v);
    }
  }
}

// ---------- workspace layout (bytes) ----------
#define WS_WK   0u
#define WS_WV   16384u
#define WS_B2   32768u
#define WS_WT   49152u                               // 3072*1024*2 = 6291456
#define WS_W2T  (WS_WT + 6291456u)                   // 1024*1024*2 = 2097152
#define WS_XB   (WS_W2T + 2097152u)                  // 4096*1024*2 = 8388608 (reused as Vt)
#define WS_QKV  (WS_XB + 8388608u)                   // 4096*3072*2 = 25165824
#define WS_ATT  (WS_QKV + 25165824u)                 // 4096*1024*2 = 8388608

extern "C" void kernel_launch(void* const* d_in, const int* in_sizes, int n_in,
                              void* d_out, int out_size, void* d_ws, size_t ws_size,
                              hipStream_t stream) {
  const float* x  = (const float*)d_in[0];
  const float* Wa = (const float*)d_in[1];
  const float* ba = (const float*)d_in[2];
  const float* Wp = (const float*)d_in[3];
  const float* bp = (const float*)d_in[4];
  const float* kc = (const float*)d_in[5];
  const float* ke = (const float*)d_in[6];
  const float* vc = (const float*)d_in[7];
  const float* ve = (const float*)d_in[8];
  float* out = (float*)d_out;
  char* ws = (char*)d_ws;
  float* Wk  = (float*)(ws + WS_WK);
  float* Wv  = (float*)(ws + WS_WV);
  float* b2  = (float*)(ws + WS_B2);
  u16* Wt    = (u16*)(ws + WS_WT);
  u16* W2t   = (u16*)(ws + WS_W2T);
  u16* Xb    = (u16*)(ws + WS_XB);
  u16* QKVb  = (u16*)(ws + WS_QKV);
  u16* Att   = (u16*)(ws + WS_ATT);
  u16* Vt    = Xb;   // Xb dead after gemm1; reuse as Vt

  prep_wkv<<<32, 256, 0, stream>>>(kc, ke, vc, ve, Wk, Wv);
  prep_bias<<<12, 256, 0, stream>>>(ba, Wk, Wv, b2);
  prep_fold<<<256, 256, 0, stream>>>(Wa, Wk, Wv, Wt);
  transpose_cvt<<<dim3(16,16), 256, 0, stream>>>(Wa, 3072, Wt, 1024);   // Q part (n<1024)
  transpose_cvt<<<dim3(16,16), 256, 0, stream>>>(Wp, 1024, W2t, 1024);  // proj weight
  convert_x<<<4096, 256, 0, stream>>>(x, Xb, 1048576);
  gemm_bt<u16><<<dim3(32,24), 256, 0, stream>>>(Xb, Wt, b2, QKVb, 4096, 3072, 1024, 3072);
  v_transpose<<<dim3(32,32), 256, 0, stream>>>(QKVb, Vt);
  attn_fwd<<<dim3(32,32), 256, 0, stream>>>(QKVb, Vt, Att);
  gemm_bt<float><<<dim3(32,8), 256, 0, stream>>>(Att, W2t, bp, out, 4096, 1024, 1024, 1024);
}

// Round 5
// 143.471 us; speedup vs baseline: 1.7600x; 1.1561x over previous
//
#include <hip/hip_runtime.h>
#include <cstddef>

typedef __attribute__((ext_vector_type(8))) __bf16 bf16x8;
typedef __attribute__((ext_vector_type(4))) float f32x4;
typedef unsigned short u16;
typedef unsigned int   u32;

// ---------- helpers ----------
__device__ __forceinline__ u16 f2bf(float f){
  union { float f; u32 u; } v; v.f = f;
  u32 r = v.u + 0x7FFFu + ((v.u >> 16) & 1u);   // RNE
  return (u16)(r >> 16);
}
__device__ __forceinline__ u32 pack2(float a, float b){
  return (u32)f2bf(a) | ((u32)f2bf(b) << 16);
}

__device__ __forceinline__ void gll16(const void* g, void* l){
  __builtin_amdgcn_global_load_lds((__attribute__((address_space(1))) void*)g,
                                   (__attribute__((address_space(3))) void*)l, 16, 0, 0);
}

#define BARRIER() asm volatile("s_barrier" ::: "memory")
#define WAITL0()  asm volatile("s_waitcnt lgkmcnt(0)" ::: "memory")
#define WAITV4()  asm volatile("s_waitcnt vmcnt(4)" ::: "memory")

// ---------- prep: Wk = wk_c @ wk_e (64x64), Wv likewise ----------
__global__ void prep_wkv(const float* __restrict__ kc, const float* __restrict__ ke,
                         const float* __restrict__ vc, const float* __restrict__ ve,
                         float* __restrict__ Wk, float* __restrict__ Wv){
  int p = blockIdx.x & 1, chunk = blockIdx.x >> 1;
  const float* cm = p ? vc : kc;
  const float* em = p ? ve : ke;
  float* om = p ? Wv : Wk;
  int idx = chunk*256 + threadIdx.x;     // 0..4095
  int d = idx >> 6, j = idx & 63;
  float acc = 0.f;
  #pragma unroll
  for (int r=0;r<32;++r) acc += cm[d*32+r]*em[r*64+j];
  om[idx] = acc;
}

// ---------- prep: folded bias b2[3072] ----------
__global__ void prep_bias(const float* __restrict__ b, const float* __restrict__ Wk,
                          const float* __restrict__ Wv, float* __restrict__ b2){
  int n = blockIdx.x*256 + threadIdx.x;
  if (n >= 3072) return;
  if (n < 1024) { b2[n] = b[n]; return; }
  int rem = n - 1024;
  int p = rem >> 10; rem &= 1023;
  int h = rem >> 6, j = rem & 63;
  const float* Wm = p ? Wv : Wk;
  const float* bs = b + 1024 + p*1024 + h*64;
  float acc = 0.f;
  #pragma unroll
  for (int d=0;d<64;++d) acc += bs[d]*Wm[d*64+j];
  b2[n] = acc;
}

// ---------- prep: fold K/V expansion into attn weights (transposed, bf16) ----------
__global__ __launch_bounds__(256) void prep_fold(const float* __restrict__ W,
            const float* __restrict__ Wk, const float* __restrict__ Wv,
            u16* __restrict__ Wt){
  __shared__ float WkL[64*64];     // permuted: [d][ (j&1)*32 + (j>>1) ]
  int p = blockIdx.x >> 7, h = (blockIdx.x >> 3) & 15, ct = blockIdx.x & 7;
  const float* Wm = p ? Wv : Wk;
  int tid = threadIdx.x;
  #pragma unroll
  for (int t=0;t<16;++t){
    int idx = tid + t*256;
    int d = idx >> 6, j = idx & 63;
    WkL[d*64 + (j&1)*32 + (j>>1)] = Wm[idx];
  }
  __syncthreads();
  int cw = tid & 127, jh = tid >> 7;        // jh in {0,1}
  int c0 = ct*128;
  int coloff = 1024 + p*1024 + h*64;
  const float* wrow = W + (size_t)(c0+cw)*3072 + coloff;
  float acc[32];
  #pragma unroll
  for (int i=0;i<32;++i) acc[i]=0.f;
  for (int d=0; d<64; ++d){
    float wvv = wrow[d];
    const float4* col = (const float4*)&WkL[d*64 + jh*32];
    #pragma unroll
    for (int q=0;q<8;++q){
      float4 cv = col[q];
      acc[q*4+0] += wvv*cv.x;
      acc[q*4+1] += wvv*cv.y;
      acc[q*4+2] += wvv*cv.z;
      acc[q*4+3] += wvv*cv.w;
    }
  }
  int nbase = 1024 + p*1024 + h*64;
  #pragma unroll
  for (int i=0;i<32;++i){
    int j = jh + 2*i;
    Wt[(size_t)(nbase + j)*1024 + c0 + cw] = f2bf(acc[i]);
  }
}

// ---------- prep: transpose+convert fp32 [1024 x ld] -> bf16 ----------
__global__ __launch_bounds__(256) void transpose_cvt(const float* __restrict__ src, int ld_src,
            u16* __restrict__ dst, int ld_dst){
  __shared__ float tile[64][65];
  int c0 = blockIdx.x*64, n0 = blockIdx.y*64;
  int tx = threadIdx.x & 63, ty = threadIdx.x >> 6;  // ty 0..3
  #pragma unroll 4
  for (int k=0;k<16;++k){
    int r = 4*k + ty;
    tile[r][tx] = src[(size_t)(c0+r)*ld_src + n0 + tx];
  }
  __syncthreads();
  #pragma unroll 4
  for (int k=0;k<16;++k){
    int r = 4*k + ty;
    dst[(size_t)(n0+r)*ld_dst + c0 + tx] = f2bf(tile[tx][r]);
  }
}

// ---------- prep: x fp32 -> bf16 ----------
__global__ void convert_x(const float* __restrict__ x, u16* __restrict__ o, int n4){
  int i = blockIdx.x*blockDim.x + threadIdx.x;
  if (i >= n4) return;
  float4 v = ((const float4*)x)[i];
  ushort4 r; r.x = f2bf(v.x); r.y = f2bf(v.y); r.z = f2bf(v.z); r.w = f2bf(v.w);
  ((ushort4*)o)[i] = r;
}

// ---------- V transpose: QKV V-part -> Vt[bh*64+d][t], k-slot-permuted per 32-block ----------
__global__ __launch_bounds__(256) void v_transpose(const u16* __restrict__ QKV, u16* __restrict__ Vt){
  __shared__ u16 tile[64][72];   // [t][d]
  int tt = blockIdx.x, bh = blockIdx.y;
  int b = bh >> 4, h = bh & 15;
  int tid = threadIdx.x;
  int r = tid >> 2, cc = (tid & 3)*16;
  const u16* src = QKV + (size_t)(b*2048 + tt*64 + r)*3072 + 2048 + h*64 + cc;
  *(uint4*)&tile[r][cc]     = *(const uint4*)src;
  *(uint4*)&tile[r][cc + 8] = *(const uint4*)(src + 8);
  __syncthreads();
  int d = tid >> 2, pc = (tid & 3)*16;
  u16 vals[16];
  #pragma unroll
  for (int i=0;i<16;++i){
    int p = pc + i;
    int c = p >> 5, q = p & 31, g = q >> 3, j = q & 7;
    int o = 16*(j>>2) + 4*g + (j&3);
    vals[i] = tile[c*32 + o][d];
  }
  u16* drow = Vt + (size_t)(bh*64 + d)*2048 + tt*64 + pc;
  *(uint4*)drow       = *(const uint4*)&vals[0];
  *(uint4*)(drow + 8) = *(const uint4*)&vals[8];
}

// ---------- 256x256 8-phase bf16 GEMM (T2+T3+T4+T5), C = A * Bt^T + bias ----------
// 512 thr = 8 waves (2M x 4N); BK=64; LDS 128 KiB; vmcnt(4) at P4/P8 only.
// LDS halves: A0=rows0-127,A1=128-255 of M-tile; B0/B1 same over N-tile.
// Swizzle: colb' = colb ^ ((row&7)<<4), both sides (linear gll16 dest + pre-swizzled src).
#define STG(ab, buf, h, kt) do { \
    const u16* _g = ((ab) ? gB : gA) + (size_t)((h)*128)*K + (size_t)(kt)*64; \
    gll16(_g + (size_t)((0*8+w)*8+srow)*K, &SH[ab][buf][h][(0*8+w)*512]); \
    gll16(_g + (size_t)((1*8+w)*8+srow)*K, &SH[ab][buf][h][(1*8+w)*512]); \
  } while(0)
#define RDA(buf, h) do { const char* _b = (const char*)&SH[0][buf][h][0]; \
    _Pragma("unroll") for (int ii=0; ii<4; ++ii){ \
      const char* _r = _b + (ii*32 + wm*16 + lr)*128; \
      aF[ii][0] = *(const bf16x8*)(_r + cswz0); \
      aF[ii][1] = *(const bf16x8*)(_r + (cswz0 ^ 64)); } \
  } while(0)
#define RDB(buf, h, BF) do { const char* _b = (const char*)&SH[1][buf][h][0]; \
    _Pragma("unroll") for (int jj=0; jj<2; ++jj){ \
      const char* _r = _b + (jj*64 + wn*16 + lr)*128; \
      BF[jj][0] = *(const bf16x8*)(_r + cswz0); \
      BF[jj][1] = *(const bf16x8*)(_r + (cswz0 ^ 64)); } \
  } while(0)
#define QUAD(mh, bh, BF) do { \
    _Pragma("unroll") for (int ii=0; ii<4; ++ii) \
    _Pragma("unroll") for (int jj=0; jj<2; ++jj) \
    _Pragma("unroll") for (int ks=0; ks<2; ++ks) \
      acc[(mh)*4+ii][(bh)*2+jj] = __builtin_amdgcn_mfma_f32_16x16x32_bf16( \
          aF[ii][ks], BF[jj][ks], acc[(mh)*4+ii][(bh)*2+jj], 0,0,0); \
  } while(0)

__global__ __launch_bounds__(512, 2) void gemm256(const u16* __restrict__ Ag, const u16* __restrict__ Bg,
        const float* __restrict__ bias, u16* __restrict__ C, int M, int N, int K, int ldc){
  __shared__ u16 SH[2][2][2][8192];   // [ab][buf][half][128*64]
  const int nwg = gridDim.x * gridDim.y;
  const int id  = blockIdx.x + gridDim.x * blockIdx.y;
  const int nid = (id & 7) * (nwg >> 3) + (id >> 3);   // nwg % 8 == 0
  const int bx = nid % gridDim.x, by = nid / gridDim.x;
  const int m0 = bx*256, n0 = by*256;
  const int tid = threadIdx.x, w = tid>>6, ln = tid&63;
  const int wm = w>>2, wn = w&3;
  const int lr = ln&15, gq = ln>>4;
  const int srow = ln>>3;                 // 0..7
  const int ce = ((ln&7) ^ srow) * 8;     // pre-swizzled source col (elements)
  const int cswz0 = (gq*16) ^ ((lr&7)<<4);
  const int NKT = K >> 6;                 // 16

  f32x4 acc[8][4] = {};
  bf16x8 aF[4][2], bF0[2][2], bF1[2][2];

  const u16* gA = Ag + (size_t)m0*K + ce;
  const u16* gB = Bg + (size_t)n0*K + ce;

  // prologue: buf0 <- tile0 (A0,B0,B1,A1); buf1 <- tile1 (A0',B0')
  STG(0,0,0,0); STG(1,0,0,0); STG(1,0,1,0); STG(0,0,1,0);
  STG(0,1,0,1); STG(1,1,0,1);
  WAITV4();            // completes all of buf0; A0',B0' stay in flight
  BARRIER();

  for (int it = 0; it < (NKT>>1); ++it){
    const int t1 = 2*it+1;
    const int t2 = (2*it+2 < NKT) ? 2*it+2 : NKT-1;   // tail: clamp (never read)
    const int t3 = (2*it+3 < NKT) ? 2*it+3 : NKT-1;
    // P1: read buf0.A0 + buf0.B0 (12 ds_reads); stage buf1.B1(t1)
    RDA(0,0); RDB(0,0,bF0); STG(1,1,1,t1);
    BARRIER(); WAITL0();
    __builtin_amdgcn_s_setprio(1); QUAD(0,0,bF0); __builtin_amdgcn_s_setprio(0);
    BARRIER();
    // P2: read buf0.B1; stage buf1.A1(t1)
    RDB(0,1,bF1); STG(0,1,1,t1);
    BARRIER(); WAITL0();
    __builtin_amdgcn_s_setprio(1); QUAD(0,1,bF1); __builtin_amdgcn_s_setprio(0);
    BARRIER();
    // P3: read buf0.A1; stage buf0.A0(t2)
    RDA(0,1); STG(0,0,0,t2);
    BARRIER(); WAITL0();
    __builtin_amdgcn_s_setprio(1); QUAD(1,0,bF0); __builtin_amdgcn_s_setprio(0);
    BARRIER();
    // P4: stage buf0.B0(t2); vmcnt(4) -> all of buf1 tile t1 landed
    STG(1,0,0,t2);
    BARRIER();
    __builtin_amdgcn_s_setprio(1); QUAD(1,1,bF1); __builtin_amdgcn_s_setprio(0);
    WAITV4();
    BARRIER();
    // P5: read buf1.A0 + buf1.B0; stage buf0.B1(t2)
    RDA(1,0); RDB(1,0,bF0); STG(1,0,1,t2);
    BARRIER(); WAITL0();
    __builtin_amdgcn_s_setprio(1); QUAD(0,0,bF0); __builtin_amdgcn_s_setprio(0);
    BARRIER();
    // P6: read buf1.B1; stage buf0.A1(t2)
    RDB(1,1,bF1); STG(0,0,1,t2);
    BARRIER(); WAITL0();
    __builtin_amdgcn_s_setprio(1); QUAD(0,1,bF1); __builtin_amdgcn_s_setprio(0);
    BARRIER();
    // P7: read buf1.A1; stage buf1.A0(t3)
    RDA(1,1); STG(0,1,0,t3);
    BARRIER(); WAITL0();
    __builtin_amdgcn_s_setprio(1); QUAD(1,0,bF0); __builtin_amdgcn_s_setprio(0);
    BARRIER();
    // P8: stage buf1.B0(t3); vmcnt(4) -> all of buf0 tile t2 landed
    STG(1,1,0,t3);
    BARRIER();
    __builtin_amdgcn_s_setprio(1); QUAD(1,1,bF1); __builtin_amdgcn_s_setprio(0);
    WAITV4();
    BARRIER();
  }

  // epilogue: frag (i,j): rows m0 + i*32 + wm*16 + 4*gq + rr, col n0 + j*64 + wn*16 + lr
  #pragma unroll
  for (int j=0;j<4;++j){
    int col = n0 + j*64 + wn*16 + lr;
    float bv = bias[col];
    #pragma unroll
    for (int i=0;i<8;++i){
      int row = m0 + i*32 + wm*16 + 4*gq;
      #pragma unroll
      for (int rr=0;rr<4;++rr)
        C[(size_t)(row+rr)*ldc + col] = f2bf(acc[i][j][rr] + bv);
    }
  }
}

// ---------- 128x128 bf16 GEMM (2-phase) for the small N=1024 proj ----------
template<typename OT>
__global__ __launch_bounds__(256) void gemm_bt(const u16* __restrict__ A, const u16* __restrict__ Bt,
        const float* __restrict__ bias, OT* __restrict__ C, int M, int N, int K, int ldc){
  __shared__ u16 As[128*64];
  __shared__ u16 Bs[128*64];
  const int nwg = gridDim.x * gridDim.y;
  const int id  = blockIdx.x + gridDim.x * blockIdx.y;
  const int nid = (id & 7) * (nwg >> 3) + (id >> 3);
  const int bx = nid % gridDim.x, by = nid / gridDim.x;
  const int tid = threadIdx.x, wv = tid>>6, ln = tid&63;
  const int lr = ln&15, g8 = (ln>>4)*8;
  const int m0 = bx*128, n0 = by*128;
  const int wr = (wv>>1)*64, wc = (wv&1)*64;
  f32x4 acc[4][4] = {};
  const int nk = K >> 6;
  for (int kt=0; kt<nk; ++kt){
    #pragma unroll
    for (int it=0; it<4; ++it){
      int chunk = wv*4+it;
      int row = chunk*8 + (ln>>3), colc = (ln&7)*8;
      gll16(A  + (size_t)(m0+row)*K + kt*64 + colc, &As[chunk*512]);
      gll16(Bt + (size_t)(n0+row)*K + kt*64 + colc, &Bs[chunk*512]);
    }
    __syncthreads();
    #pragma unroll
    for (int ks=0; ks<2; ++ks){
      bf16x8 af[4], bfr[4];
      #pragma unroll
      for (int mt=0;mt<4;++mt) af[mt]  = *(const bf16x8*)&As[(wr+mt*16+lr)*64 + ks*32 + g8];
      #pragma unroll
      for (int nt=0;nt<4;++nt) bfr[nt] = *(const bf16x8*)&Bs[(wc+nt*16+lr)*64 + ks*32 + g8];
      #pragma unroll
      for (int mt=0;mt<4;++mt)
        #pragma unroll
        for (int nt=0;nt<4;++nt)
          acc[mt][nt] = __builtin_amdgcn_mfma_f32_16x16x32_bf16(af[mt], bfr[nt], acc[mt][nt], 0,0,0);
    }
    __syncthreads();
  }
  #pragma unroll
  for (int mt=0;mt<4;++mt){
    int row = m0 + wr + mt*16 + 4*(ln>>4);
    #pragma unroll
    for (int nt=0;nt<4;++nt){
      int col = n0 + wc + nt*16 + lr;
      float bv = bias[col];
      #pragma unroll
      for (int r=0;r<4;++r){
        float v = acc[mt][nt][r] + bv;
        if constexpr (sizeof(OT) == 2) C[(size_t)(row+r)*ldc + col] = f2bf(v);
        else                           C[(size_t)(row+r)*ldc + col] = v;
      }
    }
  }
}

// ---------- causal flash attention, swapped-QK^T, in-register P ----------
__global__ __launch_bounds__(256, 4) void attn_fwd(const u16* __restrict__ QKV,
            const u16* __restrict__ Vt, u16* __restrict__ Out){
  const int bh = blockIdx.x;
  const int y = blockIdx.y;
  const int qt = (y < 8) ? y : (y < 16) ? 23 - y : (y < 24) ? y : 55 - y;
  const int b = bh >> 4, h = bh & 15;
  const int tid = threadIdx.x, wv = tid>>6, ln = tid&63;
  const int lr = ln&15, gq = ln>>4;
  __shared__ u16 KB[2][64*64];
  __shared__ u16 VB[2][64*64];
  const int q0 = qt*64;
  const size_t base = (size_t)(b*2048) * 3072;
  const u16* qrow = QKV + base + (size_t)(q0 + wv*16 + lr)*3072 + h*64;
  bf16x8 qf0 = *(const bf16x8*)(qrow + gq*8);
  bf16x8 qf1 = *(const bf16x8*)(qrow + 32 + gq*8);
  const int qglob = q0 + wv*16 + lr;
  f32x4 o[4] = {};
  float m_r = -1e30f, l_r = 0.f;
  const u16* ksrc = QKV + base + 1024 + h*64;
  const u16* vsrc = Vt + (size_t)(bh*64)*2048;
  const float SCL = 0.125f * 1.44269504f;

  const int c0a = (0*4+wv)*64 + ln, c1a = (1*4+wv)*64 + ln;
  const int r0 = c0a>>3, sc0 = ((c0a&7) ^ (r0&7))*8;
  const int r1 = c1a>>3, sc1 = ((c1a&7) ^ (r1&7))*8;

  #define STAGEA(bb, kt2) do { \
    int kv0s = (kt2)*64; \
    gll16(ksrc + (size_t)(kv0s+r0)*3072 + sc0, &KB[bb][(0*4+wv)*512]); \
    gll16(vsrc + (size_t)r0*2048 + kv0s + sc0, &VB[bb][(0*4+wv)*512]); \
    gll16(ksrc + (size_t)(kv0s+r1)*3072 + sc1, &KB[bb][(1*4+wv)*512]); \
    gll16(vsrc + (size_t)r1*2048 + kv0s + sc1, &VB[bb][(1*4+wv)*512]); \
  } while(0)

  STAGEA(0, 0);
  __syncthreads();
  int buf = 0;

  for (int kt=0; kt<=qt; ++kt){
    if (kt < qt) STAGEA(buf^1, kt+1);
    const int kv0 = kt*64;
    f32x4 s4[4] = {};
    __builtin_amdgcn_s_setprio(1);
    #pragma unroll
    for (int nt=0;nt<4;++nt){
      int row = nt*16 + lr;
      int sw = (row&7)<<4;
      const char* kb = (const char*)&KB[buf][row*64];
      bf16x8 k0 = *(const bf16x8*)(kb + ((gq*16) ^ sw));
      bf16x8 k1 = *(const bf16x8*)(kb + ((64 + gq*16) ^ sw));
      s4[nt] = __builtin_amdgcn_mfma_f32_16x16x32_bf16(k0, qf0, s4[nt], 0,0,0);
      s4[nt] = __builtin_amdgcn_mfma_f32_16x16x32_bf16(k1, qf1, s4[nt], 0,0,0);
    }
    __builtin_amdgcn_s_setprio(0);
    float mloc = -1e30f;
    #pragma unroll
    for (int nt=0;nt<4;++nt){
      #pragma unroll
      for (int r=0;r<4;++r){
        float v = s4[nt][r]*SCL;
        if (kt==qt){ int k = kv0 + nt*16 + 4*gq + r; if (k > qglob) v = -1e30f; }
        s4[nt][r] = v;
        mloc = fmaxf(mloc, v);
      }
    }
    mloc = fmaxf(mloc, __shfl_xor(mloc, 16));
    mloc = fmaxf(mloc, __shfl_xor(mloc, 32));
    if (__any(mloc > m_r + 8.0f)){
      float mn = fmaxf(m_r, mloc);
      float alpha = __builtin_amdgcn_exp2f(m_r - mn);
      m_r = mn; l_r *= alpha;
      float a_o[4];
      #pragma unroll
      for (int r=0;r<4;++r) a_o[r] = __shfl(alpha, 4*gq + r);
      #pragma unroll
      for (int dt=0;dt<4;++dt)
        #pragma unroll
        for (int r=0;r<4;++r) o[dt][r] *= a_o[r];
    }
    float rs = 0.f;
    u32 wkk[2][4];
    #pragma unroll
    for (int c=0;c<2;++c){
      float pv[8];
      #pragma unroll
      for (int u=0;u<4;++u){
        pv[u]   = __builtin_amdgcn_exp2f(s4[2*c  ][u] - m_r);
        pv[4+u] = __builtin_amdgcn_exp2f(s4[2*c+1][u] - m_r);
      }
      #pragma unroll
      for (int u=0;u<8;++u) rs += pv[u];
      wkk[c][0] = pack2(pv[0], pv[1]);
      wkk[c][1] = pack2(pv[2], pv[3]);
      wkk[c][2] = pack2(pv[4], pv[5]);
      wkk[c][3] = pack2(pv[6], pv[7]);
    }
    rs += __shfl_xor(rs, 16);
    rs += __shfl_xor(rs, 32);
    l_r += rs;
    __builtin_amdgcn_s_setprio(1);
    #pragma unroll
    for (int c=0;c<2;++c){
      union { u32 u[4]; bf16x8 v; } pa;
      pa.u[0]=wkk[c][0]; pa.u[1]=wkk[c][1]; pa.u[2]=wkk[c][2]; pa.u[3]=wkk[c][3];
      #pragma unroll
      for (int dt=0;dt<4;++dt){
        int row = dt*16 + lr;
        int sw = (row&7)<<4;
        const char* vb0 = (const char*)&VB[buf][row*64];
        bf16x8 vb = *(const bf16x8*)(vb0 + ((c*64 + gq*16) ^ sw));
        o[dt] = __builtin_amdgcn_mfma_f32_16x16x32_bf16(pa.v, vb, o[dt], 0,0,0);
      }
    }
    __builtin_amdgcn_s_setprio(0);
    __syncthreads();
    buf ^= 1;
  }
  float l_o[4];
  #pragma unroll
  for (int r=0;r<4;++r) l_o[r] = __shfl(l_r, 4*gq + r);
  #pragma unroll
  for (int dt=0;dt<4;++dt){
    #pragma unroll
    for (int r=0;r<4;++r){
      float v = o[dt][r] / l_o[r];
      Out[(size_t)(b*2048 + q0 + wv*16 + 4*gq + r)*1024 + h*64 + dt*16 + lr] = f2bf(v);
    }
  }
}

// ---------- workspace layout (bytes) ----------
#define WS_WK   0u
#define WS_WV   16384u
#define WS_B2   32768u
#define WS_WT   49152u                               // 3072*1024*2 = 6291456
#define WS_W2T  (WS_WT + 6291456u)                   // 1024*1024*2 = 2097152
#define WS_XB   (WS_W2T + 2097152u)                  // 4096*1024*2 = 8388608 (reused as Vt)
#define WS_QKV  (WS_XB + 8388608u)                   // 4096*3072*2 = 25165824
#define WS_ATT  (WS_QKV + 25165824u)                 // 4096*1024*2 = 8388608

extern "C" void kernel_launch(void* const* d_in, const int* in_sizes, int n_in,
                              void* d_out, int out_size, void* d_ws, size_t ws_size,
                              hipStream_t stream) {
  const float* x  = (const float*)d_in[0];
  const float* Wa = (const float*)d_in[1];
  const float* ba = (const float*)d_in[2];
  const float* Wp = (const float*)d_in[3];
  const float* bp = (const float*)d_in[4];
  const float* kc = (const float*)d_in[5];
  const float* ke = (const float*)d_in[6];
  const float* vc = (const float*)d_in[7];
  const float* ve = (const float*)d_in[8];
  float* out = (float*)d_out;
  char* ws = (char*)d_ws;
  float* Wk  = (float*)(ws + WS_WK);
  float* Wv  = (float*)(ws + WS_WV);
  float* b2  = (float*)(ws + WS_B2);
  u16* Wt    = (u16*)(ws + WS_WT);
  u16* W2t   = (u16*)(ws + WS_W2T);
  u16* Xb    = (u16*)(ws + WS_XB);
  u16* QKVb  = (u16*)(ws + WS_QKV);
  u16* Att   = (u16*)(ws + WS_ATT);
  u16* Vt    = Xb;   // Xb dead after gemm1; reuse as Vt

  prep_wkv<<<32, 256, 0, stream>>>(kc, ke, vc, ve, Wk, Wv);
  prep_bias<<<12, 256, 0, stream>>>(ba, Wk, Wv, b2);
  prep_fold<<<256, 256, 0, stream>>>(Wa, Wk, Wv, Wt);
  transpose_cvt<<<dim3(16,16), 256, 0, stream>>>(Wa, 3072, Wt, 1024);   // Q part (n<1024)
  transpose_cvt<<<dim3(16,16), 256, 0, stream>>>(Wp, 1024, W2t, 1024);  // proj weight
  convert_x<<<4096, 256, 0, stream>>>(x, Xb, 1048576);
  gemm256<<<dim3(16,12), 512, 0, stream>>>(Xb, Wt, b2, QKVb, 4096, 3072, 1024, 3072);
  v_transpose<<<dim3(32,32), 256, 0, stream>>>(QKVb, Vt);
  attn_fwd<<<dim3(32,32), 256, 0, stream>>>(QKVb, Vt, Att);
  gemm_bt<float><<<dim3(32,8), 256, 0, stream>>>(Att, W2t, bp, out, 4096, 1024, 1024, 1024);
}

// Round 6
// 139.833 us; speedup vs baseline: 1.8058x; 1.0260x over previous
//
#include <hip/hip_runtime.h>
#include <cstddef>

typedef __attribute__((ext_vector_type(8))) __bf16 bf16x8;
typedef __attribute__((ext_vector_type(4))) float f32x4;
typedef unsigned short u16;
typedef unsigned int   u32;

// ---------- helpers ----------
__device__ __forceinline__ u16 f2bf(float f){
  union { float f; u32 u; } v; v.f = f;
  u32 r = v.u + 0x7FFFu + ((v.u >> 16) & 1u);   // RNE
  return (u16)(r >> 16);
}
__device__ __forceinline__ u32 pack2(float a, float b){
  return (u32)f2bf(a) | ((u32)f2bf(b) << 16);
}
__device__ __forceinline__ float bf2f(u16 s){
  union { u32 u; float f; } v; v.u = ((u32)s) << 16; return v.f;
}

__device__ __forceinline__ void gll16(const void* g, void* l){
  __builtin_amdgcn_global_load_lds((__attribute__((address_space(1))) void*)g,
                                   (__attribute__((address_space(3))) void*)l, 16, 0, 0);
}

#define BARRIER() asm volatile("s_barrier" ::: "memory")
#define WAITL0()  asm volatile("s_waitcnt lgkmcnt(0)" ::: "memory")
#define WAITV4()  asm volatile("s_waitcnt vmcnt(4)" ::: "memory")

// ---------- prep: Wk = wk_c @ wk_e (64x64), Wv likewise ----------
__global__ void prep_wkv(const float* __restrict__ kc, const float* __restrict__ ke,
                         const float* __restrict__ vc, const float* __restrict__ ve,
                         float* __restrict__ Wk, float* __restrict__ Wv){
  int p = blockIdx.x & 1, chunk = blockIdx.x >> 1;
  const float* cm = p ? vc : kc;
  const float* em = p ? ve : ke;
  float* om = p ? Wv : Wk;
  int idx = chunk*256 + threadIdx.x;     // 0..4095
  int d = idx >> 6, j = idx & 63;
  float acc = 0.f;
  #pragma unroll
  for (int r=0;r<32;++r) acc += cm[d*32+r]*em[r*64+j];
  om[idx] = acc;
}

// ---------- prep: folded bias b2[3072] ----------
__global__ void prep_bias(const float* __restrict__ b, const float* __restrict__ Wk,
                          const float* __restrict__ Wv, float* __restrict__ b2){
  int n = blockIdx.x*256 + threadIdx.x;
  if (n >= 3072) return;
  if (n < 1024) { b2[n] = b[n]; return; }
  int rem = n - 1024;
  int p = rem >> 10; rem &= 1023;
  int h = rem >> 6, j = rem & 63;
  const float* Wm = p ? Wv : Wk;
  const float* bs = b + 1024 + p*1024 + h*64;
  float acc = 0.f;
  #pragma unroll
  for (int d=0;d<64;++d) acc += bs[d]*Wm[d*64+j];
  b2[n] = acc;
}

// ---------- prep: fold K/V expansion into attn weights (transposed, bf16) ----------
__global__ __launch_bounds__(256) void prep_fold(const float* __restrict__ W,
            const float* __restrict__ Wk, const float* __restrict__ Wv,
            u16* __restrict__ Wt){
  __shared__ float WkL[64*64];     // permuted: [d][ (j&1)*32 + (j>>1) ]
  int p = blockIdx.x >> 7, h = (blockIdx.x >> 3) & 15, ct = blockIdx.x & 7;
  const float* Wm = p ? Wv : Wk;
  int tid = threadIdx.x;
  #pragma unroll
  for (int t=0;t<16;++t){
    int idx = tid + t*256;
    int d = idx >> 6, j = idx & 63;
    WkL[d*64 + (j&1)*32 + (j>>1)] = Wm[idx];
  }
  __syncthreads();
  int cw = tid & 127, jh = tid >> 7;        // jh in {0,1}
  int c0 = ct*128;
  int coloff = 1024 + p*1024 + h*64;
  const float* wrow = W + (size_t)(c0+cw)*3072 + coloff;
  float acc[32];
  #pragma unroll
  for (int i=0;i<32;++i) acc[i]=0.f;
  for (int d=0; d<64; ++d){
    float wvv = wrow[d];
    const float4* col = (const float4*)&WkL[d*64 + jh*32];
    #pragma unroll
    for (int q=0;q<8;++q){
      float4 cv = col[q];
      acc[q*4+0] += wvv*cv.x;
      acc[q*4+1] += wvv*cv.y;
      acc[q*4+2] += wvv*cv.z;
      acc[q*4+3] += wvv*cv.w;
    }
  }
  int nbase = 1024 + p*1024 + h*64;
  #pragma unroll
  for (int i=0;i<32;++i){
    int j = jh + 2*i;
    Wt[(size_t)(nbase + j)*1024 + c0 + cw] = f2bf(acc[i]);
  }
}

// ---------- prep: transpose+convert fp32 [1024 x ld] -> bf16 ----------
__global__ __launch_bounds__(256) void transpose_cvt(const float* __restrict__ src, int ld_src,
            u16* __restrict__ dst, int ld_dst){
  __shared__ float tile[64][65];
  int c0 = blockIdx.x*64, n0 = blockIdx.y*64;
  int tx = threadIdx.x & 63, ty = threadIdx.x >> 6;  // ty 0..3
  #pragma unroll 4
  for (int k=0;k<16;++k){
    int r = 4*k + ty;
    tile[r][tx] = src[(size_t)(c0+r)*ld_src + n0 + tx];
  }
  __syncthreads();
  #pragma unroll 4
  for (int k=0;k<16;++k){
    int r = 4*k + ty;
    dst[(size_t)(n0+r)*ld_dst + c0 + tx] = f2bf(tile[tx][r]);
  }
}

// ---------- prep: x fp32 -> bf16 ----------
__global__ void convert_x(const float* __restrict__ x, u16* __restrict__ o, int n4){
  int i = blockIdx.x*blockDim.x + threadIdx.x;
  if (i >= n4) return;
  float4 v = ((const float4*)x)[i];
  ushort4 r; r.x = f2bf(v.x); r.y = f2bf(v.y); r.z = f2bf(v.z); r.w = f2bf(v.w);
  ((ushort4*)o)[i] = r;
}

// ---------- V transpose: QKV V-part -> Vt[bh*64+d][t], k-slot-permuted per 32-block ----------
__global__ __launch_bounds__(256) void v_transpose(const u16* __restrict__ QKV, u16* __restrict__ Vt){
  __shared__ u16 tile[64][72];   // [t][d]
  int tt = blockIdx.x, bh = blockIdx.y;
  int b = bh >> 4, h = bh & 15;
  int tid = threadIdx.x;
  int r = tid >> 2, cc = (tid & 3)*16;
  const u16* src = QKV + (size_t)(b*2048 + tt*64 + r)*3072 + 2048 + h*64 + cc;
  *(uint4*)&tile[r][cc]     = *(const uint4*)src;
  *(uint4*)&tile[r][cc + 8] = *(const uint4*)(src + 8);
  __syncthreads();
  int d = tid >> 2, pc = (tid & 3)*16;
  u16 vals[16];
  #pragma unroll
  for (int i=0;i<16;++i){
    int p = pc + i;
    int c = p >> 5, q = p & 31, g = q >> 3, j = q & 7;
    int o = 16*(j>>2) + 4*g + (j&3);
    vals[i] = tile[c*32 + o][d];
  }
  u16* drow = Vt + (size_t)(bh*64 + d)*2048 + tt*64 + pc;
  *(uint4*)drow       = *(const uint4*)&vals[0];
  *(uint4*)(drow + 8) = *(const uint4*)&vals[8];
}

// ---------- 256x256 8-phase bf16 GEMM (T2+T3+T4+T5), C = A * Bt^T + bias ----------
#define STG(ab, buf, h, kt) do { \
    const u16* _g = ((ab) ? gB : gA) + (size_t)((h)*128)*K + (size_t)(kt)*64; \
    gll16(_g + (size_t)((0*8+w)*8+srow)*K, &SH[ab][buf][h][(0*8+w)*512]); \
    gll16(_g + (size_t)((1*8+w)*8+srow)*K, &SH[ab][buf][h][(1*8+w)*512]); \
  } while(0)
#define RDA(buf, h) do { const char* _b = (const char*)&SH[0][buf][h][0]; \
    _Pragma("unroll") for (int ii=0; ii<4; ++ii){ \
      const char* _r = _b + (ii*32 + wm*16 + lr)*128; \
      aF[ii][0] = *(const bf16x8*)(_r + cswz0); \
      aF[ii][1] = *(const bf16x8*)(_r + (cswz0 ^ 64)); } \
  } while(0)
#define RDB(buf, h, BF) do { const char* _b = (const char*)&SH[1][buf][h][0]; \
    _Pragma("unroll") for (int jj=0; jj<2; ++jj){ \
      const char* _r = _b + (jj*64 + wn*16 + lr)*128; \
      BF[jj][0] = *(const bf16x8*)(_r + cswz0); \
      BF[jj][1] = *(const bf16x8*)(_r + (cswz0 ^ 64)); } \
  } while(0)
#define QUAD(mh, bh, BF) do { \
    _Pragma("unroll") for (int ii=0; ii<4; ++ii) \
    _Pragma("unroll") for (int jj=0; jj<2; ++jj) \
    _Pragma("unroll") for (int ks=0; ks<2; ++ks) \
      acc[(mh)*4+ii][(bh)*2+jj] = __builtin_amdgcn_mfma_f32_16x16x32_bf16( \
          aF[ii][ks], BF[jj][ks], acc[(mh)*4+ii][(bh)*2+jj], 0,0,0); \
  } while(0)

__global__ __launch_bounds__(512, 2) void gemm256(const u16* __restrict__ Ag, const u16* __restrict__ Bg,
        const float* __restrict__ bias, u16* __restrict__ C, int M, int N, int K, int ldc){
  __shared__ u16 SH[2][2][2][8192];   // [ab][buf][half][128*64]
  const int nwg = gridDim.x * gridDim.y;
  const int id  = blockIdx.x + gridDim.x * blockIdx.y;
  const int nid = (id & 7) * (nwg >> 3) + (id >> 3);   // nwg % 8 == 0
  const int bx = nid % gridDim.x, by = nid / gridDim.x;
  const int m0 = bx*256, n0 = by*256;
  const int tid = threadIdx.x, w = tid>>6, ln = tid&63;
  const int wm = w>>2, wn = w&3;
  const int lr = ln&15, gq = ln>>4;
  const int srow = ln>>3;                 // 0..7
  const int ce = ((ln&7) ^ srow) * 8;     // pre-swizzled source col (elements)
  const int cswz0 = (gq*16) ^ ((lr&7)<<4);
  const int NKT = K >> 6;                 // 16

  f32x4 acc[8][4] = {};
  bf16x8 aF[4][2], bF0[2][2], bF1[2][2];

  const u16* gA = Ag + (size_t)m0*K + ce;
  const u16* gB = Bg + (size_t)n0*K + ce;

  STG(0,0,0,0); STG(1,0,0,0); STG(1,0,1,0); STG(0,0,1,0);
  STG(0,1,0,1); STG(1,1,0,1);
  WAITV4();
  BARRIER();

  for (int it = 0; it < (NKT>>1); ++it){
    const int t1 = 2*it+1;
    const int t2 = (2*it+2 < NKT) ? 2*it+2 : NKT-1;
    const int t3 = (2*it+3 < NKT) ? 2*it+3 : NKT-1;
    RDA(0,0); RDB(0,0,bF0); STG(1,1,1,t1);
    BARRIER(); WAITL0();
    __builtin_amdgcn_s_setprio(1); QUAD(0,0,bF0); __builtin_amdgcn_s_setprio(0);
    BARRIER();
    RDB(0,1,bF1); STG(0,1,1,t1);
    BARRIER(); WAITL0();
    __builtin_amdgcn_s_setprio(1); QUAD(0,1,bF1); __builtin_amdgcn_s_setprio(0);
    BARRIER();
    RDA(0,1); STG(0,0,0,t2);
    BARRIER(); WAITL0();
    __builtin_amdgcn_s_setprio(1); QUAD(1,0,bF0); __builtin_amdgcn_s_setprio(0);
    BARRIER();
    STG(1,0,0,t2);
    BARRIER();
    __builtin_amdgcn_s_setprio(1); QUAD(1,1,bF1); __builtin_amdgcn_s_setprio(0);
    WAITV4();
    BARRIER();
    RDA(1,0); RDB(1,0,bF0); STG(1,0,1,t2);
    BARRIER(); WAITL0();
    __builtin_amdgcn_s_setprio(1); QUAD(0,0,bF0); __builtin_amdgcn_s_setprio(0);
    BARRIER();
    RDB(1,1,bF1); STG(0,0,1,t2);
    BARRIER(); WAITL0();
    __builtin_amdgcn_s_setprio(1); QUAD(0,1,bF1); __builtin_amdgcn_s_setprio(0);
    BARRIER();
    RDA(1,1); STG(0,1,0,t3);
    BARRIER(); WAITL0();
    __builtin_amdgcn_s_setprio(1); QUAD(1,0,bF0); __builtin_amdgcn_s_setprio(0);
    BARRIER();
    STG(1,1,0,t3);
    BARRIER();
    __builtin_amdgcn_s_setprio(1); QUAD(1,1,bF1); __builtin_amdgcn_s_setprio(0);
    WAITV4();
    BARRIER();
  }

  #pragma unroll
  for (int j=0;j<4;++j){
    int col = n0 + j*64 + wn*16 + lr;
    float bv = bias[col];
    #pragma unroll
    for (int i=0;i<8;++i){
      int row = m0 + i*32 + wm*16 + 4*gq;
      #pragma unroll
      for (int rr=0;rr<4;++rr)
        C[(size_t)(row+rr)*ldc + col] = f2bf(acc[i][j][rr] + bv);
    }
  }
}

// ---------- 128x128 bf16 GEMM (2-phase) for the small N=1024 proj ----------
template<typename OT>
__global__ __launch_bounds__(256) void gemm_bt(const u16* __restrict__ A, const u16* __restrict__ Bt,
        const float* __restrict__ bias, OT* __restrict__ C, int M, int N, int K, int ldc){
  __shared__ u16 As[128*64];
  __shared__ u16 Bs[128*64];
  const int nwg = gridDim.x * gridDim.y;
  const int id  = blockIdx.x + gridDim.x * blockIdx.y;
  const int nid = (id & 7) * (nwg >> 3) + (id >> 3);
  const int bx = nid % gridDim.x, by = nid / gridDim.x;
  const int tid = threadIdx.x, wv = tid>>6, ln = tid&63;
  const int lr = ln&15, g8 = (ln>>4)*8;
  const int m0 = bx*128, n0 = by*128;
  const int wr = (wv>>1)*64, wc = (wv&1)*64;
  f32x4 acc[4][4] = {};
  const int nk = K >> 6;
  for (int kt=0; kt<nk; ++kt){
    #pragma unroll
    for (int it=0; it<4; ++it){
      int chunk = wv*4+it;
      int row = chunk*8 + (ln>>3), colc = (ln&7)*8;
      gll16(A  + (size_t)(m0+row)*K + kt*64 + colc, &As[chunk*512]);
      gll16(Bt + (size_t)(n0+row)*K + kt*64 + colc, &Bs[chunk*512]);
    }
    __syncthreads();
    #pragma unroll
    for (int ks=0; ks<2; ++ks){
      bf16x8 af[4], bfr[4];
      #pragma unroll
      for (int mt=0;mt<4;++mt) af[mt]  = *(const bf16x8*)&As[(wr+mt*16+lr)*64 + ks*32 + g8];
      #pragma unroll
      for (int nt=0;nt<4;++nt) bfr[nt] = *(const bf16x8*)&Bs[(wc+nt*16+lr)*64 + ks*32 + g8];
      #pragma unroll
      for (int mt=0;mt<4;++mt)
        #pragma unroll
        for (int nt=0;nt<4;++nt)
          acc[mt][nt] = __builtin_amdgcn_mfma_f32_16x16x32_bf16(af[mt], bfr[nt], acc[mt][nt], 0,0,0);
    }
    __syncthreads();
  }
  #pragma unroll
  for (int mt=0;mt<4;++mt){
    int row = m0 + wr + mt*16 + 4*(ln>>4);
    #pragma unroll
    for (int nt=0;nt<4;++nt){
      int col = n0 + wc + nt*16 + lr;
      float bv = bias[col];
      #pragma unroll
      for (int r=0;r<4;++r){
        float v = acc[mt][nt][r] + bv;
        if constexpr (sizeof(OT) == 2) C[(size_t)(row+r)*ldc + col] = f2bf(v);
        else                           C[(size_t)(row+r)*ldc + col] = v;
      }
    }
  }
}

// ---------- causal flash attention: dual kt-stream, in-LDS merge ----------
// grid (bh=32, y=32), qt = 31-y (LPT). 512 thr = 2 subgroups x 4 waves.
// Subgroup sg processes kt ≡ sg (mod 2); partial (m,l,O) merged in LDS at the end.
__global__ __launch_bounds__(512, 4) void attn_fwd(const u16* __restrict__ QKV,
            const u16* __restrict__ Vt, u16* __restrict__ Out){
  const int bh = blockIdx.x;
  const int qt = 31 - blockIdx.y;          // long blocks first (LPT backfill)
  const int b = bh >> 4, h = bh & 15;
  const int tid = threadIdx.x, wv = tid>>6, ln = tid&63;
  const int sg = wv>>2, wvL = wv&3;
  const int lr = ln&15, gq = ln>>4;
  __shared__ __align__(16) char SMEM[65536];
  u16* KBp = (u16*)SMEM;                   // [sg][buf][4096] = 32 KB
  u16* VBp = (u16*)(SMEM + 32768);         // 32 KB
  const int q0 = qt*64;
  const size_t base = (size_t)(b*2048) * 3072;
  const float SCL = 0.125f * 1.44269504f;  // fold into Q once (exp2 domain)

  // Q fragments, pre-scaled by SCL (bf16 re-round: ~1ulp, within margin)
  const u16* qrow = QKV + base + (size_t)(q0 + wvL*16 + lr)*3072 + h*64;
  union { bf16x8 v; u16 s[8]; } uq0, uq1;
  uq0.v = *(const bf16x8*)(qrow + gq*8);
  uq1.v = *(const bf16x8*)(qrow + 32 + gq*8);
  #pragma unroll
  for (int j=0;j<8;++j){ uq0.s[j] = f2bf(bf2f(uq0.s[j])*SCL); uq1.s[j] = f2bf(bf2f(uq1.s[j])*SCL); }
  bf16x8 qf0 = uq0.v, qf1 = uq1.v;
  const int qglob = q0 + wvL*16 + lr;
  f32x4 o[4] = {};
  float m_r = -1e30f, l_r = 0.f;
  const u16* ksrc = QKV + base + 1024 + h*64;
  const u16* vsrc = Vt + (size_t)(bh*64)*2048;

  const int c0a = (0*4+wvL)*64 + ln, c1a = (1*4+wvL)*64 + ln;
  const int r0 = c0a>>3, sc0 = ((c0a&7) ^ (r0&7))*8;
  const int r1 = c1a>>3, sc1 = ((c1a&7) ^ (r1&7))*8;

  #define STAGE2(sgi, bb, kt2) do { \
    int kv0s = (kt2)*64; \
    u16* _kb = KBp + ((sgi)*2 + (bb))*4096; \
    u16* _vb = VBp + ((sgi)*2 + (bb))*4096; \
    gll16(ksrc + (size_t)(kv0s+r0)*3072 + sc0, _kb + (0*4+wvL)*512); \
    gll16(vsrc + (size_t)r0*2048 + kv0s + sc0, _vb + (0*4+wvL)*512); \
    gll16(ksrc + (size_t)(kv0s+r1)*3072 + sc1, _kb + (1*4+wvL)*512); \
    gll16(vsrc + (size_t)r1*2048 + kv0s + sc1, _vb + (1*4+wvL)*512); \
  } while(0)

  const int nmax = (qt + 2) >> 1;          // ceil((qt+1)/2), uniform across block
  if (sg <= qt) STAGE2(sg, 0, sg);
  __syncthreads();
  int buf = 0;

  for (int i = 0; i < nmax; ++i){
    const int kt = 2*i + sg;
    const int ktn = kt + 2;
    const bool act = (kt <= qt);           // wave-uniform
    if (ktn <= qt) STAGE2(sg, buf^1, ktn);
    if (act){
      const int kv0 = kt*64;
      const u16* KB = KBp + (sg*2 + buf)*4096;
      const u16* VB = VBp + (sg*2 + buf)*4096;
      f32x4 s4[4] = {};
      __builtin_amdgcn_s_setprio(1);
      #pragma unroll
      for (int nt=0;nt<4;++nt){
        int row = nt*16 + lr;
        int sw = (row&7)<<4;
        const char* kb = (const char*)&KB[row*64];
        bf16x8 k0 = *(const bf16x8*)(kb + ((gq*16) ^ sw));
        bf16x8 k1 = *(const bf16x8*)(kb + ((64 + gq*16) ^ sw));
        s4[nt] = __builtin_amdgcn_mfma_f32_16x16x32_bf16(k0, qf0, s4[nt], 0,0,0);
        s4[nt] = __builtin_amdgcn_mfma_f32_16x16x32_bf16(k1, qf1, s4[nt], 0,0,0);
      }
      __builtin_amdgcn_s_setprio(0);
      // causal mask (diag tile only)
      if (kt == qt){
        #pragma unroll
        for (int nt=0;nt<4;++nt)
          #pragma unroll
          for (int r=0;r<4;++r){
            int k = kv0 + nt*16 + 4*gq + r;
            if (k > qglob) s4[nt][r] = -1e30f;
          }
      }
      // tree row-max (depth ~4)
      float ma = fmaxf(fmaxf(s4[0][0],s4[0][1]), fmaxf(s4[0][2],s4[0][3]));
      float mb = fmaxf(fmaxf(s4[1][0],s4[1][1]), fmaxf(s4[1][2],s4[1][3]));
      float mc = fmaxf(fmaxf(s4[2][0],s4[2][1]), fmaxf(s4[2][2],s4[2][3]));
      float md = fmaxf(fmaxf(s4[3][0],s4[3][1]), fmaxf(s4[3][2],s4[3][3]));
      float mloc = fmaxf(fmaxf(ma,mb), fmaxf(mc,md));
      mloc = fmaxf(mloc, __shfl_xor(mloc, 16));
      mloc = fmaxf(mloc, __shfl_xor(mloc, 32));
      if (__any(mloc > m_r + 8.0f)){        // T13 defer-max
        float mn = fmaxf(m_r, mloc);
        float alpha = __builtin_amdgcn_exp2f(m_r - mn);
        m_r = mn; l_r *= alpha;
        float a_o[4];
        #pragma unroll
        for (int r=0;r<4;++r) a_o[r] = __shfl(alpha, 4*gq + r);
        #pragma unroll
        for (int dt=0;dt<4;++dt)
          #pragma unroll
          for (int r=0;r<4;++r) o[dt][r] *= a_o[r];
      }
      // P = exp2(S-m), pack lane-local A-fragments
      u32 wkk[2][4];
      float rs = 0.f;
      #pragma unroll
      for (int c=0;c<2;++c){
        float pv[8];
        #pragma unroll
        for (int u=0;u<4;++u){
          pv[u]   = __builtin_amdgcn_exp2f(s4[2*c  ][u] - m_r);
          pv[4+u] = __builtin_amdgcn_exp2f(s4[2*c+1][u] - m_r);
        }
        rs += ((pv[0]+pv[1])+(pv[2]+pv[3])) + ((pv[4]+pv[5])+(pv[6]+pv[7]));
        wkk[c][0] = pack2(pv[0], pv[1]);
        wkk[c][1] = pack2(pv[2], pv[3]);
        wkk[c][2] = pack2(pv[4], pv[5]);
        wkk[c][3] = pack2(pv[6], pv[7]);
      }
      rs += __shfl_xor(rs, 16);
      rs += __shfl_xor(rs, 32);
      l_r += rs;
      __builtin_amdgcn_s_setprio(1);
      #pragma unroll
      for (int c=0;c<2;++c){
        union { u32 u[4]; bf16x8 v; } pa;
        pa.u[0]=wkk[c][0]; pa.u[1]=wkk[c][1]; pa.u[2]=wkk[c][2]; pa.u[3]=wkk[c][3];
        #pragma unroll
        for (int dt=0;dt<4;++dt){
          int row = dt*16 + lr;
          int sw = (row&7)<<4;
          const char* vb0 = (const char*)&VB[row*64];
          bf16x8 vb = *(const bf16x8*)(vb0 + ((c*64 + gq*16) ^ sw));
          o[dt] = __builtin_amdgcn_mfma_f32_16x16x32_bf16(pa.v, vb, o[dt], 0,0,0);
        }
      }
      __builtin_amdgcn_s_setprio(0);
    }
    __syncthreads();
    buf ^= 1;
  }

  // ---- in-LDS merge of the two partial softmaxes ----
  float* MO = (float*)SMEM;                 // [64][64] unnormalized O of sg1
  float* MM = (float*)(SMEM + 16384);       // m[64]
  float* ML = (float*)(SMEM + 16384 + 256); // l[64]
  if (sg == 1){
    #pragma unroll
    for (int dt=0;dt<4;++dt)
      #pragma unroll
      for (int r=0;r<4;++r)
        MO[(wvL*16 + 4*gq + r)*64 + dt*16 + lr] = o[dt][r];
    if (gq == 0){ MM[wvL*16 + lr] = m_r; ML[wvL*16 + lr] = l_r; }
  }
  __syncthreads();
  if (sg == 0){
    float mB = MM[wvL*16 + lr], lB = ML[wvL*16 + lr];
    float mS = fmaxf(m_r, mB);
    float eA = __builtin_amdgcn_exp2f(m_r - mS);
    float eB = __builtin_amdgcn_exp2f(mB - mS);
    float lS = l_r*eA + lB*eB;
    float eA_o[4], eB_o[4], lS_o[4];
    #pragma unroll
    for (int r=0;r<4;++r){
      eA_o[r] = __shfl(eA, 4*gq + r);
      eB_o[r] = __shfl(eB, 4*gq + r);
      lS_o[r] = __shfl(lS, 4*gq + r);
    }
    #pragma unroll
    for (int dt=0;dt<4;++dt){
      #pragma unroll
      for (int r=0;r<4;++r){
        float ob = MO[(wvL*16 + 4*gq + r)*64 + dt*16 + lr];
        float v = (o[dt][r]*eA_o[r] + ob*eB_o[r]) / lS_o[r];
        Out[(size_t)(b*2048 + q0 + wvL*16 + 4*gq + r)*1024 + h*64 + dt*16 + lr] = f2bf(v);
      }
    }
  }
}

// ---------- workspace layout (bytes) ----------
#define WS_WK   0u
#define WS_WV   16384u
#define WS_B2   32768u
#define WS_WT   49152u                               // 3072*1024*2 = 6291456
#define WS_W2T  (WS_WT + 6291456u)                   // 1024*1024*2 = 2097152
#define WS_XB   (WS_W2T + 2097152u)                  // 4096*1024*2 = 8388608 (reused as Vt)
#define WS_QKV  (WS_XB + 8388608u)                   // 4096*3072*2 = 25165824
#define WS_ATT  (WS_QKV + 25165824u)                 // 4096*1024*2 = 8388608

extern "C" void kernel_launch(void* const* d_in, const int* in_sizes, int n_in,
                              void* d_out, int out_size, void* d_ws, size_t ws_size,
                              hipStream_t stream) {
  const float* x  = (const float*)d_in[0];
  const float* Wa = (const float*)d_in[1];
  const float* ba = (const float*)d_in[2];
  const float* Wp = (const float*)d_in[3];
  const float* bp = (const float*)d_in[4];
  const float* kc = (const float*)d_in[5];
  const float* ke = (const float*)d_in[6];
  const float* vc = (const float*)d_in[7];
  const float* ve = (const float*)d_in[8];
  float* out = (float*)d_out;
  char* ws = (char*)d_ws;
  float* Wk  = (float*)(ws + WS_WK);
  float* Wv  = (float*)(ws + WS_WV);
  float* b2  = (float*)(ws + WS_B2);
  u16* Wt    = (u16*)(ws + WS_WT);
  u16* W2t   = (u16*)(ws + WS_W2T);
  u16* Xb    = (u16*)(ws + WS_XB);
  u16* QKVb  = (u16*)(ws + WS_QKV);
  u16* Att   = (u16*)(ws + WS_ATT);
  u16* Vt    = Xb;   // Xb dead after gemm1; reuse as Vt

  prep_wkv<<<32, 256, 0, stream>>>(kc, ke, vc, ve, Wk, Wv);
  prep_bias<<<12, 256, 0, stream>>>(ba, Wk, Wv, b2);
  prep_fold<<<256, 256, 0, stream>>>(Wa, Wk, Wv, Wt);
  transpose_cvt<<<dim3(16,16), 256, 0, stream>>>(Wa, 3072, Wt, 1024);   // Q part (n<1024)
  transpose_cvt<<<dim3(16,16), 256, 0, stream>>>(Wp, 1024, W2t, 1024);  // proj weight
  convert_x<<<4096, 256, 0, stream>>>(x, Xb, 1048576);
  gemm256<<<dim3(16,12), 512, 0, stream>>>(Xb, Wt, b2, QKVb, 4096, 3072, 1024, 3072);
  v_transpose<<<dim3(32,32), 256, 0, stream>>>(QKVb, Vt);
  attn_fwd<<<dim3(32,32), 512, 0, stream>>>(QKVb, Vt, Att);
  gemm_bt<float><<<dim3(32,8), 256, 0, stream>>>(Att, W2t, bp, out, 4096, 1024, 1024, 1024);
}

// Round 7
// 128.280 us; speedup vs baseline: 1.9684x; 1.0901x over previous
//
#include <hip/hip_runtime.h>
#include <cstddef>

typedef __attribute__((ext_vector_type(8))) __bf16 bf16x8;
typedef __attribute__((ext_vector_type(4))) float f32x4;
typedef unsigned short u16;
typedef unsigned int   u32;

// ---------- helpers ----------
__device__ __forceinline__ u16 f2bf(float f){
  union { float f; u32 u; } v; v.f = f;
  u32 r = v.u + 0x7FFFu + ((v.u >> 16) & 1u);   // RNE
  return (u16)(r >> 16);
}
__device__ __forceinline__ float bf2f(u16 s){
  union { u32 u; float f; } v; v.u = ((u32)s) << 16; return v.f;
}
__device__ __forceinline__ u32 cvtpk(float lo, float hi){
  u32 r; asm("v_cvt_pk_bf16_f32 %0, %1, %2" : "=v"(r) : "v"(lo), "v"(hi)); return r;
}

__device__ __forceinline__ void gll16(const void* g, void* l){
  __builtin_amdgcn_global_load_lds((__attribute__((address_space(1))) void*)g,
                                   (__attribute__((address_space(3))) void*)l, 16, 0, 0);
}

#define BARRIER() asm volatile("s_barrier" ::: "memory")
#define WAITL0()  asm volatile("s_waitcnt lgkmcnt(0)" ::: "memory")
#define WAITV4()  asm volatile("s_waitcnt vmcnt(4)" ::: "memory")

// ---------- prep: Wk = wk_c @ wk_e (64x64), Wv likewise ----------
__global__ void prep_wkv(const float* __restrict__ kc, const float* __restrict__ ke,
                         const float* __restrict__ vc, const float* __restrict__ ve,
                         float* __restrict__ Wk, float* __restrict__ Wv){
  int p = blockIdx.x & 1, chunk = blockIdx.x >> 1;
  const float* cm = p ? vc : kc;
  const float* em = p ? ve : ke;
  float* om = p ? Wv : Wk;
  int idx = chunk*256 + threadIdx.x;     // 0..4095
  int d = idx >> 6, j = idx & 63;
  float acc = 0.f;
  #pragma unroll
  for (int r=0;r<32;++r) acc += cm[d*32+r]*em[r*64+j];
  om[idx] = acc;
}

// ---------- prep: folded bias b2[3072] ----------
__global__ void prep_bias(const float* __restrict__ b, const float* __restrict__ Wk,
                          const float* __restrict__ Wv, float* __restrict__ b2){
  int n = blockIdx.x*256 + threadIdx.x;
  if (n >= 3072) return;
  if (n < 1024) { b2[n] = b[n]; return; }
  int rem = n - 1024;
  int p = rem >> 10; rem &= 1023;
  int h = rem >> 6, j = rem & 63;
  const float* Wm = p ? Wv : Wk;
  const float* bs = b + 1024 + p*1024 + h*64;
  float acc = 0.f;
  #pragma unroll
  for (int d=0;d<64;++d) acc += bs[d]*Wm[d*64+j];
  b2[n] = acc;
}

// ---------- prep: fold K/V expansion into attn weights (transposed, bf16) ----------
__global__ __launch_bounds__(256) void prep_fold(const float* __restrict__ W,
            const float* __restrict__ Wk, const float* __restrict__ Wv,
            u16* __restrict__ Wt){
  __shared__ float WkL[64*64];     // permuted: [d][ (j&1)*32 + (j>>1) ]
  int p = blockIdx.x >> 7, h = (blockIdx.x >> 3) & 15, ct = blockIdx.x & 7;
  const float* Wm = p ? Wv : Wk;
  int tid = threadIdx.x;
  #pragma unroll
  for (int t=0;t<16;++t){
    int idx = tid + t*256;
    int d = idx >> 6, j = idx & 63;
    WkL[d*64 + (j&1)*32 + (j>>1)] = Wm[idx];
  }
  __syncthreads();
  int cw = tid & 127, jh = tid >> 7;        // jh in {0,1}
  int c0 = ct*128;
  int coloff = 1024 + p*1024 + h*64;
  const float* wrow = W + (size_t)(c0+cw)*3072 + coloff;
  float acc[32];
  #pragma unroll
  for (int i=0;i<32;++i) acc[i]=0.f;
  for (int d=0; d<64; ++d){
    float wvv = wrow[d];
    const float4* col = (const float4*)&WkL[d*64 + jh*32];
    #pragma unroll
    for (int q=0;q<8;++q){
      float4 cv = col[q];
      acc[q*4+0] += wvv*cv.x;
      acc[q*4+1] += wvv*cv.y;
      acc[q*4+2] += wvv*cv.z;
      acc[q*4+3] += wvv*cv.w;
    }
  }
  int nbase = 1024 + p*1024 + h*64;
  #pragma unroll
  for (int i=0;i<32;++i){
    int j = jh + 2*i;
    Wt[(size_t)(nbase + j)*1024 + c0 + cw] = f2bf(acc[i]);
  }
}

// ---------- prep: transpose+convert fp32 [1024 x ld] -> bf16 ----------
__global__ __launch_bounds__(256) void transpose_cvt(const float* __restrict__ src, int ld_src,
            u16* __restrict__ dst, int ld_dst){
  __shared__ float tile[64][65];
  int c0 = blockIdx.x*64, n0 = blockIdx.y*64;
  int tx = threadIdx.x & 63, ty = threadIdx.x >> 6;  // ty 0..3
  #pragma unroll 4
  for (int k=0;k<16;++k){
    int r = 4*k + ty;
    tile[r][tx] = src[(size_t)(c0+r)*ld_src + n0 + tx];
  }
  __syncthreads();
  #pragma unroll 4
  for (int k=0;k<16;++k){
    int r = 4*k + ty;
    dst[(size_t)(n0+r)*ld_dst + c0 + tx] = f2bf(tile[tx][r]);
  }
}

// ---------- prep: x fp32 -> bf16 ----------
__global__ void convert_x(const float* __restrict__ x, u16* __restrict__ o, int n4){
  int i = blockIdx.x*blockDim.x + threadIdx.x;
  if (i >= n4) return;
  float4 v = ((const float4*)x)[i];
  ushort4 r; r.x = f2bf(v.x); r.y = f2bf(v.y); r.z = f2bf(v.z); r.w = f2bf(v.w);
  ((ushort4*)o)[i] = r;
}

// ---------- V transpose: QKV V-part -> Vt[bh*64+d][t], k-slot-permuted per 32-block ----------
__global__ __launch_bounds__(256) void v_transpose(const u16* __restrict__ QKV, u16* __restrict__ Vt){
  __shared__ u16 tile[64][72];   // [t][d]
  int tt = blockIdx.x, bh = blockIdx.y;
  int b = bh >> 4, h = bh & 15;
  int tid = threadIdx.x;
  int r = tid >> 2, cc = (tid & 3)*16;
  const u16* src = QKV + (size_t)(b*2048 + tt*64 + r)*3072 + 2048 + h*64 + cc;
  *(uint4*)&tile[r][cc]     = *(const uint4*)src;
  *(uint4*)&tile[r][cc + 8] = *(const uint4*)(src + 8);
  __syncthreads();
  int d = tid >> 2, pc = (tid & 3)*16;
  u16 vals[16];
  #pragma unroll
  for (int i=0;i<16;++i){
    int p = pc + i;
    int c = p >> 5, q = p & 31, g = q >> 3, j = q & 7;
    int o = 16*(j>>2) + 4*g + (j&3);
    vals[i] = tile[c*32 + o][d];
  }
  u16* drow = Vt + (size_t)(bh*64 + d)*2048 + tt*64 + pc;
  *(uint4*)drow       = *(const uint4*)&vals[0];
  *(uint4*)(drow + 8) = *(const uint4*)&vals[8];
}

// ---------- 256x256 8-phase bf16 GEMM (T2+T3+T4+T5), C = A * Bt^T + bias ----------
#define STG(ab, buf, h, kt) do { \
    const u16* _g = ((ab) ? gB : gA) + (size_t)((h)*128)*K + (size_t)(kt)*64; \
    gll16(_g + (size_t)((0*8+w)*8+srow)*K, &SH[ab][buf][h][(0*8+w)*512]); \
    gll16(_g + (size_t)((1*8+w)*8+srow)*K, &SH[ab][buf][h][(1*8+w)*512]); \
  } while(0)
#define RDA(buf, h) do { const char* _b = (const char*)&SH[0][buf][h][0]; \
    _Pragma("unroll") for (int ii=0; ii<4; ++ii){ \
      const char* _r = _b + (ii*32 + wm*16 + lr)*128; \
      aF[ii][0] = *(const bf16x8*)(_r + cswz0); \
      aF[ii][1] = *(const bf16x8*)(_r + (cswz0 ^ 64)); } \
  } while(0)
#define RDB(buf, h, BF) do { const char* _b = (const char*)&SH[1][buf][h][0]; \
    _Pragma("unroll") for (int jj=0; jj<2; ++jj){ \
      const char* _r = _b + (jj*64 + wn*16 + lr)*128; \
      BF[jj][0] = *(const bf16x8*)(_r + cswz0); \
      BF[jj][1] = *(const bf16x8*)(_r + (cswz0 ^ 64)); } \
  } while(0)
#define QUAD(mh, bh, BF) do { \
    _Pragma("unroll") for (int ii=0; ii<4; ++ii) \
    _Pragma("unroll") for (int jj=0; jj<2; ++jj) \
    _Pragma("unroll") for (int ks=0; ks<2; ++ks) \
      acc[(mh)*4+ii][(bh)*2+jj] = __builtin_amdgcn_mfma_f32_16x16x32_bf16( \
          aF[ii][ks], BF[jj][ks], acc[(mh)*4+ii][(bh)*2+jj], 0,0,0); \
  } while(0)

__global__ __launch_bounds__(512, 2) void gemm256(const u16* __restrict__ Ag, const u16* __restrict__ Bg,
        const float* __restrict__ bias, u16* __restrict__ C, int M, int N, int K, int ldc){
  __shared__ u16 SH[2][2][2][8192];   // [ab][buf][half][128*64]
  const int nwg = gridDim.x * gridDim.y;
  const int id  = blockIdx.x + gridDim.x * blockIdx.y;
  const int nid = (id & 7) * (nwg >> 3) + (id >> 3);   // nwg % 8 == 0
  const int bx = nid % gridDim.x, by = nid / gridDim.x;
  const int m0 = bx*256, n0 = by*256;
  const int tid = threadIdx.x, w = tid>>6, ln = tid&63;
  const int wm = w>>2, wn = w&3;
  const int lr = ln&15, gq = ln>>4;
  const int srow = ln>>3;                 // 0..7
  const int ce = ((ln&7) ^ srow) * 8;     // pre-swizzled source col (elements)
  const int cswz0 = (gq*16) ^ ((lr&7)<<4);
  const int NKT = K >> 6;                 // 16

  f32x4 acc[8][4] = {};
  bf16x8 aF[4][2], bF0[2][2], bF1[2][2];

  const u16* gA = Ag + (size_t)m0*K + ce;
  const u16* gB = Bg + (size_t)n0*K + ce;

  STG(0,0,0,0); STG(1,0,0,0); STG(1,0,1,0); STG(0,0,1,0);
  STG(0,1,0,1); STG(1,1,0,1);
  WAITV4();
  BARRIER();

  for (int it = 0; it < (NKT>>1); ++it){
    const int t1 = 2*it+1;
    const int t2 = (2*it+2 < NKT) ? 2*it+2 : NKT-1;
    const int t3 = (2*it+3 < NKT) ? 2*it+3 : NKT-1;
    RDA(0,0); RDB(0,0,bF0); STG(1,1,1,t1);
    BARRIER(); WAITL0();
    __builtin_amdgcn_s_setprio(1); QUAD(0,0,bF0); __builtin_amdgcn_s_setprio(0);
    BARRIER();
    RDB(0,1,bF1); STG(0,1,1,t1);
    BARRIER(); WAITL0();
    __builtin_amdgcn_s_setprio(1); QUAD(0,1,bF1); __builtin_amdgcn_s_setprio(0);
    BARRIER();
    RDA(0,1); STG(0,0,0,t2);
    BARRIER(); WAITL0();
    __builtin_amdgcn_s_setprio(1); QUAD(1,0,bF0); __builtin_amdgcn_s_setprio(0);
    BARRIER();
    STG(1,0,0,t2);
    BARRIER();
    __builtin_amdgcn_s_setprio(1); QUAD(1,1,bF1); __builtin_amdgcn_s_setprio(0);
    WAITV4();
    BARRIER();
    RDA(1,0); RDB(1,0,bF0); STG(1,0,1,t2);
    BARRIER(); WAITL0();
    __builtin_amdgcn_s_setprio(1); QUAD(0,0,bF0); __builtin_amdgcn_s_setprio(0);
    BARRIER();
    RDB(1,1,bF1); STG(0,0,1,t2);
    BARRIER(); WAITL0();
    __builtin_amdgcn_s_setprio(1); QUAD(0,1,bF1); __builtin_amdgcn_s_setprio(0);
    BARRIER();
    RDA(1,1); STG(0,1,0,t3);
    BARRIER(); WAITL0();
    __builtin_amdgcn_s_setprio(1); QUAD(1,0,bF0); __builtin_amdgcn_s_setprio(0);
    BARRIER();
    STG(1,1,0,t3);
    BARRIER();
    __builtin_amdgcn_s_setprio(1); QUAD(1,1,bF1); __builtin_amdgcn_s_setprio(0);
    WAITV4();
    BARRIER();
  }

  #pragma unroll
  for (int j=0;j<4;++j){
    int col = n0 + j*64 + wn*16 + lr;
    float bv = bias[col];
    #pragma unroll
    for (int i=0;i<8;++i){
      int row = m0 + i*32 + wm*16 + 4*gq;
      #pragma unroll
      for (int rr=0;rr<4;++rr)
        C[(size_t)(row+rr)*ldc + col] = f2bf(acc[i][j][rr] + bv);
    }
  }
}

// ---------- 128x128 bf16 GEMM (2-phase) for the small N=1024 proj ----------
template<typename OT>
__global__ __launch_bounds__(256) void gemm_bt(const u16* __restrict__ A, const u16* __restrict__ Bt,
        const float* __restrict__ bias, OT* __restrict__ C, int M, int N, int K, int ldc){
  __shared__ u16 As[128*64];
  __shared__ u16 Bs[128*64];
  const int nwg = gridDim.x * gridDim.y;
  const int id  = blockIdx.x + gridDim.x * blockIdx.y;
  const int nid = (id & 7) * (nwg >> 3) + (id >> 3);
  const int bx = nid % gridDim.x, by = nid / gridDim.x;
  const int tid = threadIdx.x, wv = tid>>6, ln = tid&63;
  const int lr = ln&15, g8 = (ln>>4)*8;
  const int m0 = bx*128, n0 = by*128;
  const int wr = (wv>>1)*64, wc = (wv&1)*64;
  f32x4 acc[4][4] = {};
  const int nk = K >> 6;
  for (int kt=0; kt<nk; ++kt){
    #pragma unroll
    for (int it=0; it<4; ++it){
      int chunk = wv*4+it;
      int row = chunk*8 + (ln>>3), colc = (ln&7)*8;
      gll16(A  + (size_t)(m0+row)*K + kt*64 + colc, &As[chunk*512]);
      gll16(Bt + (size_t)(n0+row)*K + kt*64 + colc, &Bs[chunk*512]);
    }
    __syncthreads();
    #pragma unroll
    for (int ks=0; ks<2; ++ks){
      bf16x8 af[4], bfr[4];
      #pragma unroll
      for (int mt=0;mt<4;++mt) af[mt]  = *(const bf16x8*)&As[(wr+mt*16+lr)*64 + ks*32 + g8];
      #pragma unroll
      for (int nt=0;nt<4;++nt) bfr[nt] = *(const bf16x8*)&Bs[(wc+nt*16+lr)*64 + ks*32 + g8];
      #pragma unroll
      for (int mt=0;mt<4;++mt)
        #pragma unroll
        for (int nt=0;nt<4;++nt)
          acc[mt][nt] = __builtin_amdgcn_mfma_f32_16x16x32_bf16(af[mt], bfr[nt], acc[mt][nt], 0,0,0);
    }
    __syncthreads();
  }
  #pragma unroll
  for (int mt=0;mt<4;++mt){
    int row = m0 + wr + mt*16 + 4*(ln>>4);
    #pragma unroll
    for (int nt=0;nt<4;++nt){
      int col = n0 + wc + nt*16 + lr;
      float bv = bias[col];
      #pragma unroll
      for (int r=0;r<4;++r){
        float v = acc[mt][nt][r] + bv;
        if constexpr (sizeof(OT) == 2) C[(size_t)(row+r)*ldc + col] = f2bf(v);
        else                           C[(size_t)(row+r)*ldc + col] = v;
      }
    }
  }
}

// ---------- causal flash attention: dual kt-stream, NO-max softmax (bounded scores) ----------
// Scores obey |S*log2e| <= 104 < 127 even at bf16 worst case -> exp2 never overflows f32.
// grid (bh=32, y=32), qt=31-y (LPT). 512 thr = 2 subgroups x 4 waves, kt ≡ sg (mod 2).
__global__ __launch_bounds__(512, 4) void attn_fwd(const u16* __restrict__ QKV,
            const u16* __restrict__ Vt, u16* __restrict__ Out){
  const int bh = blockIdx.x;
  const int qt = 31 - blockIdx.y;
  const int b = bh >> 4, h = bh & 15;
  const int tid = threadIdx.x, wv = tid>>6, ln = tid&63;
  const int sg = wv>>2, wvL = wv&3;
  const int lr = ln&15, gq = ln>>4;
  __shared__ __align__(16) char SMEM[65536];
  u16* KB0 = (u16*)(SMEM)          + (sg*2    )*4096;
  u16* KB1 = (u16*)(SMEM)          + (sg*2 + 1)*4096;
  u16* VB0 = (u16*)(SMEM + 32768)  + (sg*2    )*4096;
  u16* VB1 = (u16*)(SMEM + 32768)  + (sg*2 + 1)*4096;
  const int q0 = qt*64;
  const size_t base = (size_t)(b*2048) * 3072;
  const float SCL = 0.125f * 1.44269504f;

  // Q fragments pre-scaled by SCL (exp2 domain)
  const u16* qrow = QKV + base + (size_t)(q0 + wvL*16 + lr)*3072 + h*64;
  union { bf16x8 v; u16 s[8]; } uq0, uq1;
  uq0.v = *(const bf16x8*)(qrow + gq*8);
  uq1.v = *(const bf16x8*)(qrow + 32 + gq*8);
  #pragma unroll
  for (int j=0;j<8;++j){ uq0.s[j] = f2bf(bf2f(uq0.s[j])*SCL); uq1.s[j] = f2bf(bf2f(uq1.s[j])*SCL); }
  bf16x8 qf0 = uq0.v, qf1 = uq1.v;
  const int qglob = q0 + wvL*16 + lr;
  f32x4 o[4] = {};
  float l_r = 0.f;
  const u16* ksrc = QKV + base + 1024 + h*64;
  const u16* vsrc = Vt + (size_t)(bh*64)*2048;

  const int c0a = wvL*64 + ln, c1a = (4+wvL)*64 + ln;
  const int r0 = c0a>>3, sc0 = ((c0a&7) ^ (r0&7))*8;
  const int r1 = c1a>>3, sc1 = ((c1a&7) ^ (r1&7))*8;

  // loop-invariant LDS read byte-offsets (K and V share the formula)
  const int swl = (lr&7)<<4;
  int offb[4][2];
  #pragma unroll
  for (int nt=0;nt<4;++nt){
    int row = nt*16 + lr;
    offb[nt][0] = row*128 + ((gq*16) ^ swl);
    offb[nt][1] = row*128 + ((64 + gq*16) ^ swl);
  }

  // prologue: stage tile kt=sg into buf0
  if (sg <= qt){
    int kv0s = sg*64;
    gll16(ksrc + (size_t)(kv0s+r0)*3072 + sc0, KB0 + wvL*512);
    gll16(vsrc + (size_t)r0*2048 + kv0s + sc0, VB0 + wvL*512);
    gll16(ksrc + (size_t)(kv0s+r1)*3072 + sc1, KB0 + 2048 + wvL*512);
    gll16(vsrc + (size_t)r1*2048 + kv0s + sc1, VB0 + 2048 + wvL*512);
  }
  __syncthreads();

  // running stage pointers at tile sg+2
  const u16* kp0 = ksrc + (size_t)(sg*64 + 128 + r0)*3072 + sc0;
  const u16* kp1 = ksrc + (size_t)(sg*64 + 128 + r1)*3072 + sc1;
  const u16* vp0 = vsrc + (size_t)r0*2048 + sg*64 + 128 + sc0;
  const u16* vp1 = vsrc + (size_t)r1*2048 + sg*64 + 128 + sc1;
  const size_t KSTEP = (size_t)128*3072, VSTEP = 128;

  #define ABODY(II, KBC, VBC, KBN, VBN) do { \
    const int kt = 2*(II) + sg; \
    if (kt + 2 <= qt){ \
      gll16(kp0, KBN + wvL*512); \
      gll16(vp0, VBN + wvL*512); \
      gll16(kp1, KBN + 2048 + wvL*512); \
      gll16(vp1, VBN + 2048 + wvL*512); \
      kp0 += KSTEP; kp1 += KSTEP; vp0 += VSTEP; vp1 += VSTEP; \
    } \
    if (kt <= qt){ \
      f32x4 s4[4] = {}; \
      __builtin_amdgcn_s_setprio(1); \
      _Pragma("unroll") for (int nt=0;nt<4;++nt){ \
        bf16x8 k0 = *(const bf16x8*)((const char*)KBC + offb[nt][0]); \
        bf16x8 k1 = *(const bf16x8*)((const char*)KBC + offb[nt][1]); \
        s4[nt] = __builtin_amdgcn_mfma_f32_16x16x32_bf16(k0, qf0, s4[nt], 0,0,0); \
        s4[nt] = __builtin_amdgcn_mfma_f32_16x16x32_bf16(k1, qf1, s4[nt], 0,0,0); \
      } \
      __builtin_amdgcn_s_setprio(0); \
      if (kt == qt){ \
        const int kv0 = kt*64; \
        _Pragma("unroll") for (int nt=0;nt<4;++nt) \
        _Pragma("unroll") for (int r=0;r<4;++r){ \
          int k = kv0 + nt*16 + 4*gq + r; \
          if (k > qglob) s4[nt][r] = -1e30f; \
        } \
      } \
      u32 wk0[4], wk1[4]; \
      float p0,p1,p2,p3,p4,p5,p6,p7; \
      p0=__builtin_amdgcn_exp2f(s4[0][0]); p1=__builtin_amdgcn_exp2f(s4[0][1]); \
      p2=__builtin_amdgcn_exp2f(s4[0][2]); p3=__builtin_amdgcn_exp2f(s4[0][3]); \
      p4=__builtin_amdgcn_exp2f(s4[1][0]); p5=__builtin_amdgcn_exp2f(s4[1][1]); \
      p6=__builtin_amdgcn_exp2f(s4[1][2]); p7=__builtin_amdgcn_exp2f(s4[1][3]); \
      l_r += ((p0+p1)+(p2+p3)) + ((p4+p5)+(p6+p7)); \
      wk0[0]=cvtpk(p0,p1); wk0[1]=cvtpk(p2,p3); wk0[2]=cvtpk(p4,p5); wk0[3]=cvtpk(p6,p7); \
      p0=__builtin_amdgcn_exp2f(s4[2][0]); p1=__builtin_amdgcn_exp2f(s4[2][1]); \
      p2=__builtin_amdgcn_exp2f(s4[2][2]); p3=__builtin_amdgcn_exp2f(s4[2][3]); \
      p4=__builtin_amdgcn_exp2f(s4[3][0]); p5=__builtin_amdgcn_exp2f(s4[3][1]); \
      p6=__builtin_amdgcn_exp2f(s4[3][2]); p7=__builtin_amdgcn_exp2f(s4[3][3]); \
      l_r += ((p0+p1)+(p2+p3)) + ((p4+p5)+(p6+p7)); \
      wk1[0]=cvtpk(p0,p1); wk1[1]=cvtpk(p2,p3); wk1[2]=cvtpk(p4,p5); wk1[3]=cvtpk(p6,p7); \
      union { u32 u[4]; bf16x8 v; } pa0, pa1; \
      pa0.u[0]=wk0[0]; pa0.u[1]=wk0[1]; pa0.u[2]=wk0[2]; pa0.u[3]=wk0[3]; \
      pa1.u[0]=wk1[0]; pa1.u[1]=wk1[1]; pa1.u[2]=wk1[2]; pa1.u[3]=wk1[3]; \
      __builtin_amdgcn_s_setprio(1); \
      _Pragma("unroll") for (int dt=0;dt<4;++dt){ \
        bf16x8 vb0 = *(const bf16x8*)((const char*)VBC + offb[dt][0]); \
        o[dt] = __builtin_amdgcn_mfma_f32_16x16x32_bf16(pa0.v, vb0, o[dt], 0,0,0); \
      } \
      _Pragma("unroll") for (int dt=0;dt<4;++dt){ \
        bf16x8 vb1 = *(const bf16x8*)((const char*)VBC + offb[dt][1]); \
        o[dt] = __builtin_amdgcn_mfma_f32_16x16x32_bf16(pa1.v, vb1, o[dt], 0,0,0); \
      } \
      __builtin_amdgcn_s_setprio(0); \
    } \
    __syncthreads(); \
  } while(0)

  const int nmax = (qt + 2) >> 1;
  const int jmax = (nmax + 1) >> 1;
  for (int j = 0; j < jmax; ++j){
    ABODY(2*j,   KB0, VB0, KB1, VB1);
    ABODY(2*j+1, KB1, VB1, KB0, VB0);
  }

  // finish l: sum across the 4 gq-groups (per q = lane&15)
  l_r += __shfl_xor(l_r, 16);
  l_r += __shfl_xor(l_r, 32);

  // ---- in-LDS merge of the two partial (unnormalized) results ----
  float* MO = (float*)SMEM;                 // [64][66] padded
  float* ML = (float*)(SMEM + 20480);       // l[64]
  if (sg == 1){
    #pragma unroll
    for (int dt=0;dt<4;++dt)
      #pragma unroll
      for (int r=0;r<4;++r)
        MO[(wvL*16 + 4*gq + r)*66 + dt*16 + lr] = o[dt][r];
    if (gq == 0) ML[wvL*16 + lr] = l_r;
  }
  __syncthreads();
  if (sg == 0){
    float lS = l_r + ML[wvL*16 + lr];
    float lS_o[4];
    #pragma unroll
    for (int r=0;r<4;++r) lS_o[r] = __shfl(lS, 4*gq + r);
    #pragma unroll
    for (int dt=0;dt<4;++dt){
      #pragma unroll
      for (int r=0;r<4;++r){
        float ob = MO[(wvL*16 + 4*gq + r)*66 + dt*16 + lr];
        float v = (o[dt][r] + ob) / lS_o[r];
        Out[(size_t)(b*2048 + q0 + wvL*16 + 4*gq + r)*1024 + h*64 + dt*16 + lr] = f2bf(v);
      }
    }
  }
}

// ---------- workspace layout (bytes) ----------
#define WS_WK   0u
#define WS_WV   16384u
#define WS_B2   32768u
#define WS_WT   49152u                               // 3072*1024*2 = 6291456
#define WS_W2T  (WS_WT + 6291456u)                   // 1024*1024*2 = 2097152
#define WS_XB   (WS_W2T + 2097152u)                  // 4096*1024*2 = 8388608 (reused as Vt)
#define WS_QKV  (WS_XB + 8388608u)                   // 4096*3072*2 = 25165824
#define WS_ATT  (WS_QKV + 25165824u)                 // 4096*1024*2 = 8388608

extern "C" void kernel_launch(void* const* d_in, const int* in_sizes, int n_in,
                              void* d_out, int out_size, void* d_ws, size_t ws_size,
                              hipStream_t stream) {
  const float* x  = (const float*)d_in[0];
  const float* Wa = (const float*)d_in[1];
  const float* ba = (const float*)d_in[2];
  const float* Wp = (const float*)d_in[3];
  const float* bp = (const float*)d_in[4];
  const float* kc = (const float*)d_in[5];
  const float* ke = (const float*)d_in[6];
  const float* vc = (const float*)d_in[7];
  const float* ve = (const float*)d_in[8];
  float* out = (float*)d_out;
  char* ws = (char*)d_ws;
  float* Wk  = (float*)(ws + WS_WK);
  float* Wv  = (float*)(ws + WS_WV);
  float* b2  = (float*)(ws + WS_B2);
  u16* Wt    = (u16*)(ws + WS_WT);
  u16* W2t   = (u16*)(ws + WS_W2T);
  u16* Xb    = (u16*)(ws + WS_XB);
  u16* QKVb  = (u16*)(ws + WS_QKV);
  u16* Att   = (u16*)(ws + WS_ATT);
  u16* Vt    = Xb;   // Xb dead after gemm1; reuse as Vt

  prep_wkv<<<32, 256, 0, stream>>>(kc, ke, vc, ve, Wk, Wv);
  prep_bias<<<12, 256, 0, stream>>>(ba, Wk, Wv, b2);
  prep_fold<<<256, 256, 0, stream>>>(Wa, Wk, Wv, Wt);
  transpose_cvt<<<dim3(16,16), 256, 0, stream>>>(Wa, 3072, Wt, 1024);   // Q part (n<1024)
  transpose_cvt<<<dim3(16,16), 256, 0, stream>>>(Wp, 1024, W2t, 1024);  // proj weight
  convert_x<<<4096, 256, 0, stream>>>(x, Xb, 1048576);
  gemm256<<<dim3(16,12), 512, 0, stream>>>(Xb, Wt, b2, QKVb, 4096, 3072, 1024, 3072);
  v_transpose<<<dim3(32,32), 256, 0, stream>>>(QKVb, Vt);
  attn_fwd<<<dim3(32,32), 512, 0, stream>>>(QKVb, Vt, Att);
  gemm_bt<float><<<dim3(32,8), 256, 0, stream>>>(Att, W2t, bp, out, 4096, 1024, 1024, 1024);
}

// Round 8
// 111.415 us; speedup vs baseline: 2.2664x; 1.1514x over previous
//
#include <hip/hip_runtime.h>
#include <cstddef>

typedef __attribute__((ext_vector_type(8))) __bf16 bf16x8;
typedef __attribute__((ext_vector_type(4))) float f32x4;
typedef unsigned short u16;
typedef unsigned int   u32;

#define SCLF (0.125f * 1.44269504f)   // softmax scale * log2(e), folded into q' weights

// ---------- helpers ----------
__device__ __forceinline__ u16 f2bf(float f){
  union { float f; u32 u; } v; v.f = f;
  u32 r = v.u + 0x7FFFu + ((v.u >> 16) & 1u);   // RNE
  return (u16)(r >> 16);
}
__device__ __forceinline__ u32 cvtpk(float lo, float hi){
  u32 r; asm("v_cvt_pk_bf16_f32 %0, %1, %2" : "=v"(r) : "v"(lo), "v"(hi)); return r;
}
__device__ __forceinline__ void gll16(const void* g, void* l){
  __builtin_amdgcn_global_load_lds((__attribute__((address_space(1))) void*)g,
                                   (__attribute__((address_space(3))) void*)l, 16, 0, 0);
}

// ---------- fold: attn weights -> latent space (Bt layout [1536][1024] bf16) ----------
// part 0: q'  rows  h*32+r       = sum_d Wa[c][h*64+d]      * wk_e[r][d]  * SCLF
// part 1: k_lat rows 512+h*32+r  = sum_d Wa[c][1024+h*64+d] * wk_c[d][r]
// part 2: v_lat rows 1024+h*32+r = sum_d Wa[c][2048+h*64+d] * wv_c[d][r]
__global__ __launch_bounds__(256) void fold_qkv(const float* __restrict__ Wa,
      const float* __restrict__ kc, const float* __restrict__ ke,
      const float* __restrict__ vc, u16* __restrict__ Wt){
  __shared__ float Ws[2048];    // [d][r]
  int cc = blockIdx.x, h = blockIdx.y, part = blockIdx.z;
  int tid = threadIdx.x;
  #pragma unroll
  for (int i=0;i<8;++i){
    int idx = tid + i*256; int d = idx>>5, r = idx&31;
    Ws[idx] = (part==0) ? ke[r*64+d] : (part==1) ? kc[idx] : vc[idx];
  }
  __syncthreads();
  int c = cc*256 + tid;
  const float4* wrow = (const float4*)(Wa + (size_t)c*3072 + part*1024 + h*64);
  float out[32] = {};
  #pragma unroll
  for (int dq=0; dq<16; ++dq){
    float4 av = wrow[dq];
    #pragma unroll
    for (int rr=0; rr<32; ++rr)
      out[rr] += av.x*Ws[(4*dq+0)*32+rr] + av.y*Ws[(4*dq+1)*32+rr]
               + av.z*Ws[(4*dq+2)*32+rr] + av.w*Ws[(4*dq+3)*32+rr];
  }
  float scl = (part==0) ? SCLF : 1.f;
  int nbase = part*512 + h*32;
  #pragma unroll
  for (int r=0;r<32;++r)
    Wt[(size_t)(nbase+r)*1024 + c] = f2bf(out[r]*scl);
}

// ---------- fold: bias -> latent (b2[1536]) ----------
__global__ void fold_bias(const float* __restrict__ ba, const float* __restrict__ kc,
                          const float* __restrict__ ke, const float* __restrict__ vc,
                          float* __restrict__ b2){
  int n = blockIdx.x*256 + threadIdx.x;
  if (n >= 1536) return;
  int part = n>>9, h = (n>>5)&15, r = n&31;
  const float* bs = ba + part*1024 + h*64;
  float acc = 0.f;
  for (int d=0;d<64;++d){
    float w = (part==0) ? ke[r*64+d] : (part==1) ? kc[d*32+r] : vc[d*32+r];
    acc += bs[d]*w;
  }
  b2[n] = acc * ((part==0) ? SCLF : 1.f);
}

// ---------- fold: proj weights W2t[j][h*32+r] = sum_d wv_e[r][d]*Wp[h*64+d][j] ----------
__global__ __launch_bounds__(256) void fold_proj(const float* __restrict__ Wp,
      const float* __restrict__ ve, u16* __restrict__ W2t){
  __shared__ float WpL[8192];   // [64 d][128 j]
  __shared__ float WeL[2048];   // [32 r][64 d]
  int jc = blockIdx.x, h = blockIdx.y;
  int tid = threadIdx.x;
  #pragma unroll
  for (int i=0;i<32;++i){
    int idx = tid + i*256; int d = idx>>7, jj = idx&127;
    WpL[idx] = Wp[(size_t)(h*64+d)*1024 + jc*128 + jj];
  }
  #pragma unroll
  for (int i=0;i<8;++i) WeL[tid + i*256] = ve[tid + i*256];
  __syncthreads();
  int jj = tid & 127, rg = tid >> 7;
  float out[16] = {};
  #pragma unroll
  for (int d=0; d<64; ++d){
    float pv = WpL[d*128 + jj];
    #pragma unroll
    for (int rr=0; rr<16; ++rr) out[rr] += WeL[(rg*16+rr)*64 + d] * pv;
  }
  #pragma unroll
  for (int rr=0; rr<16; ++rr)
    W2t[(size_t)(jc*128 + jj)*512 + h*32 + rg*16 + rr] = f2bf(out[rr]);
}

// ---------- prep: x fp32 -> bf16 ----------
__global__ void convert_x(const float* __restrict__ x, u16* __restrict__ o, int n4){
  int i = blockIdx.x*blockDim.x + threadIdx.x;
  if (i >= n4) return;
  float4 v = ((const float4*)x)[i];
  ushort4 r; r.x = f2bf(v.x); r.y = f2bf(v.y); r.z = f2bf(v.z); r.w = f2bf(v.w);
  ((ushort4*)o)[i] = r;
}

// ---------- V transpose (latent): QKV' v_lat part -> Vt[bh*32+r][t], k-slot-permuted ----------
__global__ __launch_bounds__(256) void v_transpose_lat(const u16* __restrict__ QKV,
      u16* __restrict__ Vt){
  __shared__ u16 tile[64][40];   // [t][r] padded
  int tt = blockIdx.x, bh = blockIdx.y;
  int b = bh>>4, h = bh&15;
  int tid = threadIdx.x;
  int row = tid>>2, cc2 = (tid&3)*8;
  const u16* src = QKV + (size_t)(b*2048 + tt*64 + row)*1536 + 1024 + h*32 + cc2;
  *(uint4*)&tile[row][cc2] = *(const uint4*)src;
  __syncthreads();
  int r = tid>>3, pc = (tid&7)*8;
  u16 vals[8];
  #pragma unroll
  for (int i=0;i<8;++i){
    int p = pc+i; int c = p>>5, q = p&31, g = q>>3, j = q&7;
    int o = c*32 + 16*(j>>2) + 4*g + (j&3);
    vals[i] = tile[o][r];
  }
  u16* drow = Vt + (size_t)(bh*32 + r)*2048 + tt*64 + pc;
  *(uint4*)drow = *(const uint4*)&vals[0];
}

// ---------- 128x128 bf16 GEMM (2-phase): C[M,N] = A[M,K]*Bt[N,K]^T + bias ----------
template<typename OT>
__global__ __launch_bounds__(256) void gemm_bt(const u16* __restrict__ A, const u16* __restrict__ Bt,
        const float* __restrict__ bias, OT* __restrict__ C, int M, int N, int K, int ldc){
  __shared__ u16 As[128*64];
  __shared__ u16 Bs[128*64];
  const int nwg = gridDim.x * gridDim.y;
  const int id  = blockIdx.x + gridDim.x * blockIdx.y;
  const int nid = (id & 7) * (nwg >> 3) + (id >> 3);   // nwg % 8 == 0
  const int bx = nid % gridDim.x, by = nid / gridDim.x;
  const int tid = threadIdx.x, wv = tid>>6, ln = tid&63;
  const int lr = ln&15, g8 = (ln>>4)*8;
  const int m0 = bx*128, n0 = by*128;
  const int wr = (wv>>1)*64, wc = (wv&1)*64;
  f32x4 acc[4][4] = {};
  const int nk = K >> 6;
  for (int kt=0; kt<nk; ++kt){
    #pragma unroll
    for (int it=0; it<4; ++it){
      int chunk = wv*4+it;
      int row = chunk*8 + (ln>>3), colc = (ln&7)*8;
      gll16(A  + (size_t)(m0+row)*K + kt*64 + colc, &As[chunk*512]);
      gll16(Bt + (size_t)(n0+row)*K + kt*64 + colc, &Bs[chunk*512]);
    }
    __syncthreads();
    #pragma unroll
    for (int ks=0; ks<2; ++ks){
      bf16x8 af[4], bfr[4];
      #pragma unroll
      for (int mt=0;mt<4;++mt) af[mt]  = *(const bf16x8*)&As[(wr+mt*16+lr)*64 + ks*32 + g8];
      #pragma unroll
      for (int nt=0;nt<4;++nt) bfr[nt] = *(const bf16x8*)&Bs[(wc+nt*16+lr)*64 + ks*32 + g8];
      #pragma unroll
      for (int mt=0;mt<4;++mt)
        #pragma unroll
        for (int nt=0;nt<4;++nt)
          acc[mt][nt] = __builtin_amdgcn_mfma_f32_16x16x32_bf16(af[mt], bfr[nt], acc[mt][nt], 0,0,0);
    }
    __syncthreads();
  }
  #pragma unroll
  for (int mt=0;mt<4;++mt){
    int row = m0 + wr + mt*16 + 4*(ln>>4);
    #pragma unroll
    for (int nt=0;nt<4;++nt){
      int col = n0 + wc + nt*16 + lr;
      float bv = bias[col];
      #pragma unroll
      for (int r=0;r<4;++r){
        float v = acc[mt][nt][r] + bv;
        if constexpr (sizeof(OT) == 2) C[(size_t)(row+r)*ldc + col] = f2bf(v);
        else                           C[(size_t)(row+r)*ldc + col] = v;
      }
    }
  }
}

// ---------- causal flash attention in rank-32 latent space ----------
// QKV'[4096][1536]: q' (SCLF-scaled) at 0, k_lat at 512, v_lat at 1024 (+h*32).
// Vt[bh*32+r][2048] permuted. Out = Att[4096][512]. No-max softmax (bounded scores).
// grid (bh=32, y=32) qt=31-y (LPT); 512 thr = 2 subgroups x 4 waves, kt ≡ sg (mod 2).
__global__ __launch_bounds__(512, 8) void attn_fwd(const u16* __restrict__ QKV,
            const u16* __restrict__ Vt, u16* __restrict__ Out){
  const int bh = blockIdx.x;
  const int qt = 31 - blockIdx.y;
  const int b = bh >> 4, h = bh & 15;
  const int tid = threadIdx.x, wv = tid>>6, ln = tid&63;
  const int sg = wv>>2, wvL = wv&3;
  const int lr = ln&15, gq = ln>>4;
  __shared__ __align__(16) char SMEM[32768];
  u16* KB0 = (u16*)SMEM           + (sg*2    )*2048;   // 4 KB tiles [64 kv][32 d]
  u16* KB1 = (u16*)SMEM           + (sg*2 + 1)*2048;
  u16* VB0 = (u16*)(SMEM + 16384) + (sg*2    )*2048;   // 4 KB tiles [32 r][64 kv-perm]
  u16* VB1 = (u16*)(SMEM + 16384) + (sg*2 + 1)*2048;
  const int q0 = qt*64;
  const size_t base = (size_t)(b*2048) * 1536;
  bf16x8 qf = *(const bf16x8*)(QKV + base + (size_t)(q0 + wvL*16 + lr)*1536 + h*32 + gq*8);
  const int qglob = q0 + wvL*16 + lr;
  f32x4 o0 = {}, o1 = {};
  float l_r = 0.f;
  const u16* ksrc = QKV + base + 512 + h*32;
  const u16* vsrc = Vt + (size_t)(bh*32)*2048;

  // staging (per subgroup: 256 threads, 1 gll16 each for K and V)
  const int ci = wvL*64 + ln;
  const int rK = ci>>2, cK = 8*((ci&3) ^ (rK&3));      // K row 64B: swz bits[5:4]
  const int rV = ci>>3, cV = 8*((ci&7) ^ (rV&7));      // V row 128B: swz bits[6:4]

  int offK[4], offV[2][2];
  #pragma unroll
  for (int nt=0;nt<4;++nt)
    offK[nt] = (nt*16+lr)*64 + ((gq*16) ^ ((lr&3)<<4));
  #pragma unroll
  for (int dt=0;dt<2;++dt)
    #pragma unroll
    for (int c=0;c<2;++c)
      offV[dt][c] = (dt*16+lr)*128 + ((c*64 + gq*16) ^ ((lr&7)<<4));

  if (sg <= qt){
    gll16(ksrc + (size_t)(sg*64 + rK)*1536 + cK, KB0 + wvL*512);
    gll16(vsrc + (size_t)rV*2048 + sg*64 + cV,   VB0 + wvL*512);
  }
  __syncthreads();
  const u16* kp = ksrc + (size_t)(sg*64 + 128 + rK)*1536 + cK;
  const u16* vp = vsrc + (size_t)rV*2048 + sg*64 + 128 + cV;
  const size_t KSTEP = (size_t)128*1536;

  #define ABODY(II, KBC, VBC, KBN, VBN) do { \
    const int kt = 2*(II) + sg; \
    if (kt + 2 <= qt){ \
      gll16(kp, (KBN) + wvL*512); \
      gll16(vp, (VBN) + wvL*512); \
      kp += KSTEP; vp += 128; \
    } \
    if (kt <= qt){ \
      f32x4 s4[4] = {}; \
      __builtin_amdgcn_s_setprio(1); \
      _Pragma("unroll") for (int nt=0;nt<4;++nt){ \
        bf16x8 k0 = *(const bf16x8*)((const char*)(KBC) + offK[nt]); \
        s4[nt] = __builtin_amdgcn_mfma_f32_16x16x32_bf16(k0, qf, s4[nt], 0,0,0); \
      } \
      __builtin_amdgcn_s_setprio(0); \
      if (kt == qt){ \
        const int kv0 = kt*64; \
        _Pragma("unroll") for (int nt=0;nt<4;++nt) \
        _Pragma("unroll") for (int r=0;r<4;++r){ \
          int k = kv0 + nt*16 + 4*gq + r; \
          if (k > qglob) s4[nt][r] = -1e30f; \
        } \
      } \
      float p0,p1,p2,p3,p4,p5,p6,p7; \
      p0=__builtin_amdgcn_exp2f(s4[0][0]); p1=__builtin_amdgcn_exp2f(s4[0][1]); \
      p2=__builtin_amdgcn_exp2f(s4[0][2]); p3=__builtin_amdgcn_exp2f(s4[0][3]); \
      p4=__builtin_amdgcn_exp2f(s4[1][0]); p5=__builtin_amdgcn_exp2f(s4[1][1]); \
      p6=__builtin_amdgcn_exp2f(s4[1][2]); p7=__builtin_amdgcn_exp2f(s4[1][3]); \
      l_r += ((p0+p1)+(p2+p3)) + ((p4+p5)+(p6+p7)); \
      union { u32 u[4]; bf16x8 v; } pa0, pa1; \
      pa0.u[0]=cvtpk(p0,p1); pa0.u[1]=cvtpk(p2,p3); pa0.u[2]=cvtpk(p4,p5); pa0.u[3]=cvtpk(p6,p7); \
      p0=__builtin_amdgcn_exp2f(s4[2][0]); p1=__builtin_amdgcn_exp2f(s4[2][1]); \
      p2=__builtin_amdgcn_exp2f(s4[2][2]); p3=__builtin_amdgcn_exp2f(s4[2][3]); \
      p4=__builtin_amdgcn_exp2f(s4[3][0]); p5=__builtin_amdgcn_exp2f(s4[3][1]); \
      p6=__builtin_amdgcn_exp2f(s4[3][2]); p7=__builtin_amdgcn_exp2f(s4[3][3]); \
      l_r += ((p0+p1)+(p2+p3)) + ((p4+p5)+(p6+p7)); \
      pa1.u[0]=cvtpk(p0,p1); pa1.u[1]=cvtpk(p2,p3); pa1.u[2]=cvtpk(p4,p5); pa1.u[3]=cvtpk(p6,p7); \
      __builtin_amdgcn_s_setprio(1); \
      o0 = __builtin_amdgcn_mfma_f32_16x16x32_bf16(pa0.v, *(const bf16x8*)((const char*)(VBC) + offV[0][0]), o0, 0,0,0); \
      o1 = __builtin_amdgcn_mfma_f32_16x16x32_bf16(pa0.v, *(const bf16x8*)((const char*)(VBC) + offV[1][0]), o1, 0,0,0); \
      o0 = __builtin_amdgcn_mfma_f32_16x16x32_bf16(pa1.v, *(const bf16x8*)((const char*)(VBC) + offV[0][1]), o0, 0,0,0); \
      o1 = __builtin_amdgcn_mfma_f32_16x16x32_bf16(pa1.v, *(const bf16x8*)((const char*)(VBC) + offV[1][1]), o1, 0,0,0); \
      __builtin_amdgcn_s_setprio(0); \
    } \
    __syncthreads(); \
  } while(0)

  const int nmax = (qt + 2) >> 1;
  const int jmax = (nmax + 1) >> 1;
  for (int j = 0; j < jmax; ++j){
    ABODY(2*j,   KB0, VB0, KB1, VB1);
    ABODY(2*j+1, KB1, VB1, KB0, VB0);
  }
  l_r += __shfl_xor(l_r, 16);
  l_r += __shfl_xor(l_r, 32);

  // ---- in-LDS merge of the two partial (unnormalized) results ----
  float* MO = (float*)SMEM;               // [64][34] padded
  float* ML = (float*)(SMEM + 12288);     // l[64]
  if (sg == 1){
    #pragma unroll
    for (int r=0;r<4;++r){
      MO[(wvL*16 + 4*gq + r)*34 + lr]      = o0[r];
      MO[(wvL*16 + 4*gq + r)*34 + 16 + lr] = o1[r];
    }
    if (gq == 0) ML[wvL*16 + lr] = l_r;
  }
  __syncthreads();
  if (sg == 0){
    float lS = l_r + ML[wvL*16 + lr];
    float lS_o[4];
    #pragma unroll
    for (int r=0;r<4;++r) lS_o[r] = __shfl(lS, 4*gq + r);
    #pragma unroll
    for (int r=0;r<4;++r){
      int orow = wvL*16 + 4*gq + r;
      float v0 = (o0[r] + MO[orow*34 + lr])      / lS_o[r];
      float v1 = (o1[r] + MO[orow*34 + 16 + lr]) / lS_o[r];
      size_t ob = (size_t)(b*2048 + q0 + orow)*512 + h*32;
      Out[ob + lr]      = f2bf(v0);
      Out[ob + 16 + lr] = f2bf(v1);
    }
  }
}

// ---------- workspace layout (bytes) ----------
#define WS_B2   0u
#define WS_WT   8192u                                // 1536*1024*2 = 3145728
#define WS_W2T  (WS_WT + 3145728u)                   // 1024*512*2  = 1048576
#define WS_XB   (WS_W2T + 1048576u)                  // 4096*1024*2 = 8388608
#define WS_QKV  (WS_XB + 8388608u)                   // 4096*1536*2 = 12582912
#define WS_VT   (WS_QKV + 12582912u)                 // 1024*2048*2 = 4194304
#define WS_ATT  (WS_VT + 4194304u)                   // 4096*512*2  = 4194304

extern "C" void kernel_launch(void* const* d_in, const int* in_sizes, int n_in,
                              void* d_out, int out_size, void* d_ws, size_t ws_size,
                              hipStream_t stream) {
  const float* x  = (const float*)d_in[0];
  const float* Wa = (const float*)d_in[1];
  const float* ba = (const float*)d_in[2];
  const float* Wp = (const float*)d_in[3];
  const float* bp = (const float*)d_in[4];
  const float* kc = (const float*)d_in[5];
  const float* ke = (const float*)d_in[6];
  const float* vc = (const float*)d_in[7];
  const float* ve = (const float*)d_in[8];
  float* out = (float*)d_out;
  char* ws = (char*)d_ws;
  float* b2  = (float*)(ws + WS_B2);
  u16* Wt    = (u16*)(ws + WS_WT);
  u16* W2t   = (u16*)(ws + WS_W2T);
  u16* Xb    = (u16*)(ws + WS_XB);
  u16* QKVb  = (u16*)(ws + WS_QKV);
  u16* Vt    = (u16*)(ws + WS_VT);
  u16* Att   = (u16*)(ws + WS_ATT);

  fold_qkv<<<dim3(4,16,3), 256, 0, stream>>>(Wa, kc, ke, vc, Wt);
  fold_bias<<<6, 256, 0, stream>>>(ba, kc, ke, vc, b2);
  fold_proj<<<dim3(8,16), 256, 0, stream>>>(Wp, ve, W2t);
  convert_x<<<4096, 256, 0, stream>>>(x, Xb, 1048576);
  gemm_bt<u16><<<dim3(32,12), 256, 0, stream>>>(Xb, Wt, b2, QKVb, 4096, 1536, 1024, 1536);
  v_transpose_lat<<<dim3(32,32), 256, 0, stream>>>(QKVb, Vt);
  attn_fwd<<<dim3(32,32), 512, 0, stream>>>(QKVb, Vt, Att);
  gemm_bt<float><<<dim3(32,8), 256, 0, stream>>>(Att, W2t, bp, out, 4096, 1024, 512, 1024);
}

// Round 9
// 103.060 us; speedup vs baseline: 2.4501x; 1.0811x over previous
//
#include <hip/hip_runtime.h>
#include <cstddef>

typedef __attribute__((ext_vector_type(8))) __bf16 bf16x8;
typedef __attribute__((ext_vector_type(4))) float f32x4;
typedef unsigned short u16;
typedef unsigned int   u32;

#define SCLF (0.125f * 1.44269504f)   // softmax scale * log2(e), folded into q' weights

// ---------- helpers ----------
__device__ __forceinline__ u16 f2bf(float f){
  union { float f; u32 u; } v; v.f = f;
  u32 r = v.u + 0x7FFFu + ((v.u >> 16) & 1u);   // RNE
  return (u16)(r >> 16);
}
__device__ __forceinline__ u32 cvtpk(float lo, float hi){
  u32 r; asm("v_cvt_pk_bf16_f32 %0, %1, %2" : "=v"(r) : "v"(lo), "v"(hi)); return r;
}
__device__ __forceinline__ void gll16(const void* g, void* l){
  __builtin_amdgcn_global_load_lds((__attribute__((address_space(1))) void*)g,
                                   (__attribute__((address_space(3))) void*)l, 16, 0, 0);
}

// ---------- fold: attn weights -> latent space (Bt layout [1536][1024] bf16) ----------
// part 0: q'  rows  h*32+r       = sum_d Wa[c][h*64+d]      * wk_e[r][d]  * SCLF
// part 1: k_lat rows 512+h*32+r  = sum_d Wa[c][1024+h*64+d] * wk_c[d][r]
// part 2: v_lat rows 1024+h*32+r = sum_d Wa[c][2048+h*64+d] * wv_c[d][r]
// Coalesced: Wa tile staged via LDS (wave-contiguous 256B row reads).
__global__ __launch_bounds__(256) void fold_qkv(const float* __restrict__ Wa,
      const float* __restrict__ kc, const float* __restrict__ ke,
      const float* __restrict__ vc, u16* __restrict__ Wt){
  __shared__ float WaL[64*65];  // [c][d] pad 65 -> bank (c+d)%32, 2-way free
  __shared__ float Ws[2048];    // [d][r]
  const int cc = blockIdx.x, h = blockIdx.y, part = blockIdx.z;
  const int tid = threadIdx.x;
  #pragma unroll
  for (int i=0;i<8;++i){
    int idx = tid + i*256; int d = idx>>5, r = idx&31;
    Ws[idx] = (part==0) ? ke[r*64+d] : (part==1) ? kc[idx] : vc[idx];
  }
  const int c0 = cc*64, off = part*1024 + h*64;
  {
    int col = tid & 63, rbase = tid >> 6;     // wave reads 64 consecutive floats of a row
    #pragma unroll
    for (int i=0;i<16;++i){
      int row = i*4 + rbase;
      WaL[row*65 + col] = Wa[(size_t)(c0+row)*3072 + off + col];
    }
  }
  __syncthreads();
  const int c = tid & 63, rg = tid >> 6;      // wave-uniform rg -> Ws reads broadcast
  float acc[8] = {};
  for (int d=0; d<64; ++d){
    float a = WaL[c*65 + d];
    #pragma unroll
    for (int rr=0;rr<8;++rr) acc[rr] += a * Ws[d*32 + rg*8 + rr];
  }
  const float scl = (part==0) ? SCLF : 1.f;
  const int nbase = part*512 + h*32 + rg*8;
  #pragma unroll
  for (int rr=0;rr<8;++rr)
    Wt[(size_t)(nbase+rr)*1024 + c0 + c] = f2bf(acc[rr]*scl);
}

// ---------- fold: bias -> latent (b2[1536]) ----------
__global__ void fold_bias(const float* __restrict__ ba, const float* __restrict__ kc,
                          const float* __restrict__ ke, const float* __restrict__ vc,
                          float* __restrict__ b2){
  int n = blockIdx.x*256 + threadIdx.x;
  if (n >= 1536) return;
  int part = n>>9, h = (n>>5)&15, r = n&31;
  const float* bs = ba + part*1024 + h*64;
  float acc = 0.f;
  for (int d=0;d<64;++d){
    float w = (part==0) ? ke[r*64+d] : (part==1) ? kc[d*32+r] : vc[d*32+r];
    acc += bs[d]*w;
  }
  b2[n] = acc * ((part==0) ? SCLF : 1.f);
}

// ---------- fold: proj weights W2t[j][h*32+r] = sum_d wv_e[r][d]*Wp[h*64+d][j] ----------
__global__ __launch_bounds__(256) void fold_proj(const float* __restrict__ Wp,
      const float* __restrict__ ve, u16* __restrict__ W2t){
  __shared__ float WpL[8192];   // [64 d][128 j]
  __shared__ float WeL[2048];   // [32 r][64 d]
  int jc = blockIdx.x, h = blockIdx.y;
  int tid = threadIdx.x;
  #pragma unroll
  for (int i=0;i<32;++i){
    int idx = tid + i*256; int d = idx>>7, jj = idx&127;
    WpL[idx] = Wp[(size_t)(h*64+d)*1024 + jc*128 + jj];
  }
  #pragma unroll
  for (int i=0;i<8;++i) WeL[tid + i*256] = ve[tid + i*256];
  __syncthreads();
  int jj = tid & 127, rg = tid >> 7;
  float out[16] = {};
  #pragma unroll
  for (int d=0; d<64; ++d){
    float pv = WpL[d*128 + jj];
    #pragma unroll
    for (int rr=0; rr<16; ++rr) out[rr] += WeL[(rg*16+rr)*64 + d] * pv;
  }
  #pragma unroll
  for (int rr=0; rr<16; ++rr)
    W2t[(size_t)(jc*128 + jj)*512 + h*32 + rg*16 + rr] = f2bf(out[rr]);
}

// ---------- prep: x fp32 -> bf16 ----------
__global__ void convert_x(const float* __restrict__ x, u16* __restrict__ o, int n4){
  int i = blockIdx.x*blockDim.x + threadIdx.x;
  if (i >= n4) return;
  float4 v = ((const float4*)x)[i];
  ushort4 r; r.x = f2bf(v.x); r.y = f2bf(v.y); r.z = f2bf(v.z); r.w = f2bf(v.w);
  ((ushort4*)o)[i] = r;
}

// ---------- V transpose (latent): QKV' v_lat part -> Vt[bh*32+r][t], k-slot-permuted ----------
__global__ __launch_bounds__(256) void v_transpose_lat(const u16* __restrict__ QKV,
      u16* __restrict__ Vt){
  __shared__ u16 tile[64][40];   // [t][r] padded
  int tt = blockIdx.x, bh = blockIdx.y;
  int b = bh>>4, h = bh&15;
  int tid = threadIdx.x;
  int row = tid>>2, cc2 = (tid&3)*8;
  const u16* src = QKV + (size_t)(b*2048 + tt*64 + row)*1536 + 1024 + h*32 + cc2;
  *(uint4*)&tile[row][cc2] = *(const uint4*)src;
  __syncthreads();
  int r = tid>>3, pc = (tid&7)*8;
  u16 vals[8];
  #pragma unroll
  for (int i=0;i<8;++i){
    int p = pc+i; int c = p>>5, q = p&31, g = q>>3, j = q&7;
    int o = c*32 + 16*(j>>2) + 4*g + (j&3);
    vals[i] = tile[o][r];
  }
  u16* drow = Vt + (size_t)(bh*32 + r)*2048 + tt*64 + pc;
  *(uint4*)drow = *(const uint4*)&vals[0];
}

// ---------- 128x128 bf16 GEMM (2-phase): C[M,N] = A[M,K]*Bt[N,K]^T + bias ----------
template<typename OT>
__global__ __launch_bounds__(256) void gemm_bt(const u16* __restrict__ A, const u16* __restrict__ Bt,
        const float* __restrict__ bias, OT* __restrict__ C, int M, int N, int K, int ldc){
  __shared__ u16 As[128*64];
  __shared__ u16 Bs[128*64];
  const int nwg = gridDim.x * gridDim.y;
  const int id  = blockIdx.x + gridDim.x * blockIdx.y;
  const int nid = (id & 7) * (nwg >> 3) + (id >> 3);   // nwg % 8 == 0
  const int bx = nid % gridDim.x, by = nid / gridDim.x;
  const int tid = threadIdx.x, wv = tid>>6, ln = tid&63;
  const int lr = ln&15, g8 = (ln>>4)*8;
  const int m0 = bx*128, n0 = by*128;
  const int wr = (wv>>1)*64, wc = (wv&1)*64;
  f32x4 acc[4][4] = {};
  const int nk = K >> 6;
  for (int kt=0; kt<nk; ++kt){
    #pragma unroll
    for (int it=0; it<4; ++it){
      int chunk = wv*4+it;
      int row = chunk*8 + (ln>>3), colc = (ln&7)*8;
      gll16(A  + (size_t)(m0+row)*K + kt*64 + colc, &As[chunk*512]);
      gll16(Bt + (size_t)(n0+row)*K + kt*64 + colc, &Bs[chunk*512]);
    }
    __syncthreads();
    #pragma unroll
    for (int ks=0; ks<2; ++ks){
      bf16x8 af[4], bfr[4];
      #pragma unroll
      for (int mt=0;mt<4;++mt) af[mt]  = *(const bf16x8*)&As[(wr+mt*16+lr)*64 + ks*32 + g8];
      #pragma unroll
      for (int nt=0;nt<4;++nt) bfr[nt] = *(const bf16x8*)&Bs[(wc+nt*16+lr)*64 + ks*32 + g8];
      #pragma unroll
      for (int mt=0;mt<4;++mt)
        #pragma unroll
        for (int nt=0;nt<4;++nt)
          acc[mt][nt] = __builtin_amdgcn_mfma_f32_16x16x32_bf16(af[mt], bfr[nt], acc[mt][nt], 0,0,0);
    }
    __syncthreads();
  }
  #pragma unroll
  for (int mt=0;mt<4;++mt){
    int row = m0 + wr + mt*16 + 4*(ln>>4);
    #pragma unroll
    for (int nt=0;nt<4;++nt){
      int col = n0 + wc + nt*16 + lr;
      float bv = bias[col];
      #pragma unroll
      for (int r=0;r<4;++r){
        float v = acc[mt][nt][r] + bv;
        if constexpr (sizeof(OT) == 2) C[(size_t)(row+r)*ldc + col] = f2bf(v);
        else                           C[(size_t)(row+r)*ldc + col] = v;
      }
    }
  }
}

// ---------- causal flash attention in rank-32 latent space ----------
// QKV'[4096][1536]: q' (SCLF-scaled) at 0, k_lat at 512, v_lat at 1024 (+h*32).
// Vt[bh*32+r][2048] permuted. Out = Att[4096][512]. No-max softmax (bounded scores).
// grid (bh=32, y=32) qt=31-y (LPT); 512 thr = 2 subgroups x 4 waves, kt ≡ sg (mod 2).
__global__ __launch_bounds__(512, 8) void attn_fwd(const u16* __restrict__ QKV,
            const u16* __restrict__ Vt, u16* __restrict__ Out){
  const int bh = blockIdx.x;
  const int qt = 31 - blockIdx.y;
  const int b = bh >> 4, h = bh & 15;
  const int tid = threadIdx.x, wv = tid>>6, ln = tid&63;
  const int sg = wv>>2, wvL = wv&3;
  const int lr = ln&15, gq = ln>>4;
  __shared__ __align__(16) char SMEM[32768];
  u16* KB0 = (u16*)SMEM           + (sg*2    )*2048;   // 4 KB tiles [64 kv][32 d]
  u16* KB1 = (u16*)SMEM           + (sg*2 + 1)*2048;
  u16* VB0 = (u16*)(SMEM + 16384) + (sg*2    )*2048;   // 4 KB tiles [32 r][64 kv-perm]
  u16* VB1 = (u16*)(SMEM + 16384) + (sg*2 + 1)*2048;
  const int q0 = qt*64;
  const size_t base = (size_t)(b*2048) * 1536;
  bf16x8 qf = *(const bf16x8*)(QKV + base + (size_t)(q0 + wvL*16 + lr)*1536 + h*32 + gq*8);
  const int qglob = q0 + wvL*16 + lr;
  f32x4 o0 = {}, o1 = {};
  float l_r = 0.f;
  const u16* ksrc = QKV + base + 512 + h*32;
  const u16* vsrc = Vt + (size_t)(bh*32)*2048;

  // staging (per subgroup: 256 threads, 1 gll16 each for K and V)
  const int ci = wvL*64 + ln;
  const int rK = ci>>2, cK = 8*((ci&3) ^ (rK&3));      // K row 64B: swz bits[5:4]
  const int rV = ci>>3, cV = 8*((ci&7) ^ (rV&7));      // V row 128B: swz bits[6:4]

  int offK[4], offV[2][2];
  #pragma unroll
  for (int nt=0;nt<4;++nt)
    offK[nt] = (nt*16+lr)*64 + ((gq*16) ^ ((lr&3)<<4));
  #pragma unroll
  for (int dt=0;dt<2;++dt)
    #pragma unroll
    for (int c=0;c<2;++c)
      offV[dt][c] = (dt*16+lr)*128 + ((c*64 + gq*16) ^ ((lr&7)<<4));

  if (sg <= qt){
    gll16(ksrc + (size_t)(sg*64 + rK)*1536 + cK, KB0 + wvL*512);
    gll16(vsrc + (size_t)rV*2048 + sg*64 + cV,   VB0 + wvL*512);
  }
  __syncthreads();
  const u16* kp = ksrc + (size_t)(sg*64 + 128 + rK)*1536 + cK;
  const u16* vp = vsrc + (size_t)rV*2048 + sg*64 + 128 + cV;
  const size_t KSTEP = (size_t)128*1536;

  #define ABODY(II, KBC, VBC, KBN, VBN) do { \
    const int kt = 2*(II) + sg; \
    if (kt + 2 <= qt){ \
      gll16(kp, (KBN) + wvL*512); \
      gll16(vp, (VBN) + wvL*512); \
      kp += KSTEP; vp += 128; \
    } \
    if (kt <= qt){ \
      f32x4 s4[4] = {}; \
      __builtin_amdgcn_s_setprio(1); \
      _Pragma("unroll") for (int nt=0;nt<4;++nt){ \
        bf16x8 k0 = *(const bf16x8*)((const char*)(KBC) + offK[nt]); \
        s4[nt] = __builtin_amdgcn_mfma_f32_16x16x32_bf16(k0, qf, s4[nt], 0,0,0); \
      } \
      __builtin_amdgcn_s_setprio(0); \
      if (kt == qt){ \
        const int kv0 = kt*64; \
        _Pragma("unroll") for (int nt=0;nt<4;++nt) \
        _Pragma("unroll") for (int r=0;r<4;++r){ \
          int k = kv0 + nt*16 + 4*gq + r; \
          if (k > qglob) s4[nt][r] = -1e30f; \
        } \
      } \
      float p0,p1,p2,p3,p4,p5,p6,p7; \
      p0=__builtin_amdgcn_exp2f(s4[0][0]); p1=__builtin_amdgcn_exp2f(s4[0][1]); \
      p2=__builtin_amdgcn_exp2f(s4[0][2]); p3=__builtin_amdgcn_exp2f(s4[0][3]); \
      p4=__builtin_amdgcn_exp2f(s4[1][0]); p5=__builtin_amdgcn_exp2f(s4[1][1]); \
      p6=__builtin_amdgcn_exp2f(s4[1][2]); p7=__builtin_amdgcn_exp2f(s4[1][3]); \
      l_r += ((p0+p1)+(p2+p3)) + ((p4+p5)+(p6+p7)); \
      union { u32 u[4]; bf16x8 v; } pa0, pa1; \
      pa0.u[0]=cvtpk(p0,p1); pa0.u[1]=cvtpk(p2,p3); pa0.u[2]=cvtpk(p4,p5); pa0.u[3]=cvtpk(p6,p7); \
      p0=__builtin_amdgcn_exp2f(s4[2][0]); p1=__builtin_amdgcn_exp2f(s4[2][1]); \
      p2=__builtin_amdgcn_exp2f(s4[2][2]); p3=__builtin_amdgcn_exp2f(s4[2][3]); \
      p4=__builtin_amdgcn_exp2f(s4[3][0]); p5=__builtin_amdgcn_exp2f(s4[3][1]); \
      p6=__builtin_amdgcn_exp2f(s4[3][2]); p7=__builtin_amdgcn_exp2f(s4[3][3]); \
      l_r += ((p0+p1)+(p2+p3)) + ((p4+p5)+(p6+p7)); \
      pa1.u[0]=cvtpk(p0,p1); pa1.u[1]=cvtpk(p2,p3); pa1.u[2]=cvtpk(p4,p5); pa1.u[3]=cvtpk(p6,p7); \
      __builtin_amdgcn_s_setprio(1); \
      o0 = __builtin_amdgcn_mfma_f32_16x16x32_bf16(pa0.v, *(const bf16x8*)((const char*)(VBC) + offV[0][0]), o0, 0,0,0); \
      o1 = __builtin_amdgcn_mfma_f32_16x16x32_bf16(pa0.v, *(const bf16x8*)((const char*)(VBC) + offV[1][0]), o1, 0,0,0); \
      o0 = __builtin_amdgcn_mfma_f32_16x16x32_bf16(pa1.v, *(const bf16x8*)((const char*)(VBC) + offV[0][1]), o0, 0,0,0); \
      o1 = __builtin_amdgcn_mfma_f32_16x16x32_bf16(pa1.v, *(const bf16x8*)((const char*)(VBC) + offV[1][1]), o1, 0,0,0); \
      __builtin_amdgcn_s_setprio(0); \
    } \
    __syncthreads(); \
  } while(0)

  const int nmax = (qt + 2) >> 1;
  const int jmax = (nmax + 1) >> 1;
  for (int j = 0; j < jmax; ++j){
    ABODY(2*j,   KB0, VB0, KB1, VB1);
    ABODY(2*j+1, KB1, VB1, KB0, VB0);
  }
  l_r += __shfl_xor(l_r, 16);
  l_r += __shfl_xor(l_r, 32);

  // ---- in-LDS merge of the two partial (unnormalized) results ----
  float* MO = (float*)SMEM;               // [64][34] padded
  float* ML = (float*)(SMEM + 12288);     // l[64]
  if (sg == 1){
    #pragma unroll
    for (int r=0;r<4;++r){
      MO[(wvL*16 + 4*gq + r)*34 + lr]      = o0[r];
      MO[(wvL*16 + 4*gq + r)*34 + 16 + lr] = o1[r];
    }
    if (gq == 0) ML[wvL*16 + lr] = l_r;
  }
  __syncthreads();
  if (sg == 0){
    float lS = l_r + ML[wvL*16 + lr];
    float lS_o[4];
    #pragma unroll
    for (int r=0;r<4;++r) lS_o[r] = __shfl(lS, 4*gq + r);
    #pragma unroll
    for (int r=0;r<4;++r){
      int orow = wvL*16 + 4*gq + r;
      float v0 = (o0[r] + MO[orow*34 + lr])      / lS_o[r];
      float v1 = (o1[r] + MO[orow*34 + 16 + lr]) / lS_o[r];
      size_t ob = (size_t)(b*2048 + q0 + orow)*512 + h*32;
      Out[ob + lr]      = f2bf(v0);
      Out[ob + 16 + lr] = f2bf(v1);
    }
  }
}

// ---------- workspace layout (bytes) ----------
#define WS_B2   0u
#define WS_WT   8192u                                // 1536*1024*2 = 3145728
#define WS_W2T  (WS_WT + 3145728u)                   // 1024*512*2  = 1048576
#define WS_XB   (WS_W2T + 1048576u)                  // 4096*1024*2 = 8388608
#define WS_QKV  (WS_XB + 8388608u)                   // 4096*1536*2 = 12582912
#define WS_VT   (WS_QKV + 12582912u)                 // 1024*2048*2 = 4194304
#define WS_ATT  (WS_VT + 4194304u)                   // 4096*512*2  = 4194304

extern "C" void kernel_launch(void* const* d_in, const int* in_sizes, int n_in,
                              void* d_out, int out_size, void* d_ws, size_t ws_size,
                              hipStream_t stream) {
  const float* x  = (const float*)d_in[0];
  const float* Wa = (const float*)d_in[1];
  const float* ba = (const float*)d_in[2];
  const float* Wp = (const float*)d_in[3];
  const float* bp = (const float*)d_in[4];
  const float* kc = (const float*)d_in[5];
  const float* ke = (const float*)d_in[6];
  const float* vc = (const float*)d_in[7];
  const float* ve = (const float*)d_in[8];
  float* out = (float*)d_out;
  char* ws = (char*)d_ws;
  float* b2  = (float*)(ws + WS_B2);
  u16* Wt    = (u16*)(ws + WS_WT);
  u16* W2t   = (u16*)(ws + WS_W2T);
  u16* Xb    = (u16*)(ws + WS_XB);
  u16* QKVb  = (u16*)(ws + WS_QKV);
  u16* Vt    = (u16*)(ws + WS_VT);
  u16* Att   = (u16*)(ws + WS_ATT);

  fold_qkv<<<dim3(16,16,3), 256, 0, stream>>>(Wa, kc, ke, vc, Wt);
  fold_bias<<<6, 256, 0, stream>>>(ba, kc, ke, vc, b2);
  fold_proj<<<dim3(8,16), 256, 0, stream>>>(Wp, ve, W2t);
  convert_x<<<4096, 256, 0, stream>>>(x, Xb, 1048576);
  gemm_bt<u16><<<dim3(32,12), 256, 0, stream>>>(Xb, Wt, b2, QKVb, 4096, 1536, 1024, 1536);
  v_transpose_lat<<<dim3(32,32), 256, 0, stream>>>(QKVb, Vt);
  attn_fwd<<<dim3(32,32), 512, 0, stream>>>(QKVb, Vt, Att);
  gemm_bt<float><<<dim3(32,8), 256, 0, stream>>>(Att, W2t, bp, out, 4096, 1024, 512, 1024);
}

// Round 10
// 86.202 us; speedup vs baseline: 2.9293x; 1.1956x over previous
//
#include <hip/hip_runtime.h>
#include <cstddef>

typedef __attribute__((ext_vector_type(8))) __bf16 bf16x8;
typedef __attribute__((ext_vector_type(4))) float f32x4;
typedef unsigned short u16;
typedef unsigned int   u32;

#define SCLF (0.125f * 1.44269504f)   // softmax scale * log2(e), folded into q' weights

// ---------- helpers ----------
__device__ __forceinline__ u16 f2bf(float f){
  union { float f; u32 u; } v; v.f = f;
  u32 r = v.u + 0x7FFFu + ((v.u >> 16) & 1u);   // RNE
  return (u16)(r >> 16);
}
__device__ __forceinline__ u32 cvtpk(float lo, float hi){
  u32 r; asm("v_cvt_pk_bf16_f32 %0, %1, %2" : "=v"(r) : "v"(lo), "v"(hi)); return r;
}
__device__ __forceinline__ void gll16(const void* g, void* l){
  __builtin_amdgcn_global_load_lds((__attribute__((address_space(1))) void*)g,
                                   (__attribute__((address_space(3))) void*)l, 16, 0, 0);
}

// ---------- fused prep: fold_qkv (768) | fold_proj (128) | convert_x (1024) | fold_bias (6) ----------
__global__ __launch_bounds__(256) void prep_all(const float* __restrict__ x,
      const float* __restrict__ Wa, const float* __restrict__ ba, const float* __restrict__ Wp,
      const float* __restrict__ kc, const float* __restrict__ ke,
      const float* __restrict__ vc, const float* __restrict__ ve,
      u16* __restrict__ Wt, float* __restrict__ b2, u16* __restrict__ W2t,
      u16* __restrict__ Xb){
  __shared__ __align__(16) char PS[40960];
  const int bid = blockIdx.x, tid = threadIdx.x;
  if (bid < 768){
    // fold attn weights -> latent [1536][1024] bf16 (Bt layout)
    float* WaL = (float*)PS;             // [64][65]
    float* Ws  = (float*)(PS + 16640);   // [64 d][32 r]
    const int part = bid >> 8, rem = bid & 255, h = rem >> 4, cc = rem & 15;
    #pragma unroll
    for (int i=0;i<8;++i){
      int idx = tid + i*256; int d = idx>>5, r = idx&31;
      Ws[idx] = (part==0) ? ke[r*64+d] : (part==1) ? kc[idx] : vc[idx];
    }
    const int c0 = cc*64, off = part*1024 + h*64;
    {
      int col = tid & 63, rbase = tid >> 6;
      #pragma unroll
      for (int i=0;i<16;++i){
        int row = i*4 + rbase;
        WaL[row*65 + col] = Wa[(size_t)(c0+row)*3072 + off + col];
      }
    }
    __syncthreads();
    const int c = tid & 63, rg = tid >> 6;
    float acc[8] = {};
    for (int d=0; d<64; ++d){
      float a = WaL[c*65 + d];
      #pragma unroll
      for (int rr=0;rr<8;++rr) acc[rr] += a * Ws[d*32 + rg*8 + rr];
    }
    const float scl = (part==0) ? SCLF : 1.f;
    const int nbase = part*512 + h*32 + rg*8;
    #pragma unroll
    for (int rr=0;rr<8;++rr)
      Wt[(size_t)(nbase+rr)*1024 + c0 + c] = f2bf(acc[rr]*scl);
  } else if (bid < 896){
    // fold proj weights: W2t[j][h*32+r] = sum_d wv_e[r][d]*Wp[h*64+d][j]
    float* WpL = (float*)PS;             // [64 d][128 j]
    float* WeL = (float*)(PS + 32768);   // [32 r][64 d]
    const int idx2 = bid - 768, jc = idx2 & 7, h = idx2 >> 3;
    #pragma unroll
    for (int i=0;i<32;++i){
      int idx = tid + i*256; int d = idx>>7, jj = idx&127;
      WpL[idx] = Wp[(size_t)(h*64+d)*1024 + jc*128 + jj];
    }
    #pragma unroll
    for (int i=0;i<8;++i) WeL[tid + i*256] = ve[tid + i*256];
    __syncthreads();
    const int jj = tid & 127, rg = tid >> 7;
    float out[16] = {};
    #pragma unroll
    for (int d=0; d<64; ++d){
      float pv = WpL[d*128 + jj];
      #pragma unroll
      for (int rr=0; rr<16; ++rr) out[rr] += WeL[(rg*16+rr)*64 + d] * pv;
    }
    #pragma unroll
    for (int rr=0; rr<16; ++rr)
      W2t[(size_t)(jc*128 + jj)*512 + h*32 + rg*16 + rr] = f2bf(out[rr]);
  } else if (bid < 1920){
    // x fp32 -> bf16 (4 float4 per thread)
    const int i0 = (bid - 896)*1024 + tid;
    #pragma unroll
    for (int t=0;t<4;++t){
      int i = i0 + t*256;
      float4 v = ((const float4*)x)[i];
      ushort4 r; r.x = f2bf(v.x); r.y = f2bf(v.y); r.z = f2bf(v.z); r.w = f2bf(v.w);
      ((ushort4*)Xb)[i] = r;
    }
  } else {
    // bias -> latent b2[1536]
    int n = (bid - 1920)*256 + tid;
    int part = n>>9, h = (n>>5)&15, r = n&31;
    const float* bs = ba + part*1024 + h*64;
    float acc = 0.f;
    for (int d=0;d<64;++d){
      float w = (part==0) ? ke[r*64+d] : (part==1) ? kc[d*32+r] : vc[d*32+r];
      acc += bs[d]*w;
    }
    b2[n] = acc * ((part==0) ? SCLF : 1.f);
  }
}

// ---------- V transpose (latent): QKV' v_lat part -> Vt[bh*32+r][t], k-slot-permuted ----------
__global__ __launch_bounds__(256) void v_transpose_lat(const u16* __restrict__ QKV,
      u16* __restrict__ Vt){
  __shared__ u16 tile[64][40];   // [t][r] padded
  int tt = blockIdx.x, bh = blockIdx.y;
  int b = bh>>4, h = bh&15;
  int tid = threadIdx.x;
  int row = tid>>2, cc2 = (tid&3)*8;
  const u16* src = QKV + (size_t)(b*2048 + tt*64 + row)*1536 + 1024 + h*32 + cc2;
  *(uint4*)&tile[row][cc2] = *(const uint4*)src;
  __syncthreads();
  int r = tid>>3, pc = (tid&7)*8;
  u16 vals[8];
  #pragma unroll
  for (int i=0;i<8;++i){
    int p = pc+i; int c = p>>5, q = p&31, g = q>>3, j = q&7;
    int o = c*32 + 16*(j>>2) + 4*g + (j&3);
    vals[i] = tile[o][r];
  }
  u16* drow = Vt + (size_t)(bh*32 + r)*2048 + tt*64 + pc;
  *(uint4*)drow = *(const uint4*)&vals[0];
}

// ---------- 64x128 bf16 GEMM (2-phase): C[M,N] = A[M,K]*Bt[N,K]^T + bias ----------
// 4 waves, each 32x64 output; 24 KB LDS; perfect-fill grids (768 / 512 blocks).
template<typename OT>
__global__ __launch_bounds__(256) void gemm64(const u16* __restrict__ A, const u16* __restrict__ Bt,
        const float* __restrict__ bias, OT* __restrict__ C, int M, int N, int K, int ldc){
  __shared__ u16 As[64*64];     // 8 chunks
  __shared__ u16 Bs[128*64];    // 16 chunks
  const int nwg = gridDim.x * gridDim.y;
  const int id  = blockIdx.x + gridDim.x * blockIdx.y;
  const int nid = (id & 7) * (nwg >> 3) + (id >> 3);   // nwg % 8 == 0
  const int bx = nid % gridDim.x, by = nid / gridDim.x;
  const int tid = threadIdx.x, wv = tid>>6, ln = tid&63;
  const int lr = ln&15, g8 = (ln>>4)*8;
  const int m0 = bx*64, n0 = by*128;
  const int wr = (wv>>1)*32, wc = (wv&1)*64;
  const int lrow = ln>>3, lcol = (ln&7)*8;
  f32x4 acc[2][4] = {};
  const int nk = K >> 6;
  for (int kt=0; kt<nk; ++kt){
    #pragma unroll
    for (int it=0; it<6; ++it){
      int chunk = wv*6 + it;                  // 0..23: first 8 A, rest B
      if (chunk < 8){
        int row = chunk*8 + lrow;
        gll16(A + (size_t)(m0+row)*K + kt*64 + lcol, &As[chunk*512]);
      } else {
        int bc = chunk - 8;
        int row = bc*8 + lrow;
        gll16(Bt + (size_t)(n0+row)*K + kt*64 + lcol, &Bs[bc*512]);
      }
    }
    __syncthreads();
    #pragma unroll
    for (int ks=0; ks<2; ++ks){
      bf16x8 af[2], bfr[4];
      #pragma unroll
      for (int mt=0;mt<2;++mt) af[mt]  = *(const bf16x8*)&As[(wr+mt*16+lr)*64 + ks*32 + g8];
      #pragma unroll
      for (int nt=0;nt<4;++nt) bfr[nt] = *(const bf16x8*)&Bs[(wc+nt*16+lr)*64 + ks*32 + g8];
      #pragma unroll
      for (int mt=0;mt<2;++mt)
        #pragma unroll
        for (int nt=0;nt<4;++nt)
          acc[mt][nt] = __builtin_amdgcn_mfma_f32_16x16x32_bf16(af[mt], bfr[nt], acc[mt][nt], 0,0,0);
    }
    __syncthreads();
  }
  #pragma unroll
  for (int mt=0;mt<2;++mt){
    int row = m0 + wr + mt*16 + 4*(ln>>4);
    #pragma unroll
    for (int nt=0;nt<4;++nt){
      int col = n0 + wc + nt*16 + lr;
      float bv = bias[col];
      #pragma unroll
      for (int r=0;r<4;++r){
        float v = acc[mt][nt][r] + bv;
        if constexpr (sizeof(OT) == 2) C[(size_t)(row+r)*ldc + col] = f2bf(v);
        else                           C[(size_t)(row+r)*ldc + col] = v;
      }
    }
  }
}

// ---------- causal flash attention in rank-32 latent space ----------
// QKV'[4096][1536]: q' (SCLF-scaled) at 0, k_lat at 512, v_lat at 1024 (+h*32).
// Vt[bh*32+r][2048] permuted. Out = Att[4096][512]. No-max softmax (bounded scores).
// grid (bh=32, y=32) qt=31-y (LPT); 512 thr = 2 subgroups x 4 waves, kt ≡ sg (mod 2).
__global__ __launch_bounds__(512, 8) void attn_fwd(const u16* __restrict__ QKV,
            const u16* __restrict__ Vt, u16* __restrict__ Out){
  const int bh = blockIdx.x;
  const int qt = 31 - blockIdx.y;
  const int b = bh >> 4, h = bh & 15;
  const int tid = threadIdx.x, wv = tid>>6, ln = tid&63;
  const int sg = wv>>2, wvL = wv&3;
  const int lr = ln&15, gq = ln>>4;
  __shared__ __align__(16) char SMEM[32768];
  u16* KB0 = (u16*)SMEM           + (sg*2    )*2048;   // 4 KB tiles [64 kv][32 d]
  u16* KB1 = (u16*)SMEM           + (sg*2 + 1)*2048;
  u16* VB0 = (u16*)(SMEM + 16384) + (sg*2    )*2048;   // 4 KB tiles [32 r][64 kv-perm]
  u16* VB1 = (u16*)(SMEM + 16384) + (sg*2 + 1)*2048;
  const int q0 = qt*64;
  const size_t base = (size_t)(b*2048) * 1536;
  bf16x8 qf = *(const bf16x8*)(QKV + base + (size_t)(q0 + wvL*16 + lr)*1536 + h*32 + gq*8);
  const int qglob = q0 + wvL*16 + lr;
  f32x4 o0 = {}, o1 = {};
  float l_r = 0.f;
  const u16* ksrc = QKV + base + 512 + h*32;
  const u16* vsrc = Vt + (size_t)(bh*32)*2048;

  // staging (per subgroup: 256 threads, 1 gll16 each for K and V)
  const int ci = wvL*64 + ln;
  const int rK = ci>>2, cK = 8*((ci&3) ^ (rK&3));      // K row 64B: swz bits[5:4]
  const int rV = ci>>3, cV = 8*((ci&7) ^ (rV&7));      // V row 128B: swz bits[6:4]

  int offK[4], offV[2][2];
  #pragma unroll
  for (int nt=0;nt<4;++nt)
    offK[nt] = (nt*16+lr)*64 + ((gq*16) ^ ((lr&3)<<4));
  #pragma unroll
  for (int dt=0;dt<2;++dt)
    #pragma unroll
    for (int c=0;c<2;++c)
      offV[dt][c] = (dt*16+lr)*128 + ((c*64 + gq*16) ^ ((lr&7)<<4));

  if (sg <= qt){
    gll16(ksrc + (size_t)(sg*64 + rK)*1536 + cK, KB0 + wvL*512);
    gll16(vsrc + (size_t)rV*2048 + sg*64 + cV,   VB0 + wvL*512);
  }
  __syncthreads();
  const u16* kp = ksrc + (size_t)(sg*64 + 128 + rK)*1536 + cK;
  const u16* vp = vsrc + (size_t)rV*2048 + sg*64 + 128 + cV;
  const size_t KSTEP = (size_t)128*1536;

  #define ABODY(II, KBC, VBC, KBN, VBN) do { \
    const int kt = 2*(II) + sg; \
    if (kt + 2 <= qt){ \
      gll16(kp, (KBN) + wvL*512); \
      gll16(vp, (VBN) + wvL*512); \
      kp += KSTEP; vp += 128; \
    } \
    if (kt <= qt){ \
      f32x4 s4[4] = {}; \
      __builtin_amdgcn_s_setprio(1); \
      _Pragma("unroll") for (int nt=0;nt<4;++nt){ \
        bf16x8 k0 = *(const bf16x8*)((const char*)(KBC) + offK[nt]); \
        s4[nt] = __builtin_amdgcn_mfma_f32_16x16x32_bf16(k0, qf, s4[nt], 0,0,0); \
      } \
      __builtin_amdgcn_s_setprio(0); \
      if (kt == qt){ \
        const int kv0 = kt*64; \
        _Pragma("unroll") for (int nt=0;nt<4;++nt) \
        _Pragma("unroll") for (int r=0;r<4;++r){ \
          int k = kv0 + nt*16 + 4*gq + r; \
          if (k > qglob) s4[nt][r] = -1e30f; \
        } \
      } \
      float p0,p1,p2,p3,p4,p5,p6,p7; \
      p0=__builtin_amdgcn_exp2f(s4[0][0]); p1=__builtin_amdgcn_exp2f(s4[0][1]); \
      p2=__builtin_amdgcn_exp2f(s4[0][2]); p3=__builtin_amdgcn_exp2f(s4[0][3]); \
      p4=__builtin_amdgcn_exp2f(s4[1][0]); p5=__builtin_amdgcn_exp2f(s4[1][1]); \
      p6=__builtin_amdgcn_exp2f(s4[1][2]); p7=__builtin_amdgcn_exp2f(s4[1][3]); \
      l_r += ((p0+p1)+(p2+p3)) + ((p4+p5)+(p6+p7)); \
      union { u32 u[4]; bf16x8 v; } pa0, pa1; \
      pa0.u[0]=cvtpk(p0,p1); pa0.u[1]=cvtpk(p2,p3); pa0.u[2]=cvtpk(p4,p5); pa0.u[3]=cvtpk(p6,p7); \
      p0=__builtin_amdgcn_exp2f(s4[2][0]); p1=__builtin_amdgcn_exp2f(s4[2][1]); \
      p2=__builtin_amdgcn_exp2f(s4[2][2]); p3=__builtin_amdgcn_exp2f(s4[2][3]); \
      p4=__builtin_amdgcn_exp2f(s4[3][0]); p5=__builtin_amdgcn_exp2f(s4[3][1]); \
      p6=__builtin_amdgcn_exp2f(s4[3][2]); p7=__builtin_amdgcn_exp2f(s4[3][3]); \
      l_r += ((p0+p1)+(p2+p3)) + ((p4+p5)+(p6+p7)); \
      pa1.u[0]=cvtpk(p0,p1); pa1.u[1]=cvtpk(p2,p3); pa1.u[2]=cvtpk(p4,p5); pa1.u[3]=cvtpk(p6,p7); \
      __builtin_amdgcn_s_setprio(1); \
      o0 = __builtin_amdgcn_mfma_f32_16x16x32_bf16(pa0.v, *(const bf16x8*)((const char*)(VBC) + offV[0][0]), o0, 0,0,0); \
      o1 = __builtin_amdgcn_mfma_f32_16x16x32_bf16(pa0.v, *(const bf16x8*)((const char*)(VBC) + offV[1][0]), o1, 0,0,0); \
      o0 = __builtin_amdgcn_mfma_f32_16x16x32_bf16(pa1.v, *(const bf16x8*)((const char*)(VBC) + offV[0][1]), o0, 0,0,0); \
      o1 = __builtin_amdgcn_mfma_f32_16x16x32_bf16(pa1.v, *(const bf16x8*)((const char*)(VBC) + offV[1][1]), o1, 0,0,0); \
      __builtin_amdgcn_s_setprio(0); \
    } \
    __syncthreads(); \
  } while(0)

  const int nmax = (qt + 2) >> 1;
  const int jmax = (nmax + 1) >> 1;
  for (int j = 0; j < jmax; ++j){
    ABODY(2*j,   KB0, VB0, KB1, VB1);
    ABODY(2*j+1, KB1, VB1, KB0, VB0);
  }
  l_r += __shfl_xor(l_r, 16);
  l_r += __shfl_xor(l_r, 32);

  // ---- in-LDS merge of the two partial (unnormalized) results ----
  float* MO = (float*)SMEM;               // [64][34] padded
  float* ML = (float*)(SMEM + 12288);     // l[64]
  if (sg == 1){
    #pragma unroll
    for (int r=0;r<4;++r){
      MO[(wvL*16 + 4*gq + r)*34 + lr]      = o0[r];
      MO[(wvL*16 + 4*gq + r)*34 + 16 + lr] = o1[r];
    }
    if (gq == 0) ML[wvL*16 + lr] = l_r;
  }
  __syncthreads();
  if (sg == 0){
    float lS = l_r + ML[wvL*16 + lr];
    float lS_o[4];
    #pragma unroll
    for (int r=0;r<4;++r) lS_o[r] = __shfl(lS, 4*gq + r);
    #pragma unroll
    for (int r=0;r<4;++r){
      int orow = wvL*16 + 4*gq + r;
      float v0 = (o0[r] + MO[orow*34 + lr])      / lS_o[r];
      float v1 = (o1[r] + MO[orow*34 + 16 + lr]) / lS_o[r];
      size_t ob = (size_t)(b*2048 + q0 + orow)*512 + h*32;
      Out[ob + lr]      = f2bf(v0);
      Out[ob + 16 + lr] = f2bf(v1);
    }
  }
}

// ---------- workspace layout (bytes) ----------
#define WS_B2   0u
#define WS_WT   8192u                                // 1536*1024*2 = 3145728
#define WS_W2T  (WS_WT + 3145728u)                   // 1024*512*2  = 1048576
#define WS_XB   (WS_W2T + 1048576u)                  // 4096*1024*2 = 8388608
#define WS_QKV  (WS_XB + 8388608u)                   // 4096*1536*2 = 12582912
#define WS_VT   (WS_QKV + 12582912u)                 // 1024*2048*2 = 4194304
#define WS_ATT  (WS_VT + 4194304u)                   // 4096*512*2  = 4194304

extern "C" void kernel_launch(void* const* d_in, const int* in_sizes, int n_in,
                              void* d_out, int out_size, void* d_ws, size_t ws_size,
                              hipStream_t stream) {
  const float* x  = (const float*)d_in[0];
  const float* Wa = (const float*)d_in[1];
  const float* ba = (const float*)d_in[2];
  const float* Wp = (const float*)d_in[3];
  const float* bp = (const float*)d_in[4];
  const float* kc = (const float*)d_in[5];
  const float* ke = (const float*)d_in[6];
  const float* vc = (const float*)d_in[7];
  const float* ve = (const float*)d_in[8];
  float* out = (float*)d_out;
  char* ws = (char*)d_ws;
  float* b2  = (float*)(ws + WS_B2);
  u16* Wt    = (u16*)(ws + WS_WT);
  u16* W2t   = (u16*)(ws + WS_W2T);
  u16* Xb    = (u16*)(ws + WS_XB);
  u16* QKVb  = (u16*)(ws + WS_QKV);
  u16* Vt    = (u16*)(ws + WS_VT);
  u16* Att   = (u16*)(ws + WS_ATT);

  prep_all<<<1926, 256, 0, stream>>>(x, Wa, ba, Wp, kc, ke, vc, ve, Wt, b2, W2t, Xb);
  gemm64<u16><<<dim3(64,12), 256, 0, stream>>>(Xb, Wt, b2, QKVb, 4096, 1536, 1024, 1536);
  v_transpose_lat<<<dim3(32,32), 256, 0, stream>>>(QKVb, Vt);
  attn_fwd<<<dim3(32,32), 512, 0, stream>>>(QKVb, Vt, Att);
  gemm64<float><<<dim3(64,8), 256, 0, stream>>>(Att, W2t, bp, out, 4096, 1024, 512, 1024);
}